// Round 5
// baseline (1519.403 us; speedup 1.0000x reference)
//
#include <hip/hip_runtime.h>
#include <hip/hip_bf16.h>
#include <hip/hip_cooperative_groups.h>
#include <cstdint>

// GGNN encoder, B=4, N=1024, DIN=D=256, E=5, STEP=5. Inputs fp32 (sniffed).
// Round 13: single persistent cooperative kernel for h-init + 5x{heT ->
// part||gh -> gi+gate} + conv + finish (17 phases, grid.sync between).
// Tile bodies are round-3's verbatim (430 us best), as device fns over a
// 32KB LDS union. Pre: detect/prep/wcvt/bias_gi/adj_cvt dispatches. Fallback
// to the round-3 dispatch path if cooperative launch unavailable.

namespace cg = cooperative_groups;

typedef __attribute__((ext_vector_type(8))) short bf16x8;
typedef __attribute__((ext_vector_type(4))) float f32x4;

__device__ __forceinline__ float bf2f(__hip_bfloat16 x) { return __bfloat162float(x); }
__device__ __forceinline__ __hip_bfloat16 f2bf(float x) { return __float2bfloat16(x); }
__device__ __forceinline__ short f2bs(float x) {
  __hip_bfloat16 h = __float2bfloat16(x);
  return *reinterpret_cast<short*>(&h);
}
__device__ __forceinline__ float s2f(short x) {
  __hip_bfloat16 h = *reinterpret_cast<__hip_bfloat16*>(&x);
  return __bfloat162float(h);
}

__device__ __forceinline__ bf16x8 ld8_ext(const void* base, long off, bool f32) {
  if (f32) {
    const float* p = (const float*)base + off;
    bf16x8 r;
#pragma unroll
    for (int i = 0; i < 8; ++i) r[i] = f2bs(p[i]);
    return r;
  }
  return *(const bf16x8*)((const __hip_bfloat16*)base + off);
}

// sum of 5 bf16 part slices: part[(b*5+e)][1024][256], row = b*1024+node
__device__ __forceinline__ bf16x8 ld8_sum5(const __hip_bfloat16* part, int row, int k) {
  const long base = (long)row * 256 + (long)(row >> 10) * 1048576 + k;
  float s[8] = {0.f, 0.f, 0.f, 0.f, 0.f, 0.f, 0.f, 0.f};
#pragma unroll
  for (int e = 0; e < 5; ++e) {
    bf16x8 v = *(const bf16x8*)(part + base + e * 262144);
#pragma unroll
    for (int j = 0; j < 8; ++j) s[j] += s2f(v[j]);
  }
  bf16x8 r;
#pragma unroll
  for (int j = 0; j < 8; ++j) r[j] = f2bs(s[j]);
  return r;
}

// ---- dtype sniffer: flag = 1 if inputs are fp32, 0 if bf16 ----
__global__ void detect_dtype(const uint32_t* __restrict__ raw, int* __restrict__ flag) {
  __shared__ int cnt;
  if (threadIdx.x == 0) cnt = 0;
  __syncthreads();
  int c = 0;
  for (int i = threadIdx.x; i < 512; i += 256) {
    uint32_t byte = (raw[i] >> 8) & 0xFF;
    if (byte >= 0x28 && byte <= 0x40) ++c;
  }
  atomicAdd(&cnt, c);
  __syncthreads();
  if (threadIdx.x == 0) *flag = (cnt < 300) ? 1 : 0;
}

// fp32 pool: [0:256) fc_b | [256:1024) b_ih | [1024:1792) b_hh | [1792:2048)
// conv1_b | [2048:2304) conv2_b | [2304:2560) sum_e edge_b | [2560:3328) bias_gi
__global__ void prep_pool(const void* fcb, const void* bih, const void* bhh,
                          const void* c1b, const void* c2b, const void* edgeb,
                          const int* __restrict__ flag,
                          float* __restrict__ pool, float* __restrict__ ge,
                          float* __restrict__ am32) {
  const bool f32 = (*flag != 0);
  for (int t = threadIdx.x; t < 2560; t += 256) {
    const void* p; int i;
    if (t < 256)       { p = fcb;  i = t; }
    else if (t < 1024) { p = bih;  i = t - 256; }
    else if (t < 1792) { p = bhh;  i = t - 1024; }
    else if (t < 2048) { p = c1b;  i = t - 1792; }
    else if (t < 2304) { p = c2b;  i = t - 2048; }
    else {
      int k = t - 2304; float s = 0.f;
      for (int e = 0; e < 5; ++e)
        s += f32 ? ((const float*)edgeb)[e * 256 + k]
                 : bf2f(((const __hip_bfloat16*)edgeb)[e * 256 + k]);
      pool[t] = s; continue;
    }
    pool[t] = f32 ? ((const float*)p)[i] : bf2f(((const __hip_bfloat16*)p)[i]);
  }
  for (int t = threadIdx.x; t < 1024; t += 256) ge[t] = 0.f;
  for (int t = threadIdx.x; t < 4096; t += 256) am32[t] = 0.f;
}

// bias_gi[n] = b_ih[n] + sum_k sum_edge_b[k] * w_ih[n][k]   (n < 768)
__global__ void bias_gi_k(const float* __restrict__ pool,
                          const __hip_bfloat16* __restrict__ wih,
                          float* __restrict__ out) {
  const int n = blockIdx.x * 256 + threadIdx.x;
  if (n >= 768) return;
  float s = pool[256 + n];
  for (int k = 0; k < 256; ++k) s += pool[2304 + k] * bf2f(wih[n * 256 + k]);
  out[n] = s;
}

// ingest all 6 weight matrices into one internal bf16 pool
__global__ void wcvt_all(const void* fcw, const void* edw, const void* wih,
                         const void* whh, const void* c1w, const void* c2w,
                         const int* __restrict__ flag, __hip_bfloat16* __restrict__ dst) {
  const bool f32 = (*flag != 0);
  const int i = blockIdx.x * 256 + threadIdx.x;   // 0..917503
  const void* src; int off;
  if      (i < 65536)  { src = fcw; off = i; }
  else if (i < 393216) { src = edw; off = i - 65536; }
  else if (i < 589824) { src = wih; off = i - 393216; }
  else if (i < 786432) { src = whh; off = i - 589824; }
  else if (i < 851968) { src = c1w; off = i - 786432; }
  else                 { src = c2w; off = i - 851968; }
  dst[i] = f32 ? f2bf(((const float*)src)[off])
               : ((const __hip_bfloat16*)src)[off];
}

// one-time adj -> internal bf16 (20,971,520 elems), 8 elems/thread
__global__ void adj_cvt(const void* __restrict__ src, const int* __restrict__ flag,
                        __hip_bfloat16* __restrict__ dst) {
  const bool f32 = (*flag != 0);
  const long i = ((long)blockIdx.x * 256 + threadIdx.x) * 8;
  bf16x8 r;
  if (f32) {
    const float* p = (const float*)src + i;
#pragma unroll
    for (int j = 0; j < 8; ++j) r[j] = f2bs(p[j]);
  } else {
    r = *(const bf16x8*)((const __hip_bfloat16*)src + i);
  }
  *(bf16x8*)(dst + i) = r;
}

// ===========================================================================
// Device tile bodies for the cooperative kernel (round-3 structures verbatim)
// smem union (32 KB): tile128: sA[128*64]@0, sB[64*64]@16384B
//                     gi_tile: sA@0, sB0@8192, sB1@16384, sB2@24576
//                     conv:    sA@0, sB1@8192, sB2@16384, sge@24576, sam@24832
// ===========================================================================

// 128x64-tile GEMM body: C = A @ Bt^T (+bias). A via ld8_ext (bf16 or fp32).
__device__ __forceinline__ void tile128(char* smem, int t,
    const void* Abase, int lda, bool af32,
    const __hip_bfloat16* Bb, int ldb,
    const float* bias, __hip_bfloat16* C, int ldc,
    int K, int m0, int n0)
{
  __hip_bfloat16* sA = (__hip_bfloat16*)smem;
  __hip_bfloat16* sB = (__hip_bfloat16*)(smem + 16384);
  const int w = t >> 6, l = t & 63;
  int sra[4], sca[4];
#pragma unroll
  for (int i = 0; i < 4; ++i) {
    const int p = t + 256 * i;
    sra[i] = p >> 3;
    sca[i] = (p & 7) ^ (sra[i] & 7);
  }
  const int p0 = t, p1 = t + 256;
  const int sr0 = p0 >> 3, sc0 = (p0 & 7) ^ (sr0 & 7);
  const int sr1 = p1 >> 3, sc1 = (p1 & 7) ^ (sr1 & 7);

  f32x4 acc[2][4];
#pragma unroll
  for (int i = 0; i < 2; ++i)
#pragma unroll
    for (int j = 0; j < 4; ++j) acc[i][j] = (f32x4){0.f, 0.f, 0.f, 0.f};

  const int r15 = l & 15;
  const int quad = l >> 4;

  for (int k0 = 0; k0 < K; k0 += 64) {
    bf16x8 av[4];
#pragma unroll
    for (int i = 0; i < 4; ++i)
      av[i] = ld8_ext(Abase, (long)(m0 + sra[i]) * lda + (k0 + sca[i] * 8), af32);
    bf16x8 b0 = *(const bf16x8*)(Bb + (long)(n0 + sr0) * ldb + (k0 + sc0 * 8));
    bf16x8 b1 = *(const bf16x8*)(Bb + (long)(n0 + sr1) * ldb + (k0 + sc1 * 8));
    __syncthreads();
#pragma unroll
    for (int i = 0; i < 4; ++i) *(bf16x8*)(sA + (t + 256 * i) * 8) = av[i];
    *(bf16x8*)(sB + p0 * 8) = b0;
    *(bf16x8*)(sB + p1 * 8) = b1;
    __syncthreads();
#pragma unroll
    for (int ks = 0; ks < 2; ++ks) {
      const int cg = ks * 4 + quad;
      bf16x8 aF[2], bF[4];
#pragma unroll
      for (int mi = 0; mi < 2; ++mi) {
        const int row = mi * 64 + w * 16 + r15;
        aF[mi] = *(const bf16x8*)(sA + row * 64 + ((cg ^ (row & 7)) * 8));
      }
#pragma unroll
      for (int ni = 0; ni < 4; ++ni) {
        const int nrow = ni * 16 + r15;
        bF[ni] = *(const bf16x8*)(sB + nrow * 64 + ((cg ^ (nrow & 7)) * 8));
      }
#pragma unroll
      for (int mi = 0; mi < 2; ++mi)
#pragma unroll
        for (int ni = 0; ni < 4; ++ni)
          acc[mi][ni] = __builtin_amdgcn_mfma_f32_16x16x32_bf16(
              aF[mi], bF[ni], acc[mi][ni], 0, 0, 0);
    }
  }

  const bool hasb = (bias != nullptr);
#pragma unroll
  for (int mi = 0; mi < 2; ++mi) {
#pragma unroll
    for (int ni = 0; ni < 4; ++ni) {
      const int n = n0 + ni * 16 + r15;
      const float bv = hasb ? bias[n] : 0.f;
#pragma unroll
      for (int r = 0; r < 4; ++r) {
        const int m = m0 + mi * 64 + w * 16 + quad * 4 + r;
        C[(long)m * ldc + n] = f2bf(acc[mi][ni][r] + bv);
      }
    }
  }
}

// gi (sum_e part @ wih^T, 3 gates) + GRU gate epilogue, h in-place.
__device__ __forceinline__ void gi_tile(char* smem, int t,
    const __hip_bfloat16* ms, const __hip_bfloat16* wih,
    const float* biasgi, const __hip_bfloat16* gh,
    __hip_bfloat16* hbf, void* ns_out, bool f32flag, int m0, int n0)
{
  __hip_bfloat16* sA  = (__hip_bfloat16*)smem;
  __hip_bfloat16* sB0 = (__hip_bfloat16*)(smem + 8192);
  __hip_bfloat16* sB1 = (__hip_bfloat16*)(smem + 16384);
  __hip_bfloat16* sB2 = (__hip_bfloat16*)(smem + 24576);
  const int w = t >> 6, l = t & 63;
  const int p0 = t, p1 = t + 256;
  const int sr0 = p0 >> 3, sc0 = (p0 & 7) ^ (sr0 & 7);
  const int sr1 = p1 >> 3, sc1 = (p1 & 7) ^ (sr1 & 7);

  f32x4 acc[3][4];
#pragma unroll
  for (int g = 0; g < 3; ++g)
#pragma unroll
    for (int j = 0; j < 4; ++j) acc[g][j] = (f32x4){0.f, 0.f, 0.f, 0.f};

  const int mrow = w * 16 + (l & 15);
  const int r15 = l & 15;
  const int quad = l >> 4;

  for (int k0 = 0; k0 < 256; k0 += 64) {
    bf16x8 a0 = ld8_sum5(ms, m0 + sr0, k0 + sc0 * 8);
    bf16x8 a1 = ld8_sum5(ms, m0 + sr1, k0 + sc1 * 8);
    bf16x8 bg[3][2];
#pragma unroll
    for (int g = 0; g < 3; ++g) {
      bg[g][0] = *(const bf16x8*)(wih + (long)(g * 256 + n0 + sr0) * 256 + (k0 + sc0 * 8));
      bg[g][1] = *(const bf16x8*)(wih + (long)(g * 256 + n0 + sr1) * 256 + (k0 + sc1 * 8));
    }
    __syncthreads();
    *(bf16x8*)(sA + p0 * 8) = a0;
    *(bf16x8*)(sA + p1 * 8) = a1;
    *(bf16x8*)(sB0 + p0 * 8) = bg[0][0]; *(bf16x8*)(sB0 + p1 * 8) = bg[0][1];
    *(bf16x8*)(sB1 + p0 * 8) = bg[1][0]; *(bf16x8*)(sB1 + p1 * 8) = bg[1][1];
    *(bf16x8*)(sB2 + p0 * 8) = bg[2][0]; *(bf16x8*)(sB2 + p1 * 8) = bg[2][1];
    __syncthreads();
#pragma unroll
    for (int ks = 0; ks < 2; ++ks) {
      const int cg = ks * 4 + quad;
      bf16x8 af = *(const bf16x8*)(sA + mrow * 64 + ((cg ^ (mrow & 7)) * 8));
#pragma unroll
      for (int t4 = 0; t4 < 4; ++t4) {
        const int nrow = t4 * 16 + r15;
        const int so = nrow * 64 + ((cg ^ (nrow & 7)) * 8);
        bf16x8 b0f = *(const bf16x8*)(sB0 + so);
        bf16x8 b1f = *(const bf16x8*)(sB1 + so);
        bf16x8 b2f = *(const bf16x8*)(sB2 + so);
        acc[0][t4] = __builtin_amdgcn_mfma_f32_16x16x32_bf16(af, b0f, acc[0][t4], 0, 0, 0);
        acc[1][t4] = __builtin_amdgcn_mfma_f32_16x16x32_bf16(af, b1f, acc[1][t4], 0, 0, 0);
        acc[2][t4] = __builtin_amdgcn_mfma_f32_16x16x32_bf16(af, b2f, acc[2][t4], 0, 0, 0);
      }
    }
  }

  const bool f32out = (ns_out != nullptr) && f32flag;
#pragma unroll
  for (int t4 = 0; t4 < 4; ++t4) {
    const int n = n0 + t4 * 16 + r15;
    const float bgr = biasgi[n];
    const float bgz = biasgi[256 + n];
    const float bgn = biasgi[512 + n];
#pragma unroll
    for (int r = 0; r < 4; ++r) {
      const int m = m0 + w * 16 + quad * 4 + r;
      const long gb = (long)m * 768;
      const float ir = acc[0][t4][r] + bgr;
      const float iz = acc[1][t4][r] + bgz;
      const float inn = acc[2][t4][r] + bgn;
      const float hr = bf2f(gh[gb + n]);
      const float hz = bf2f(gh[gb + 256 + n]);
      const float hn = bf2f(gh[gb + 512 + n]);
      const long hidx = (long)m * 256 + n;
      const float h = bf2f(hbf[hidx]);
      const float rr = 1.f / (1.f + __expf(-(ir + hr)));
      const float zz = 1.f / (1.f + __expf(-(iz + hz)));
      const float nn = tanhf(inn + rr * hn);
      const float hnew = (1.f - zz) * nn + zz * h;
      const __hip_bfloat16 hb = f2bf(hnew);
      hbf[hidx] = hb;
      if (ns_out) {
        if (f32out) ((float*)ns_out)[1024 + hidx] = hnew;
        else        ((__hip_bfloat16*)ns_out)[1024 + hidx] = hb;
      }
    }
  }
}

// conv epilogue tile: attl/fetl MFMA + sigmoid/tanh + LDS/atomic reductions
__device__ __forceinline__ void conv_tile(char* smem, int t,
    const __hip_bfloat16* hbf, const __hip_bfloat16* c1w,
    const __hip_bfloat16* c2w, const float* pool,
    float* geg, float* am32, int m0, int n0)
{
  __hip_bfloat16* sA  = (__hip_bfloat16*)smem;
  __hip_bfloat16* sB1 = (__hip_bfloat16*)(smem + 8192);
  __hip_bfloat16* sB2 = (__hip_bfloat16*)(smem + 16384);
  float* sge = (float*)(smem + 24576);
  float* sam = (float*)(smem + 24832);
  const int w = t >> 6, l = t & 63;
  if (t < 64) { sge[t] = 0.f; sam[t] = 0.f; }
  const int p0 = t, p1 = t + 256;
  const int sr0 = p0 >> 3, sc0 = (p0 & 7) ^ (sr0 & 7);
  const int sr1 = p1 >> 3, sc1 = (p1 & 7) ^ (sr1 & 7);
  f32x4 a1[4], a2[4];
#pragma unroll
  for (int i = 0; i < 4; ++i) { a1[i] = (f32x4){0,0,0,0}; a2[i] = (f32x4){0,0,0,0}; }
  const int mrow = w * 16 + (l & 15);
  const int quad = l >> 4;
  for (int k0 = 0; k0 < 256; k0 += 64) {
    bf16x8 va0 = *(const bf16x8*)(hbf + (long)(m0 + sr0) * 256 + (k0 + sc0 * 8));
    bf16x8 va1 = *(const bf16x8*)(hbf + (long)(m0 + sr1) * 256 + (k0 + sc1 * 8));
    bf16x8 vb0 = *(const bf16x8*)(c1w + (long)(n0 + sr0) * 256 + (k0 + sc0 * 8));
    bf16x8 vb1 = *(const bf16x8*)(c1w + (long)(n0 + sr1) * 256 + (k0 + sc1 * 8));
    bf16x8 vc0 = *(const bf16x8*)(c2w + (long)(n0 + sr0) * 256 + (k0 + sc0 * 8));
    bf16x8 vc1 = *(const bf16x8*)(c2w + (long)(n0 + sr1) * 256 + (k0 + sc1 * 8));
    __syncthreads();
    *(bf16x8*)(sA + p0 * 8) = va0;  *(bf16x8*)(sA + p1 * 8) = va1;
    *(bf16x8*)(sB1 + p0 * 8) = vb0; *(bf16x8*)(sB1 + p1 * 8) = vb1;
    *(bf16x8*)(sB2 + p0 * 8) = vc0; *(bf16x8*)(sB2 + p1 * 8) = vc1;
    __syncthreads();
#pragma unroll
    for (int ks = 0; ks < 2; ++ks) {
      const int cg = ks * 4 + quad;
      bf16x8 af = *(const bf16x8*)(sA + mrow * 64 + ((cg ^ (mrow & 7)) * 8));
#pragma unroll
      for (int t4 = 0; t4 < 4; ++t4) {
        const int nrow = t4 * 16 + (l & 15);
        bf16x8 b1f = *(const bf16x8*)(sB1 + nrow * 64 + ((cg ^ (nrow & 7)) * 8));
        bf16x8 b2f = *(const bf16x8*)(sB2 + nrow * 64 + ((cg ^ (nrow & 7)) * 8));
        a1[t4] = __builtin_amdgcn_mfma_f32_16x16x32_bf16(af, b1f, a1[t4], 0, 0, 0);
        a2[t4] = __builtin_amdgcn_mfma_f32_16x16x32_bf16(af, b2f, a2[t4], 0, 0, 0);
      }
    }
  }
  float asum[4] = {0.f, 0.f, 0.f, 0.f};
#pragma unroll
  for (int t4 = 0; t4 < 4; ++t4) {
    const int n = n0 + t4 * 16 + (l & 15);
    const float bb1 = pool[1792 + n], bb2 = pool[2048 + n];
    float g = 0.f;
#pragma unroll
    for (int r = 0; r < 4; ++r) {
      const float av = 1.f / (1.f + __expf(-(a1[t4][r] + bb1)));
      const float fv = tanhf(a2[t4][r] + bb2);
      g += av * fv;
      asum[r] += av;
    }
    atomicAdd(&sge[t4 * 16 + (l & 15)], g);
  }
#pragma unroll
  for (int r = 0; r < 4; ++r) atomicAdd(&sam[w * 16 + quad * 4 + r], asum[r]);
  __syncthreads();
  if (t < 64) atomicAdd(&geg[(m0 >> 10) * 256 + n0 + t], sge[t]);
  else if (t < 128) atomicAdd(&am32[m0 + (t - 64)], sam[t - 64]);
}

// ===========================================================================
// The persistent cooperative kernel: 17 phases, grid-stride item loops.
// ===========================================================================
__global__ __launch_bounds__(256, 2)
void ggnn_all(const __hip_bfloat16* wbf, const float* bp,
              const void* node_f, const __hip_bfloat16* adjb,
              __hip_bfloat16* hbf, __hip_bfloat16* heT,
              __hip_bfloat16* ms, __hip_bfloat16* gh,
              float* geg, float* am32, void* dout, const int* flag)
{
  cg::grid_group gg = cg::this_grid();
  __shared__ __align__(16) char smem[32768];
  const int t = threadIdx.x;
  const bool f32 = (*flag != 0);
  const __hip_bfloat16* fcw = wbf;
  const __hip_bfloat16* ew  = wbf + 65536;
  const __hip_bfloat16* wih = wbf + 393216;
  const __hip_bfloat16* whh = wbf + 589824;
  const __hip_bfloat16* c1w = wbf + 786432;
  const __hip_bfloat16* c2w = wbf + 851968;

  // P0: h = X @ fc_w^T + fc_b  (M=4096 N=256, 128 items of 128x64)
  for (int it = blockIdx.x; it < 128; it += gridDim.x) {
    const int m0 = (it & 31) * 128, n0 = (it >> 5) * 64;
    tile128(smem, t, node_f, 256, f32, fcw, 256, bp + 0, hbf, 256, 256, m0, n0);
  }
  __threadfence(); gg.sync();

  for (int s = 0; s < 5; ++s) {
    // A: heT[z] = edge_w[e] @ h[b]^T  (M=256 N=1024 K=256, 640 items)
    for (int it = blockIdx.x; it < 640; it += gridDim.x) {
      const int z = it >> 5, rem = it & 31;
      const int m0 = (rem & 1) * 128, n0 = (rem >> 1) * 64;
      tile128(smem, t, ew + (z % 5) * 65536, 256, false,
              hbf + (long)(z / 5) * 262144, 256,
              nullptr, heT + (long)z * 262144, 1024, 256, m0, n0);
    }
    __threadfence(); gg.sync();
    // B: part[z] = adj[z] @ he[z] (640) || gh = h @ w_hh^T + b_hh (384)
    for (int it = blockIdx.x; it < 1024; it += gridDim.x) {
      if (it < 640) {
        const int z = it >> 5, rem = it & 31;
        const int m0 = (rem & 7) * 128, n0 = (rem >> 3) * 64;
        tile128(smem, t, adjb + (long)z * 1048576, 1024, false,
                heT + (long)z * 262144, 1024,
                nullptr, ms + (long)z * 262144, 256, 1024, m0, n0);
      } else {
        const int idx = it - 640;
        const int m0 = (idx & 31) * 128, n0 = (idx >> 5) * 64;
        tile128(smem, t, hbf, 256, false, whh, 256,
                bp + 1024, gh, 768, 256, m0, n0);
      }
    }
    __threadfence(); gg.sync();
    // C: gi (3-gate, sum5 A) + GRU gates -> h in place (256 items)
    void* ns = (s == 4) ? dout : nullptr;
    for (int it = blockIdx.x; it < 256; it += gridDim.x) {
      const int m0 = (it & 63) * 64, n0 = (it >> 6) * 64;
      gi_tile(smem, t, ms, wih, bp + 2560, gh, hbf, ns, f32, m0, n0);
    }
    __threadfence(); gg.sync();
  }

  // conv epilogue (256 items)
  for (int it = blockIdx.x; it < 256; it += gridDim.x) {
    const int m0 = (it & 63) * 64, n0 = (it >> 6) * 64;
    conv_tile(smem, t, hbf, c1w, c2w, bp, geg, am32, m0, n0);
  }
  __threadfence(); gg.sync();
  // finish (20 items)
  for (int it = blockIdx.x; it < 20; it += gridDim.x) {
    const int tt = it * 256 + t;
    if (tt < 1024) {
      if (f32) ((float*)dout)[tt] = geg[tt];
      else     ((__hip_bfloat16*)dout)[tt] = f2bf(geg[tt]);
    } else {
      const float v = am32[tt - 1024] * (1.f / 256.f);
      if (f32) ((float*)dout)[1049600 + tt - 1024] = v;
      else     ((__hip_bfloat16*)dout)[1049600 + tt - 1024] = f2bf(v);
    }
  }
}

// ===========================================================================
// Round-3 fallback kernels (dispatch path)
// ===========================================================================
template<bool HAS_BIAS, bool DUAL>
__global__ __launch_bounds__(256)
void gemm_bt128(const __hip_bfloat16* __restrict__ A, const __hip_bfloat16* __restrict__ Bt,
                const float* __restrict__ bias, __hip_bfloat16* __restrict__ C,
                const __hip_bfloat16* __restrict__ A2, const __hip_bfloat16* __restrict__ Bt2,
                const float* __restrict__ bias2, __hip_bfloat16* __restrict__ C2,
                int K, int lda, int ldb, int ldc,
                long aBatch, int zdivA, int zmodA,
                long bBatch, int zdivB, int zmodB,
                long cBatch, int zdivC, int zSplit)
{
  __shared__ __align__(16) char smem[24576];
  const int t = threadIdx.x;
  const int m0 = blockIdx.x * 128;
  const int n0 = blockIdx.y * 64;
  int z = blockIdx.z;
  const __hip_bfloat16* Au = A; const __hip_bfloat16* Btu = Bt;
  const float* biasu = bias; __hip_bfloat16* Cu = C;
  if (DUAL && z >= zSplit) { Au = A2; Btu = Bt2; biasu = bias2; Cu = C2; z -= zSplit; }
  const __hip_bfloat16* Ab = Au + (long)((z / zdivA) % zmodA) * aBatch;
  const __hip_bfloat16* Bb = Btu + (long)((z / zdivB) % zmodB) * bBatch;
  tile128(smem, t, Ab, lda, false, Bb, ldb, HAS_BIAS ? biasu : nullptr,
          Cu + (long)(z / zdivC) * cBatch, ldc, K, m0, n0);
}

__global__ __launch_bounds__(256)
void part_gh(const __hip_bfloat16* __restrict__ adjb,
             const __hip_bfloat16* __restrict__ heT,
             __hip_bfloat16* __restrict__ part,
             const __hip_bfloat16* __restrict__ hbf,
             const __hip_bfloat16* __restrict__ whh,
             const float* __restrict__ bhh,
             __hip_bfloat16* __restrict__ gh)
{
  __shared__ __align__(16) char smem[24576];
  const int t = threadIdx.x;
  const int bid = blockIdx.x;
  if (bid < 640) {
    const int z = bid >> 5, rem = bid & 31;
    tile128(smem, t, adjb + (long)z * 1048576, 1024, false,
            heT + (long)z * 262144, 1024, nullptr,
            part + (long)z * 262144, 256, 1024,
            (rem & 7) * 128, (rem >> 3) * 64);
  } else {
    const int idx = bid - 640;
    tile128(smem, t, hbf, 256, false, whh, 256, bhh, gh, 768, 256,
            (idx & 31) * 128, (idx >> 5) * 64);
  }
}

__global__ __launch_bounds__(256)
void gi_gate(const __hip_bfloat16* __restrict__ part,
             const __hip_bfloat16* __restrict__ wih,
             const float* __restrict__ biasgi,
             const __hip_bfloat16* __restrict__ gh,
             __hip_bfloat16* __restrict__ hbf,
             void* __restrict__ ns_out, const int* __restrict__ flag)
{
  __shared__ __align__(16) char smem[32768];
  gi_tile(smem, threadIdx.x, part, wih, biasgi, gh, hbf, ns_out,
          (*flag != 0), (blockIdx.x & 63) * 64, (blockIdx.x >> 6) * 64);
}

// generic 64^2 GEMM for pre-loop / non-adjb fallbacks
template<int OUT_MODE, bool HAS_BIAS, int A_MODE, bool DUAL>
__global__ __launch_bounds__(256)
void gemm_bt(const void* __restrict__ A, const __hip_bfloat16* __restrict__ Bt,
             const float* __restrict__ bias, void* __restrict__ Cp,
             const void* __restrict__ A2, const __hip_bfloat16* __restrict__ Bt2,
             const float* __restrict__ bias2, void* __restrict__ Cp2,
             const int* __restrict__ flag,
             int Kg, int ngrp, int lda, int ldb, int ldc,
             long aBatch, int zdivA, int zmodA,
             long bBatch, int zdivB, int zmodB,
             long cBatch, int zdivC, long aGrp, long bGrp, int zSplit)
{
  __shared__ __align__(16) __hip_bfloat16 sA[64 * 64];
  __shared__ __align__(16) __hip_bfloat16 sB[64 * 64];
  const bool af32 = (A_MODE == 1) ? (*flag != 0) : false;
  const int t = threadIdx.x;
  const int w = t >> 6;
  const int l = t & 63;
  const int m0 = blockIdx.x * 64;
  const int n0 = blockIdx.y * 64;
  int z = blockIdx.z;

  const void* Au = A; const __hip_bfloat16* Btu = Bt;
  const float* biasu = bias; void* Cpu = Cp;
  bool second = false;
  if (DUAL && z >= zSplit) {
    Au = A2; Btu = Bt2; biasu = bias2; Cpu = Cp2; z -= zSplit; second = true;
  }

  const long aOff = (long)((z / zdivA) % zmodA) * aBatch;
  const __hip_bfloat16* Bb = Btu + (long)((z / zdivB) % zmodB) * bBatch;

  const int p0 = t, p1 = t + 256;
  const int sr0 = p0 >> 3, sc0 = (p0 & 7) ^ (sr0 & 7);
  const int sr1 = p1 >> 3, sc1 = (p1 & 7) ^ (sr1 & 7);

  f32x4 acc[4];
#pragma unroll
  for (int i = 0; i < 4; ++i) acc[i] = (f32x4){0.f, 0.f, 0.f, 0.f};

  const int mrow = w * 16 + (l & 15);
  const int quad = l >> 4;

  for (int g = 0; g < ngrp; ++g) {
    const long aG = aOff + (long)g * aGrp;
    const __hip_bfloat16* Bg = Bb + (long)g * bGrp;
    for (int k0 = 0; k0 < Kg; k0 += 64) {
      bf16x8 a0, a1;
      if (A_MODE == 2 && !second) {
        a0 = ld8_sum5((const __hip_bfloat16*)Au, m0 + sr0, k0 + sc0 * 8);
        a1 = ld8_sum5((const __hip_bfloat16*)Au, m0 + sr1, k0 + sc1 * 8);
      } else if (A_MODE == 1) {
        a0 = ld8_ext(Au, aG + (long)(m0 + sr0) * lda + (k0 + sc0 * 8), af32);
        a1 = ld8_ext(Au, aG + (long)(m0 + sr1) * lda + (k0 + sc1 * 8), af32);
      } else {
        const __hip_bfloat16* Ab = (const __hip_bfloat16*)Au;
        a0 = *(const bf16x8*)(Ab + aG + (long)(m0 + sr0) * lda + (k0 + sc0 * 8));
        a1 = *(const bf16x8*)(Ab + aG + (long)(m0 + sr1) * lda + (k0 + sc1 * 8));
      }
      bf16x8 b0 = *(const bf16x8*)(Bg + (long)(n0 + sr0) * ldb + (k0 + sc0 * 8));
      bf16x8 b1 = *(const bf16x8*)(Bg + (long)(n0 + sr1) * ldb + (k0 + sc1 * 8));
      __syncthreads();
      *(bf16x8*)(sA + p0 * 8) = a0;
      *(bf16x8*)(sA + p1 * 8) = a1;
      *(bf16x8*)(sB + p0 * 8) = b0;
      *(bf16x8*)(sB + p1 * 8) = b1;
      __syncthreads();
#pragma unroll
      for (int ks = 0; ks < 2; ++ks) {
        const int cg = ks * 4 + quad;
        bf16x8 af = *(const bf16x8*)(sA + mrow * 64 + ((cg ^ (mrow & 7)) * 8));
#pragma unroll
        for (int t4 = 0; t4 < 4; ++t4) {
          const int nrow = t4 * 16 + (l & 15);
          bf16x8 bfr = *(const bf16x8*)(sB + nrow * 64 + ((cg ^ (nrow & 7)) * 8));
          acc[t4] = __builtin_amdgcn_mfma_f32_16x16x32_bf16(af, bfr, acc[t4], 0, 0, 0);
        }
      }
    }
  }

  const long cOff = (long)(z / zdivC) * cBatch;
#pragma unroll
  for (int t4 = 0; t4 < 4; ++t4) {
    const int n = n0 + t4 * 16 + (l & 15);
    float bv = 0.f;
    if (HAS_BIAS) bv = biasu[n];
#pragma unroll
    for (int r = 0; r < 4; ++r) {
      const int m = m0 + w * 16 + quad * 4 + r;
      const float v = acc[t4][r] + bv;
      if (OUT_MODE == 0)
        ((__hip_bfloat16*)Cpu)[cOff + (long)m * ldc + n] = f2bf(v);
      else
        ((float*)Cpu)[cOff + (long)m * ldc + n] = v;
    }
  }
}

__global__ void gru_gate8(const __hip_bfloat16* __restrict__ gi,
                          const __hip_bfloat16* __restrict__ gh,
                          __hip_bfloat16* __restrict__ hbf,
                          void* __restrict__ ns_out, const int* __restrict__ flag)
{
  const int t = blockIdx.x * 256 + threadIdx.x;
  const int m = t >> 5;
  const int k = (t & 31) * 8;
  const long gb = (long)m * 768 + k;
  bf16x8 vir = *(const bf16x8*)(gi + gb);
  bf16x8 viz = *(const bf16x8*)(gi + gb + 256);
  bf16x8 vin = *(const bf16x8*)(gi + gb + 512);
  bf16x8 vhr = *(const bf16x8*)(gh + gb);
  bf16x8 vhz = *(const bf16x8*)(gh + gb + 256);
  bf16x8 vhn = *(const bf16x8*)(gh + gb + 512);
  const long hidx = (long)m * 256 + k;
  bf16x8 vh = *(const bf16x8*)(hbf + hidx);
  bf16x8 out;
  float hf[8];
#pragma unroll
  for (int j = 0; j < 8; ++j) {
    const float r = 1.f / (1.f + __expf(-(s2f(vir[j]) + s2f(vhr[j]))));
    const float zz = 1.f / (1.f + __expf(-(s2f(viz[j]) + s2f(vhz[j]))));
    const float nn = tanhf(s2f(vin[j]) + r * s2f(vhn[j]));
    hf[j] = (1.f - zz) * nn + zz * s2f(vh[j]);
    out[j] = f2bs(hf[j]);
  }
  *(bf16x8*)(hbf + hidx) = out;
  if (ns_out) {
    if (*flag) {
      float* o = (float*)ns_out + 1024 + hidx;
#pragma unroll
      for (int j = 0; j < 8; ++j) o[j] = hf[j];
    } else {
      *(bf16x8*)((__hip_bfloat16*)ns_out + 1024 + hidx) = out;
    }
  }
}

__global__ __launch_bounds__(256)
void conv_fused(const __hip_bfloat16* __restrict__ hbf,
                const __hip_bfloat16* __restrict__ c1w,
                const __hip_bfloat16* __restrict__ c2w,
                const float* __restrict__ pool,
                float* __restrict__ geg, float* __restrict__ am32)
{
  __shared__ __align__(16) char smem[25088];
  conv_tile(smem, threadIdx.x, hbf, c1w, c2w, pool, geg, am32,
            blockIdx.x * 64, blockIdx.y * 64);
}

__global__ void finish_out(const float* __restrict__ ge, const float* __restrict__ am32,
                           void* __restrict__ dout, const int* __restrict__ flag)
{
  const int t = blockIdx.x * 256 + threadIdx.x;
  const bool f32 = (*flag != 0);
  if (t < 1024) {
    if (f32) ((float*)dout)[t] = ge[t];
    else     ((__hip_bfloat16*)dout)[t] = f2bf(ge[t]);
  } else {
    const float v = am32[t - 1024] * (1.f / 256.f);
    if (f32) ((float*)dout)[1049600 + t - 1024] = v;
    else     ((__hip_bfloat16*)dout)[1049600 + t - 1024] = f2bf(v);
  }
}

extern "C" void kernel_launch(void* const* d_in, const int* in_sizes, int n_in,
                              void* d_out, int out_size, void* d_ws, size_t ws_size,
                              hipStream_t stream) {
  (void)in_sizes; (void)n_in; (void)out_size;
  const void* node_f = d_in[0];
  const void* adj    = d_in[1];
  const void* fc_w   = d_in[2];
  const void* fc_b   = d_in[3];
  const void* edge_w = d_in[4];
  const void* edge_b = d_in[5];
  const void* w_ih   = d_in[6];
  const void* w_hh   = d_in[7];
  const void* b_ih   = d_in[8];
  const void* b_hh   = d_in[9];
  const void* c1w    = d_in[10];
  const void* c1b    = d_in[11];
  const void* c2w    = d_in[12];
  const void* c2b    = d_in[13];

  char* ws = (char*)d_ws;
  const size_t MB = (size_t)1 << 20;
  int*            flag = (int*)(ws);
  float*          bp   = (float*)(ws + 256);
  float*          ge   = (float*)(ws + 14336);
  float*          am32 = (float*)(ws + 18432);
  __hip_bfloat16* wbf  = (__hip_bfloat16*)(ws + 34816);
  __hip_bfloat16* hbf  = (__hip_bfloat16*)(ws + 1869824);
  char*           S    = ws + 3966976;
  __hip_bfloat16* heT  = (__hip_bfloat16*)(S);
  __hip_bfloat16* ms   = (__hip_bfloat16*)(S + 10 * MB);
  __hip_bfloat16* gi   = (__hip_bfloat16*)(S + 20 * MB);   // fallback only
  __hip_bfloat16* gh   = (__hip_bfloat16*)(S + 26 * MB);
  __hip_bfloat16* adjb = (__hip_bfloat16*)(ws + 40 * MB);

  const bool has_split = ws_size >= 38 * MB;
  const bool has_adjb  = ws_size >= 81 * MB;

  detect_dtype<<<1, 256, 0, stream>>>((const uint32_t*)adj, flag);
  prep_pool<<<1, 256, 0, stream>>>(fc_b, b_ih, b_hh, c1b, c2b, edge_b, flag, bp, ge, am32);
  wcvt_all<<<3584, 256, 0, stream>>>(fc_w, edge_w, w_ih, w_hh, c1w, c2w, flag, wbf);
  bias_gi_k<<<3, 256, 0, stream>>>(bp, wbf + 393216, bp + 2560);

  if (has_adjb) {
    adj_cvt<<<10240, 256, 0, stream>>>(adj, flag, adjb);

    // try the persistent cooperative kernel
    int maxB = 0;
    hipError_t oe = hipOccupancyMaxActiveBlocksPerMultiprocessor(&maxB, ggnn_all, 256, 0);
    int grid = 0;
    if (oe == hipSuccess && maxB > 0) {
      grid = maxB * 256;
      if (grid > 1024) grid = 1024;
    }
    if (grid >= 256) {
      void* doutL = d_out;
      void* args[12] = {
        (void*)&wbf, (void*)&bp, (void*)&node_f, (void*)&adjb,
        (void*)&hbf, (void*)&heT, (void*)&ms, (void*)&gh,
        (void*)&ge, (void*)&am32, (void*)&doutL, (void*)&flag };
      hipError_t le = hipLaunchCooperativeKernel(
          (void*)ggnn_all, dim3(grid), dim3(256), args, 0, stream);
      if (le == hipSuccess) return;
    }

    // --- fallback: round-3 dispatch path ---
    gemm_bt<0, true, 1, false><<<dim3(64, 4, 1), 256, 0, stream>>>(
        node_f, wbf + 0, bp + 0, hbf, nullptr, nullptr, nullptr, nullptr, flag,
        256, 1, 256, 256, 256, 0, 1, 1, 0, 1, 1, 0, 1, 0, 0, 0);
    for (int s = 0; s < 5; ++s) {
      gemm_bt128<false, false><<<dim3(2, 16, 20), 256, 0, stream>>>(
          wbf + 65536, hbf, nullptr, heT, nullptr, nullptr, nullptr, nullptr,
          256, 256, 256, 1024,
          65536, 1, 5,
          262144, 5, 4,
          262144, 1, 0);
      part_gh<<<1024, 256, 0, stream>>>(adjb, heT, ms,
                                        hbf, wbf + 589824, bp + 1024, gh);
      gi_gate<<<256, 256, 0, stream>>>(ms, wbf + 393216, bp + 2560, gh, hbf,
                                       (s == 4) ? d_out : nullptr, flag);
    }
    conv_fused<<<dim3(64, 4), 256, 0, stream>>>(hbf, wbf + 786432, wbf + 851968,
                                                bp, ge, am32);
    finish_out<<<20, 256, 0, stream>>>(ge, am32, d_out, flag);
    return;
  }

  // --- small-ws fallbacks (unchanged) ---
  gemm_bt<0, true, 1, false><<<dim3(64, 4, 1), 256, 0, stream>>>(
      node_f, wbf + 0, bp + 0, hbf, nullptr, nullptr, nullptr, nullptr, flag,
      256, 1, 256, 256, 256, 0, 1, 1, 0, 1, 1, 0, 1, 0, 0, 0);
  for (int s = 0; s < 5; ++s) {
    if (has_split) {
      gemm_bt<0, false, 0, false><<<dim3(4, 16, 20), 256, 0, stream>>>(
          wbf + 65536, hbf, nullptr, heT, nullptr, nullptr, nullptr, nullptr, flag,
          256, 1, 256, 256, 1024,
          65536, 1, 5, 262144, 5, 4,
          262144, 1, 0, 0, 0);
      gemm_bt<0, false, 1, false><<<dim3(16, 4, 20), 256, 0, stream>>>(
          adj, heT, nullptr, ms, nullptr, nullptr, nullptr, nullptr, flag,
          1024, 1, 1024, 1024, 256,
          1048576, 1, 20, 262144, 1, 20,
          262144, 1, 0, 0, 0);
      gemm_bt<0, true, 2, true><<<dim3(64, 12, 2), 256, 0, stream>>>(
          ms, wbf + 393216, bp + 2560, gi,
          hbf,  wbf + 589824, bp + 1024, gh, flag,
          256, 1, 256, 256, 768, 0, 1, 1, 0, 1, 1, 0, 1, 0, 0, 1);
      gru_gate8<<<512, 256, 0, stream>>>(gi, gh, hbf,
                                         (s == 4) ? d_out : nullptr, flag);
    } else {
      gemm_bt<0, false, 0, false><<<dim3(4, 16, 20), 256, 0, stream>>>(
          wbf + 65536, hbf, nullptr, heT, nullptr, nullptr, nullptr, nullptr, flag,
          256, 1, 256, 256, 1024,
          65536, 1, 5, 262144, 5, 4,
          262144, 1, 0, 0, 0);
      gemm_bt<0, true, 1, false><<<dim3(16, 4, 4), 256, 0, stream>>>(
          adj, heT, bp + 2304, ms, nullptr, nullptr, nullptr, nullptr, flag,
          1024, 5, 1024, 1024, 256,
          (long)5 * 1048576, 1, 4, (long)5 * 262144, 1, 4,
          262144, 1, 1048576, 262144, 0);
      gemm_bt<0, true, 0, true><<<dim3(64, 12, 2), 256, 0, stream>>>(
          ms, wbf + 393216, bp + 256, gi,
          hbf,  wbf + 589824, bp + 1024, gh, flag,
          256, 1, 256, 256, 768, 0, 1, 1, 0, 1, 1, 0, 1, 0, 0, 1);
      gru_gate8<<<512, 256, 0, stream>>>(gi, gh, hbf,
                                         (s == 4) ? d_out : nullptr, flag);
    }
  }
  conv_fused<<<dim3(64, 4), 256, 0, stream>>>(hbf, wbf + 786432, wbf + 851968,
                                              bp, ge, am32);
  finish_out<<<20, 256, 0, stream>>>(ge, am32, d_out, flag);
}

// Round 6
// 662.465 us; speedup vs baseline: 2.2936x; 2.2936x over previous
//
#include <hip/hip_runtime.h>
#include <hip/hip_bf16.h>
#include <cstdint>

// GGNN encoder, B=4, N=1024, DIN=D=256, E=5, STEP=5. Inputs fp32 (sniffed).
// Round 14: round-3 dispatch structure (best, 430us) + B-direct fragments:
// B operands (heT/whh/wih/c1w/c2w, all L2-resident) are loaded as MFMA
// fragments straight from global (per-lane 16B, 4 lanes/row x 64B runs),
// deleting sB staging. LDS reads/K-step drop 12->4 (was LDS-read-bound 2:1),
// LDS/block 8-16KB (occupancy up). A stays LDS-staged (adj streams from L3).
// Coop-kernel experiment (r13) reverted: grid.sync+threadfence forced HBM
// refetch (394MB FETCH, 2230us) on non-coherent XCD L2s.

typedef __attribute__((ext_vector_type(8))) short bf16x8;
typedef __attribute__((ext_vector_type(4))) float f32x4;

__device__ __forceinline__ float bf2f(__hip_bfloat16 x) { return __bfloat162float(x); }
__device__ __forceinline__ __hip_bfloat16 f2bf(float x) { return __float2bfloat16(x); }
__device__ __forceinline__ short f2bs(float x) {
  __hip_bfloat16 h = __float2bfloat16(x);
  return *reinterpret_cast<short*>(&h);
}
__device__ __forceinline__ float s2f(short x) {
  __hip_bfloat16 h = *reinterpret_cast<__hip_bfloat16*>(&x);
  return __bfloat162float(h);
}

__device__ __forceinline__ bf16x8 ld8_ext(const void* base, long off, bool f32) {
  if (f32) {
    const float* p = (const float*)base + off;
    bf16x8 r;
#pragma unroll
    for (int i = 0; i < 8; ++i) r[i] = f2bs(p[i]);
    return r;
  }
  return *(const bf16x8*)((const __hip_bfloat16*)base + off);
}

// sum of 5 bf16 part slices: part[(b*5+e)][1024][256], row = b*1024+node
__device__ __forceinline__ bf16x8 ld8_sum5(const __hip_bfloat16* part, int row, int k) {
  const long base = (long)row * 256 + (long)(row >> 10) * 1048576 + k;
  float s[8] = {0.f, 0.f, 0.f, 0.f, 0.f, 0.f, 0.f, 0.f};
#pragma unroll
  for (int e = 0; e < 5; ++e) {
    bf16x8 v = *(const bf16x8*)(part + base + e * 262144);
#pragma unroll
    for (int j = 0; j < 8; ++j) s[j] += s2f(v[j]);
  }
  bf16x8 r;
#pragma unroll
  for (int j = 0; j < 8; ++j) r[j] = f2bs(s[j]);
  return r;
}

// ---- dtype sniffer: flag = 1 if inputs are fp32, 0 if bf16 ----
__global__ void detect_dtype(const uint32_t* __restrict__ raw, int* __restrict__ flag) {
  __shared__ int cnt;
  if (threadIdx.x == 0) cnt = 0;
  __syncthreads();
  int c = 0;
  for (int i = threadIdx.x; i < 512; i += 256) {
    uint32_t byte = (raw[i] >> 8) & 0xFF;
    if (byte >= 0x28 && byte <= 0x40) ++c;
  }
  atomicAdd(&cnt, c);
  __syncthreads();
  if (threadIdx.x == 0) *flag = (cnt < 300) ? 1 : 0;
}

// fp32 pool: [0:256) fc_b | [256:1024) b_ih | [1024:1792) b_hh | [1792:2048)
// conv1_b | [2048:2304) conv2_b | [2304:2560) sum_e edge_b | [2560:3328) bias_gi
__global__ void prep_pool(const void* fcb, const void* bih, const void* bhh,
                          const void* c1b, const void* c2b, const void* edgeb,
                          const int* __restrict__ flag,
                          float* __restrict__ pool, float* __restrict__ ge,
                          float* __restrict__ am32) {
  const bool f32 = (*flag != 0);
  for (int t = threadIdx.x; t < 2560; t += 256) {
    const void* p; int i;
    if (t < 256)       { p = fcb;  i = t; }
    else if (t < 1024) { p = bih;  i = t - 256; }
    else if (t < 1792) { p = bhh;  i = t - 1024; }
    else if (t < 2048) { p = c1b;  i = t - 1792; }
    else if (t < 2304) { p = c2b;  i = t - 2048; }
    else {
      int k = t - 2304; float s = 0.f;
      for (int e = 0; e < 5; ++e)
        s += f32 ? ((const float*)edgeb)[e * 256 + k]
                 : bf2f(((const __hip_bfloat16*)edgeb)[e * 256 + k]);
      pool[t] = s; continue;
    }
    pool[t] = f32 ? ((const float*)p)[i] : bf2f(((const __hip_bfloat16*)p)[i]);
  }
  for (int t = threadIdx.x; t < 1024; t += 256) ge[t] = 0.f;
  for (int t = threadIdx.x; t < 4096; t += 256) am32[t] = 0.f;
}

// bias_gi[n] = b_ih[n] + sum_k sum_edge_b[k] * w_ih[n][k]   (n < 768)
__global__ void bias_gi_k(const float* __restrict__ pool,
                          const __hip_bfloat16* __restrict__ wih,
                          float* __restrict__ out) {
  const int n = blockIdx.x * 256 + threadIdx.x;
  if (n >= 768) return;
  float s = pool[256 + n];
  for (int k = 0; k < 256; ++k) s += pool[2304 + k] * bf2f(wih[n * 256 + k]);
  out[n] = s;
}

// ingest all 6 weight matrices into one internal bf16 pool
__global__ void wcvt_all(const void* fcw, const void* edw, const void* wih,
                         const void* whh, const void* c1w, const void* c2w,
                         const int* __restrict__ flag, __hip_bfloat16* __restrict__ dst) {
  const bool f32 = (*flag != 0);
  const int i = blockIdx.x * 256 + threadIdx.x;   // 0..917503
  const void* src; int off;
  if      (i < 65536)  { src = fcw; off = i; }
  else if (i < 393216) { src = edw; off = i - 65536; }
  else if (i < 589824) { src = wih; off = i - 393216; }
  else if (i < 786432) { src = whh; off = i - 589824; }
  else if (i < 851968) { src = c1w; off = i - 786432; }
  else                 { src = c2w; off = i - 851968; }
  dst[i] = f32 ? f2bf(((const float*)src)[off])
               : ((const __hip_bfloat16*)src)[off];
}

// one-time adj -> internal bf16 (20,971,520 elems), 8 elems/thread
__global__ void adj_cvt(const void* __restrict__ src, const int* __restrict__ flag,
                        __hip_bfloat16* __restrict__ dst) {
  const bool f32 = (*flag != 0);
  const long i = ((long)blockIdx.x * 256 + threadIdx.x) * 8;
  bf16x8 r;
  if (f32) {
    const float* p = (const float*)src + i;
#pragma unroll
    for (int j = 0; j < 8; ++j) r[j] = f2bs(p[j]);
  } else {
    r = *(const bf16x8*)((const __hip_bfloat16*)src + i);
  }
  *(bf16x8*)(dst + i) = r;
}

// ---------------------------------------------------------------------------
// B-direct 128x64 tile body: C = A @ Bt^T (+bias). A LDS-staged (XOR swizzle,
// conflict-free); B-fragments loaded straight from global (Bt row-major
// [N][K]; per-lane 16B, 4 lanes share a row -> 64B contiguous runs).
// LDS = 16KB (sA only). Per K-step/wave: 4 ds_read_b128 + 16 MFMA.
// ---------------------------------------------------------------------------
__device__ __forceinline__ void tile128bd(__hip_bfloat16* sA, int t,
    const __hip_bfloat16* Ab, int lda,
    const __hip_bfloat16* Bb, int ldb,
    const float* bias, __hip_bfloat16* C, int ldc,
    int K, int m0, int n0)
{
  const int w = t >> 6, l = t & 63;
  int sra[4], sca[4];
#pragma unroll
  for (int i = 0; i < 4; ++i) {
    const int p = t + 256 * i;
    sra[i] = p >> 3;
    sca[i] = (p & 7) ^ (sra[i] & 7);
  }

  f32x4 acc[2][4];
#pragma unroll
  for (int i = 0; i < 2; ++i)
#pragma unroll
    for (int j = 0; j < 4; ++j) acc[i][j] = (f32x4){0.f, 0.f, 0.f, 0.f};

  const int r15 = l & 15;
  const int quad = l >> 4;

  // per-lane B row bases (constant over k)
  const __hip_bfloat16* Brow[4];
#pragma unroll
  for (int ni = 0; ni < 4; ++ni)
    Brow[ni] = Bb + (long)(n0 + ni * 16 + r15) * ldb;

  for (int k0 = 0; k0 < K; k0 += 64) {
    bf16x8 av[4];
#pragma unroll
    for (int i = 0; i < 4; ++i)
      av[i] = *(const bf16x8*)(Ab + (long)(m0 + sra[i]) * lda + (k0 + sca[i] * 8));
    __syncthreads();
#pragma unroll
    for (int i = 0; i < 4; ++i) *(bf16x8*)(sA + (t + 256 * i) * 8) = av[i];
    __syncthreads();
#pragma unroll
    for (int ks = 0; ks < 2; ++ks) {
      const int cg = ks * 4 + quad;
      bf16x8 aF[2], bF[4];
#pragma unroll
      for (int ni = 0; ni < 4; ++ni)
        bF[ni] = *(const bf16x8*)(Brow[ni] + k0 + cg * 8);
#pragma unroll
      for (int mi = 0; mi < 2; ++mi) {
        const int row = mi * 64 + w * 16 + r15;
        aF[mi] = *(const bf16x8*)(sA + row * 64 + ((cg ^ (row & 7)) * 8));
      }
#pragma unroll
      for (int mi = 0; mi < 2; ++mi)
#pragma unroll
        for (int ni = 0; ni < 4; ++ni)
          acc[mi][ni] = __builtin_amdgcn_mfma_f32_16x16x32_bf16(
              aF[mi], bF[ni], acc[mi][ni], 0, 0, 0);
    }
  }

  const bool hasb = (bias != nullptr);
#pragma unroll
  for (int mi = 0; mi < 2; ++mi) {
#pragma unroll
    for (int ni = 0; ni < 4; ++ni) {
      const int n = n0 + ni * 16 + r15;
      const float bv = hasb ? bias[n] : 0.f;
#pragma unroll
      for (int r = 0; r < 4; ++r) {
        const int m = m0 + mi * 64 + w * 16 + quad * 4 + r;
        C[(long)m * ldc + n] = f2bf(acc[mi][ni][r] + bv);
      }
    }
  }
}

// heT[z] = edge_w[e] @ h[b]^T : M=256 N=1024 K=256, grid 640 (20z x 2m x 16n)
__global__ __launch_bounds__(256)
void heT_k(const __hip_bfloat16* __restrict__ wbf,
           const __hip_bfloat16* __restrict__ hbf,
           __hip_bfloat16* __restrict__ heT)
{
  __shared__ __align__(16) __hip_bfloat16 sA[128 * 64];
  const int bid = blockIdx.x;
  const int z = bid >> 5, rem = bid & 31;
  const int m0 = (rem & 1) * 128, n0 = (rem >> 1) * 64;
  tile128bd(sA, threadIdx.x,
            wbf + 65536 + (z % 5) * 65536, 256,
            hbf + (long)(z / 5) * 262144, 256,
            nullptr, heT + (long)z * 262144, 1024, 256, m0, n0);
}

// part[z] = adj[z] @ he[z] (640 blk) || gh = h @ w_hh^T + b_hh (384 blk)
__global__ __launch_bounds__(256)
void part_gh(const __hip_bfloat16* __restrict__ adjb,
             const __hip_bfloat16* __restrict__ heT,
             __hip_bfloat16* __restrict__ part,
             const __hip_bfloat16* __restrict__ hbf,
             const __hip_bfloat16* __restrict__ whh,
             const float* __restrict__ bhh,
             __hip_bfloat16* __restrict__ gh)
{
  __shared__ __align__(16) __hip_bfloat16 sA[128 * 64];
  const int bid = blockIdx.x;
  if (bid < 640) {
    const int z = bid >> 5, rem = bid & 31;
    tile128bd(sA, threadIdx.x,
              adjb + (long)z * 1048576, 1024,
              heT + (long)z * 262144, 1024,
              nullptr, part + (long)z * 262144, 256, 1024,
              (rem & 7) * 128, (rem >> 3) * 64);
  } else {
    const int idx = bid - 640;
    tile128bd(sA, threadIdx.x, hbf, 256, whh, 256, bhh, gh, 768, 256,
              (idx & 31) * 128, (idx >> 5) * 64);
  }
}

// ---------------------------------------------------------------------------
// gi + GRU gate fused. A = sum_e part (LDS-staged sum5); B = w_ih rows
// {n, 256+n, 512+n} loaded direct from global. Epilogue applies torch-GRUCell
// gates [r,z,n], writes h in-place (+node_states on final step).
// Grid 256: m0=(bid&63)*64, n0=(bid>>6)*64. LDS 8KB.
// ---------------------------------------------------------------------------
__global__ __launch_bounds__(256)
void gi_gate(const __hip_bfloat16* __restrict__ part,
             const __hip_bfloat16* __restrict__ wih,
             const float* __restrict__ biasgi,
             const __hip_bfloat16* __restrict__ gh,
             __hip_bfloat16* __restrict__ hbf,
             void* __restrict__ ns_out, const int* __restrict__ flag)
{
  __shared__ __align__(16) __hip_bfloat16 sA[64 * 64];
  const int t = threadIdx.x;
  const int w = t >> 6;
  const int l = t & 63;
  const int m0 = (blockIdx.x & 63) * 64;
  const int n0 = (blockIdx.x >> 6) * 64;

  const int p0 = t, p1 = t + 256;
  const int sr0 = p0 >> 3, sc0 = (p0 & 7) ^ (sr0 & 7);
  const int sr1 = p1 >> 3, sc1 = (p1 & 7) ^ (sr1 & 7);

  f32x4 acc[3][4];
#pragma unroll
  for (int g = 0; g < 3; ++g)
#pragma unroll
    for (int j = 0; j < 4; ++j) acc[g][j] = (f32x4){0.f, 0.f, 0.f, 0.f};

  const int mrow = w * 16 + (l & 15);
  const int r15 = l & 15;
  const int quad = l >> 4;

  // per-lane B row bases for the 3 gates x 4 n-frags
  const __hip_bfloat16* Brow[3][4];
#pragma unroll
  for (int g = 0; g < 3; ++g)
#pragma unroll
    for (int ni = 0; ni < 4; ++ni)
      Brow[g][ni] = wih + (long)(g * 256 + n0 + ni * 16 + r15) * 256;

  for (int k0 = 0; k0 < 256; k0 += 64) {
    bf16x8 a0 = ld8_sum5(part, m0 + sr0, k0 + sc0 * 8);
    bf16x8 a1 = ld8_sum5(part, m0 + sr1, k0 + sc1 * 8);
    __syncthreads();
    *(bf16x8*)(sA + p0 * 8) = a0;
    *(bf16x8*)(sA + p1 * 8) = a1;
    __syncthreads();
#pragma unroll
    for (int ks = 0; ks < 2; ++ks) {
      const int cg = ks * 4 + quad;
      bf16x8 af = *(const bf16x8*)(sA + mrow * 64 + ((cg ^ (mrow & 7)) * 8));
#pragma unroll
      for (int t4 = 0; t4 < 4; ++t4) {
        bf16x8 b0f = *(const bf16x8*)(Brow[0][t4] + k0 + cg * 8);
        bf16x8 b1f = *(const bf16x8*)(Brow[1][t4] + k0 + cg * 8);
        bf16x8 b2f = *(const bf16x8*)(Brow[2][t4] + k0 + cg * 8);
        acc[0][t4] = __builtin_amdgcn_mfma_f32_16x16x32_bf16(af, b0f, acc[0][t4], 0, 0, 0);
        acc[1][t4] = __builtin_amdgcn_mfma_f32_16x16x32_bf16(af, b1f, acc[1][t4], 0, 0, 0);
        acc[2][t4] = __builtin_amdgcn_mfma_f32_16x16x32_bf16(af, b2f, acc[2][t4], 0, 0, 0);
      }
    }
  }

  const bool f32out = ns_out && (*flag != 0);
#pragma unroll
  for (int t4 = 0; t4 < 4; ++t4) {
    const int n = n0 + t4 * 16 + r15;
    const float bgr = biasgi[n];
    const float bgz = biasgi[256 + n];
    const float bgn = biasgi[512 + n];
#pragma unroll
    for (int r = 0; r < 4; ++r) {
      const int m = m0 + w * 16 + quad * 4 + r;
      const long gb = (long)m * 768;
      const float ir = acc[0][t4][r] + bgr;
      const float iz = acc[1][t4][r] + bgz;
      const float inn = acc[2][t4][r] + bgn;
      const float hr = bf2f(gh[gb + n]);
      const float hz = bf2f(gh[gb + 256 + n]);
      const float hn = bf2f(gh[gb + 512 + n]);
      const long hidx = (long)m * 256 + n;
      const float h = bf2f(hbf[hidx]);
      const float rr = 1.f / (1.f + __expf(-(ir + hr)));
      const float zz = 1.f / (1.f + __expf(-(iz + hz)));
      const float nn = tanhf(inn + rr * hn);
      const float hnew = (1.f - zz) * nn + zz * h;
      const __hip_bfloat16 hb = f2bf(hnew);
      hbf[hidx] = hb;
      if (ns_out) {
        if (f32out) ((float*)ns_out)[1024 + hidx] = hnew;
        else        ((__hip_bfloat16*)ns_out)[1024 + hidx] = hb;
      }
    }
  }
}

// OUT_MODE: 0=bf16 C; 1=fp32 C.  A_MODE: 0=internal bf16, 1=external (flag
// dtype), 2=sum-of-5-bf16-slices.  DUAL: z>=zSplit switches to 2nd set.
// (h-init + non-adjb fallback paths)
template<int OUT_MODE, bool HAS_BIAS, int A_MODE, bool DUAL>
__global__ __launch_bounds__(256)
void gemm_bt(const void* __restrict__ A, const __hip_bfloat16* __restrict__ Bt,
             const float* __restrict__ bias, void* __restrict__ Cp,
             const void* __restrict__ A2, const __hip_bfloat16* __restrict__ Bt2,
             const float* __restrict__ bias2, void* __restrict__ Cp2,
             const int* __restrict__ flag,
             int Kg, int ngrp, int lda, int ldb, int ldc,
             long aBatch, int zdivA, int zmodA,
             long bBatch, int zdivB, int zmodB,
             long cBatch, int zdivC, long aGrp, long bGrp, int zSplit)
{
  __shared__ __align__(16) __hip_bfloat16 sA[64 * 64];
  __shared__ __align__(16) __hip_bfloat16 sB[64 * 64];
  const bool af32 = (A_MODE == 1) ? (*flag != 0) : false;
  const int t = threadIdx.x;
  const int w = t >> 6;
  const int l = t & 63;
  const int m0 = blockIdx.x * 64;
  const int n0 = blockIdx.y * 64;
  int z = blockIdx.z;

  const void* Au = A; const __hip_bfloat16* Btu = Bt;
  const float* biasu = bias; void* Cpu = Cp;
  bool second = false;
  if (DUAL && z >= zSplit) {
    Au = A2; Btu = Bt2; biasu = bias2; Cpu = Cp2; z -= zSplit; second = true;
  }

  const long aOff = (long)((z / zdivA) % zmodA) * aBatch;
  const __hip_bfloat16* Bb = Btu + (long)((z / zdivB) % zmodB) * bBatch;

  const int p0 = t, p1 = t + 256;
  const int sr0 = p0 >> 3, sc0 = (p0 & 7) ^ (sr0 & 7);
  const int sr1 = p1 >> 3, sc1 = (p1 & 7) ^ (sr1 & 7);

  f32x4 acc[4];
#pragma unroll
  for (int i = 0; i < 4; ++i) acc[i] = (f32x4){0.f, 0.f, 0.f, 0.f};

  const int mrow = w * 16 + (l & 15);
  const int quad = l >> 4;

  for (int g = 0; g < ngrp; ++g) {
    const long aG = aOff + (long)g * aGrp;
    const __hip_bfloat16* Bg = Bb + (long)g * bGrp;
    for (int k0 = 0; k0 < Kg; k0 += 64) {
      bf16x8 a0, a1;
      if (A_MODE == 2 && !second) {
        a0 = ld8_sum5((const __hip_bfloat16*)Au, m0 + sr0, k0 + sc0 * 8);
        a1 = ld8_sum5((const __hip_bfloat16*)Au, m0 + sr1, k0 + sc1 * 8);
      } else if (A_MODE == 1) {
        a0 = ld8_ext(Au, aG + (long)(m0 + sr0) * lda + (k0 + sc0 * 8), af32);
        a1 = ld8_ext(Au, aG + (long)(m0 + sr1) * lda + (k0 + sc1 * 8), af32);
      } else {
        const __hip_bfloat16* Ab = (const __hip_bfloat16*)Au;
        a0 = *(const bf16x8*)(Ab + aG + (long)(m0 + sr0) * lda + (k0 + sc0 * 8));
        a1 = *(const bf16x8*)(Ab + aG + (long)(m0 + sr1) * lda + (k0 + sc1 * 8));
      }
      bf16x8 b0 = *(const bf16x8*)(Bg + (long)(n0 + sr0) * ldb + (k0 + sc0 * 8));
      bf16x8 b1 = *(const bf16x8*)(Bg + (long)(n0 + sr1) * ldb + (k0 + sc1 * 8));
      __syncthreads();
      *(bf16x8*)(sA + p0 * 8) = a0;
      *(bf16x8*)(sA + p1 * 8) = a1;
      *(bf16x8*)(sB + p0 * 8) = b0;
      *(bf16x8*)(sB + p1 * 8) = b1;
      __syncthreads();
#pragma unroll
      for (int ks = 0; ks < 2; ++ks) {
        const int cg = ks * 4 + quad;
        bf16x8 af = *(const bf16x8*)(sA + mrow * 64 + ((cg ^ (mrow & 7)) * 8));
#pragma unroll
        for (int t4 = 0; t4 < 4; ++t4) {
          const int nrow = t4 * 16 + (l & 15);
          bf16x8 bfr = *(const bf16x8*)(sB + nrow * 64 + ((cg ^ (nrow & 7)) * 8));
          acc[t4] = __builtin_amdgcn_mfma_f32_16x16x32_bf16(af, bfr, acc[t4], 0, 0, 0);
        }
      }
    }
  }

  const long cOff = (long)(z / zdivC) * cBatch;
#pragma unroll
  for (int t4 = 0; t4 < 4; ++t4) {
    const int n = n0 + t4 * 16 + (l & 15);
    float bv = 0.f;
    if (HAS_BIAS) bv = biasu[n];
#pragma unroll
    for (int r = 0; r < 4; ++r) {
      const int m = m0 + w * 16 + quad * 4 + r;
      const float v = acc[t4][r] + bv;
      if (OUT_MODE == 0)
        ((__hip_bfloat16*)Cpu)[cOff + (long)m * ldc + n] = f2bf(v);
      else
        ((float*)Cpu)[cOff + (long)m * ldc + n] = v;
    }
  }
}

// torch GRUCell gates [r,z,n] (fallback paths only)
__global__ void gru_gate8(const __hip_bfloat16* __restrict__ gi,
                          const __hip_bfloat16* __restrict__ gh,
                          __hip_bfloat16* __restrict__ hbf,
                          void* __restrict__ ns_out, const int* __restrict__ flag)
{
  const int t = blockIdx.x * 256 + threadIdx.x;  // 0..131071
  const int m = t >> 5;                          // row 0..4095
  const int k = (t & 31) * 8;                    // 0..255 step 8
  const long gb = (long)m * 768 + k;
  bf16x8 vir = *(const bf16x8*)(gi + gb);
  bf16x8 viz = *(const bf16x8*)(gi + gb + 256);
  bf16x8 vin = *(const bf16x8*)(gi + gb + 512);
  bf16x8 vhr = *(const bf16x8*)(gh + gb);
  bf16x8 vhz = *(const bf16x8*)(gh + gb + 256);
  bf16x8 vhn = *(const bf16x8*)(gh + gb + 512);
  const long hidx = (long)m * 256 + k;
  bf16x8 vh = *(const bf16x8*)(hbf + hidx);
  bf16x8 out;
  float hf[8];
#pragma unroll
  for (int j = 0; j < 8; ++j) {
    const float r = 1.f / (1.f + __expf(-(s2f(vir[j]) + s2f(vhr[j]))));
    const float zz = 1.f / (1.f + __expf(-(s2f(viz[j]) + s2f(vhz[j]))));
    const float nn = tanhf(s2f(vin[j]) + r * s2f(vhn[j]));
    hf[j] = (1.f - zz) * nn + zz * s2f(vh[j]);
    out[j] = f2bs(hf[j]);
  }
  *(bf16x8*)(hbf + hidx) = out;
  if (ns_out) {
    if (*flag) {
      float* o = (float*)ns_out + 1024 + hidx;
#pragma unroll
      for (int j = 0; j < 8; ++j) o[j] = hf[j];
    } else {
      *(bf16x8*)((__hip_bfloat16*)ns_out + 1024 + hidx) = out;
    }
  }
}

// fused output epilogue, B-direct (c1w/c2w fragments from global). LDS 8KB+.
__global__ __launch_bounds__(256)
void conv_fused(const __hip_bfloat16* __restrict__ hbf,
                const __hip_bfloat16* __restrict__ c1w,
                const __hip_bfloat16* __restrict__ c2w,
                const float* __restrict__ pool,
                float* __restrict__ geg, float* __restrict__ am32)
{
  __shared__ __align__(16) __hip_bfloat16 sA[64 * 64];
  __shared__ float sge[64];
  __shared__ float sam[64];
  const int t = threadIdx.x, w = t >> 6, l = t & 63;
  const int m0 = blockIdx.x * 64, n0 = blockIdx.y * 64;
  if (t < 64) { sge[t] = 0.f; sam[t] = 0.f; }
  const int p0 = t, p1 = t + 256;
  const int sr0 = p0 >> 3, sc0 = (p0 & 7) ^ (sr0 & 7);
  const int sr1 = p1 >> 3, sc1 = (p1 & 7) ^ (sr1 & 7);
  f32x4 a1[4], a2[4];
#pragma unroll
  for (int i = 0; i < 4; ++i) { a1[i] = (f32x4){0,0,0,0}; a2[i] = (f32x4){0,0,0,0}; }
  const int mrow = w * 16 + (l & 15);
  const int r15 = l & 15;
  const int quad = l >> 4;
  const __hip_bfloat16* B1row[4];
  const __hip_bfloat16* B2row[4];
#pragma unroll
  for (int ni = 0; ni < 4; ++ni) {
    B1row[ni] = c1w + (long)(n0 + ni * 16 + r15) * 256;
    B2row[ni] = c2w + (long)(n0 + ni * 16 + r15) * 256;
  }
  for (int k0 = 0; k0 < 256; k0 += 64) {
    bf16x8 va0 = *(const bf16x8*)(hbf + (long)(m0 + sr0) * 256 + (k0 + sc0 * 8));
    bf16x8 va1 = *(const bf16x8*)(hbf + (long)(m0 + sr1) * 256 + (k0 + sc1 * 8));
    __syncthreads();
    *(bf16x8*)(sA + p0 * 8) = va0;
    *(bf16x8*)(sA + p1 * 8) = va1;
    __syncthreads();
#pragma unroll
    for (int ks = 0; ks < 2; ++ks) {
      const int cg = ks * 4 + quad;
      bf16x8 af = *(const bf16x8*)(sA + mrow * 64 + ((cg ^ (mrow & 7)) * 8));
#pragma unroll
      for (int t4 = 0; t4 < 4; ++t4) {
        bf16x8 b1f = *(const bf16x8*)(B1row[t4] + k0 + cg * 8);
        bf16x8 b2f = *(const bf16x8*)(B2row[t4] + k0 + cg * 8);
        a1[t4] = __builtin_amdgcn_mfma_f32_16x16x32_bf16(af, b1f, a1[t4], 0, 0, 0);
        a2[t4] = __builtin_amdgcn_mfma_f32_16x16x32_bf16(af, b2f, a2[t4], 0, 0, 0);
      }
    }
  }
  float asum[4] = {0.f, 0.f, 0.f, 0.f};
#pragma unroll
  for (int t4 = 0; t4 < 4; ++t4) {
    const int n = n0 + t4 * 16 + (l & 15);
    const float bb1 = pool[1792 + n], bb2 = pool[2048 + n];
    float g = 0.f;
#pragma unroll
    for (int r = 0; r < 4; ++r) {
      const float av = 1.f / (1.f + __expf(-(a1[t4][r] + bb1)));
      const float fv = tanhf(a2[t4][r] + bb2);
      g += av * fv;
      asum[r] += av;
    }
    atomicAdd(&sge[t4 * 16 + (l & 15)], g);
  }
#pragma unroll
  for (int r = 0; r < 4; ++r) atomicAdd(&sam[w * 16 + quad * 4 + r], asum[r]);
  __syncthreads();
  if (t < 64) atomicAdd(&geg[(m0 >> 10) * 256 + n0 + t], sge[t]);
  else if (t < 128) atomicAdd(&am32[m0 + (t - 64)], sam[t - 64]);
}

__global__ void finish_out(const float* __restrict__ ge, const float* __restrict__ am32,
                           void* __restrict__ dout, const int* __restrict__ flag)
{
  const int t = blockIdx.x * 256 + threadIdx.x;   // 0..5119
  const bool f32 = (*flag != 0);
  if (t < 1024) {
    if (f32) ((float*)dout)[t] = ge[t];
    else     ((__hip_bfloat16*)dout)[t] = f2bf(ge[t]);
  } else {
    const float v = am32[t - 1024] * (1.f / 256.f);
    if (f32) ((float*)dout)[1049600 + t - 1024] = v;
    else     ((__hip_bfloat16*)dout)[1049600 + t - 1024] = f2bf(v);
  }
}

extern "C" void kernel_launch(void* const* d_in, const int* in_sizes, int n_in,
                              void* d_out, int out_size, void* d_ws, size_t ws_size,
                              hipStream_t stream) {
  (void)in_sizes; (void)n_in; (void)out_size;
  const void* node_f = d_in[0];
  const void* adj    = d_in[1];
  const void* fc_w   = d_in[2];
  const void* fc_b   = d_in[3];
  const void* edge_w = d_in[4];
  const void* edge_b = d_in[5];
  const void* w_ih   = d_in[6];
  const void* w_hh   = d_in[7];
  const void* b_ih   = d_in[8];
  const void* b_hh   = d_in[9];
  const void* c1w    = d_in[10];
  const void* c1b    = d_in[11];
  const void* c2w    = d_in[12];
  const void* c2b    = d_in[13];

  // ws layout:
  //  [0,4) flag | [256, 13568) pool (3328 f) | [14336, 18432) ge (1024 f)
  //  [18432, 34816) am32 (4096 f) | [34816, ..) wbf 1.75M | [1869824, ..) hbf 2M
  //  S = ws+3966976: heT [0,10M) | part [10M,20M) | gi(fallback) [20M,26M) |
  //  gh [26M,32M)   adjb @ ws+40MiB (40 MiB)
  char* ws = (char*)d_ws;
  const size_t MB = (size_t)1 << 20;
  int*            flag = (int*)(ws);
  float*          bp   = (float*)(ws + 256);
  float*          ge   = (float*)(ws + 14336);
  float*          am32 = (float*)(ws + 18432);
  __hip_bfloat16* wbf  = (__hip_bfloat16*)(ws + 34816);
  __hip_bfloat16* hbf  = (__hip_bfloat16*)(ws + 1869824);
  char*           S    = ws + 3966976;
  __hip_bfloat16* heT  = (__hip_bfloat16*)(S);
  __hip_bfloat16* part = (__hip_bfloat16*)(S + 10 * MB);
  __hip_bfloat16* gi   = (__hip_bfloat16*)(S + 20 * MB);   // fallback only
  __hip_bfloat16* gh   = (__hip_bfloat16*)(S + 26 * MB);
  __hip_bfloat16* adjb = (__hip_bfloat16*)(ws + 40 * MB);

  const bool has_split = ws_size >= 38 * MB;   // part/gi/gh fit
  const bool has_adjb  = ws_size >= 81 * MB;   // adjb fits

  detect_dtype<<<1, 256, 0, stream>>>((const uint32_t*)adj, flag);
  prep_pool<<<1, 256, 0, stream>>>(fc_b, b_ih, b_hh, c1b, c2b, edge_b, flag, bp, ge, am32);
  wcvt_all<<<3584, 256, 0, stream>>>(fc_w, edge_w, w_ih, w_hh, c1w, c2w, flag, wbf);
  bias_gi_k<<<3, 256, 0, stream>>>(bp, wbf + 393216, bp + 2560);
  if (has_adjb) adj_cvt<<<10240, 256, 0, stream>>>(adj, flag, adjb);

  // h = X @ fc_w^T + fc_b  (external, possibly fp32 A -> 64^2 path)
  gemm_bt<0, true, 1, false><<<dim3(64, 4, 1), 256, 0, stream>>>(
      node_f, wbf + 0, bp + 0, hbf, nullptr, nullptr, nullptr, nullptr, flag,
      256, 1, 256, 256, 256, 0, 1, 1, 0, 1, 1, 0, 1, 0, 0, 0);

  for (int s = 0; s < 5; ++s) {
    if (has_adjb) {
      heT_k<<<640, 256, 0, stream>>>(wbf, hbf, heT);
      part_gh<<<1024, 256, 0, stream>>>(adjb, heT, part,
                                        hbf, wbf + 589824, bp + 1024, gh);
      gi_gate<<<256, 256, 0, stream>>>(part, wbf + 393216, bp + 2560, gh, hbf,
                                       (s == 4) ? d_out : nullptr, flag);
    } else if (has_split) {
      gemm_bt<0, false, 0, false><<<dim3(4, 16, 20), 256, 0, stream>>>(
          wbf + 65536, hbf, nullptr, heT, nullptr, nullptr, nullptr, nullptr, flag,
          256, 1, 256, 256, 1024,
          65536, 1, 5, 262144, 5, 4,
          262144, 1, 0, 0, 0);
      gemm_bt<0, false, 1, false><<<dim3(16, 4, 20), 256, 0, stream>>>(
          adj, heT, nullptr, part, nullptr, nullptr, nullptr, nullptr, flag,
          1024, 1, 1024, 1024, 256,
          1048576, 1, 20, 262144, 1, 20,
          262144, 1, 0, 0, 0);
      gemm_bt<0, true, 2, true><<<dim3(64, 12, 2), 256, 0, stream>>>(
          part, wbf + 393216, bp + 2560, gi,
          hbf,  wbf + 589824, bp + 1024, gh, flag,
          256, 1, 256, 256, 768, 0, 1, 1, 0, 1, 1, 0, 1, 0, 0, 1);
      gru_gate8<<<512, 256, 0, stream>>>(gi, gh, hbf,
                                         (s == 4) ? d_out : nullptr, flag);
    } else {
      gemm_bt<0, false, 0, false><<<dim3(4, 16, 20), 256, 0, stream>>>(
          wbf + 65536, hbf, nullptr, heT, nullptr, nullptr, nullptr, nullptr, flag,
          256, 1, 256, 256, 1024,
          65536, 1, 5, 262144, 5, 4,
          262144, 1, 0, 0, 0);
      gemm_bt<0, true, 1, false><<<dim3(16, 4, 4), 256, 0, stream>>>(
          adj, heT, bp + 2304, part, nullptr, nullptr, nullptr, nullptr, flag,
          1024, 5, 1024, 1024, 256,
          (long)5 * 1048576, 1, 4, (long)5 * 262144, 1, 4,
          262144, 1, 1048576, 262144, 0);
      gemm_bt<0, true, 0, true><<<dim3(64, 12, 2), 256, 0, stream>>>(
          part, wbf + 393216, bp + 256, gi,
          hbf,  wbf + 589824, bp + 1024, gh, flag,
          256, 1, 256, 256, 768, 0, 1, 1, 0, 1, 1, 0, 1, 0, 0, 1);
      gru_gate8<<<512, 256, 0, stream>>>(gi, gh, hbf,
                                         (s == 4) ? d_out : nullptr, flag);
    }
  }

  conv_fused<<<dim3(64, 4), 256, 0, stream>>>(hbf, wbf + 786432, wbf + 851968,
                                              bp, ge, am32);
  finish_out<<<20, 256, 0, stream>>>(ge, am32, d_out, flag);
}

// Round 7
// 487.653 us; speedup vs baseline: 3.1157x; 1.3585x over previous
//
#include <hip/hip_runtime.h>
#include <hip/hip_bf16.h>
#include <cstdint>

// GGNN encoder, B=4, N=1024, DIN=D=256, E=5, STEP=5. Inputs fp32 (sniffed).
// Round 15: revert to round-3 structure (best, 430us; all tile bodies
// verbatim) + dispatch-count squeeze: one pre_all kernel (adj_cvt + wcvt +
// pool + bias_gi, per-block local dtype sniff) and finish folded into
// conv_fused via last-block atomic counter. 18 dispatches (was 24).
// r6 B-direct reverted (latency-bound: MfmaUtil 7%, all pipes idle);
// r5 coop-kernel reverted (grid.sync forced HBM refetch).

typedef __attribute__((ext_vector_type(8))) short bf16x8;
typedef __attribute__((ext_vector_type(4))) float f32x4;

__device__ __forceinline__ float bf2f(__hip_bfloat16 x) { return __bfloat162float(x); }
__device__ __forceinline__ __hip_bfloat16 f2bf(float x) { return __float2bfloat16(x); }
__device__ __forceinline__ short f2bs(float x) {
  __hip_bfloat16 h = __float2bfloat16(x);
  return *reinterpret_cast<short*>(&h);
}
__device__ __forceinline__ float s2f(short x) {
  __hip_bfloat16 h = *reinterpret_cast<__hip_bfloat16*>(&x);
  return __bfloat162float(h);
}

__device__ __forceinline__ bf16x8 ld8_ext(const void* base, long off, bool f32) {
  if (f32) {
    const float* p = (const float*)base + off;
    bf16x8 r;
#pragma unroll
    for (int i = 0; i < 8; ++i) r[i] = f2bs(p[i]);
    return r;
  }
  return *(const bf16x8*)((const __hip_bfloat16*)base + off);
}

// sum of 5 bf16 part slices: part[(b*5+e)][1024][256], row = b*1024+node
__device__ __forceinline__ bf16x8 ld8_sum5(const __hip_bfloat16* part, int row, int k) {
  const long base = (long)row * 256 + (long)(row >> 10) * 1048576 + k;
  float s[8] = {0.f, 0.f, 0.f, 0.f, 0.f, 0.f, 0.f, 0.f};
#pragma unroll
  for (int e = 0; e < 5; ++e) {
    bf16x8 v = *(const bf16x8*)(part + base + e * 262144);
#pragma unroll
    for (int j = 0; j < 8; ++j) s[j] += s2f(v[j]);
  }
  bf16x8 r;
#pragma unroll
  for (int j = 0; j < 8; ++j) r[j] = f2bs(s[j]);
  return r;
}

// per-block dtype sniff (same classifier as the old detect_dtype kernel)
__device__ __forceinline__ bool sniff_f32(const uint32_t* __restrict__ raw, int t) {
  __shared__ int scnt;
  if (t == 0) scnt = 0;
  __syncthreads();
  int c = 0;
  for (int i = t; i < 512; i += 256) {
    uint32_t byte = (raw[i] >> 8) & 0xFF;
    if (byte >= 0x28 && byte <= 0x40) ++c;
  }
  atomicAdd(&scnt, c);
  __syncthreads();
  return scnt < 300;
}

// ---------------------------------------------------------------------------
// pre_all: one dispatch for adj_cvt (nAdj blocks) + wcvt (3584) + pool/zero
// (1) + bias_gi (3). Every block derives the dtype flag locally from adj's
// first 2KB (identical data -> identical answer); block nAdj+3584 also
// publishes it to *flag and zeroes ge/am32/done-counter.
// fp32 pool: [0:256) fc_b | [256:1024) b_ih | [1024:1792) b_hh | [1792:2048)
// conv1_b | [2048:2304) conv2_b | [2304:2560) sum_e edge_b | [2560:3328) bias_gi
// ---------------------------------------------------------------------------
__global__ void pre_all(const uint32_t* __restrict__ adjraw,
                        const void* fcb, const void* bih, const void* bhh,
                        const void* c1b, const void* c2b, const void* edgeb,
                        const void* fcw, const void* edw, const void* wih,
                        const void* whh, const void* c1w, const void* c2w,
                        int* __restrict__ flag, float* __restrict__ pool,
                        float* __restrict__ ge, float* __restrict__ am32,
                        int* __restrict__ done,
                        __hip_bfloat16* __restrict__ wbf,
                        __hip_bfloat16* __restrict__ adjb, int nAdj)
{
  const int t = threadIdx.x;
  const bool f32 = sniff_f32(adjraw, t);
  const int bid = blockIdx.x;

  if (bid < nAdj) {               // adj -> internal bf16, 8 elems/thread
    const long i = ((long)bid * 256 + t) * 8;
    bf16x8 r;
    if (f32) {
      const float* p = (const float*)adjraw + i;
#pragma unroll
      for (int j = 0; j < 8; ++j) r[j] = f2bs(p[j]);
    } else {
      r = *(const bf16x8*)((const __hip_bfloat16*)adjraw + i);
    }
    *(bf16x8*)(adjb + i) = r;
    return;
  }
  const int r = bid - nAdj;
  if (r < 3584) {                 // weight ingest, 1 elem/thread
    const int i = r * 256 + t;
    const void* src; int off;
    if      (i < 65536)  { src = fcw; off = i; }
    else if (i < 393216) { src = edw; off = i - 65536; }
    else if (i < 589824) { src = wih; off = i - 393216; }
    else if (i < 786432) { src = whh; off = i - 589824; }
    else if (i < 851968) { src = c1w; off = i - 786432; }
    else                 { src = c2w; off = i - 851968; }
    wbf[i] = f32 ? f2bf(((const float*)src)[off])
                 : ((const __hip_bfloat16*)src)[off];
    return;
  }
  if (r == 3584) {                // pool + zero ge/am32/done + publish flag
    if (t == 0) { *flag = f32 ? 1 : 0; *done = 0; }
    for (int i = t; i < 2560; i += 256) {
      const void* p; int k;
      if (i < 256)       { p = fcb;  k = i; }
      else if (i < 1024) { p = bih;  k = i - 256; }
      else if (i < 1792) { p = bhh;  k = i - 1024; }
      else if (i < 2048) { p = c1b;  k = i - 1792; }
      else if (i < 2304) { p = c2b;  k = i - 2048; }
      else {
        int kk = i - 2304; float s = 0.f;
        for (int e = 0; e < 5; ++e)
          s += f32 ? ((const float*)edgeb)[e * 256 + kk]
                   : bf2f(((const __hip_bfloat16*)edgeb)[e * 256 + kk]);
        pool[i] = s; continue;
      }
      pool[i] = f32 ? ((const float*)p)[k] : bf2f(((const __hip_bfloat16*)p)[k]);
    }
    for (int i = t; i < 1024; i += 256) ge[i] = 0.f;
    for (int i = t; i < 4096; i += 256) am32[i] = 0.f;
    return;
  }
  // r in [3585, 3588): bias_gi[n] = b_ih[n] + sum_k seb[k]*w_ih[n][k]
  __shared__ float seb[256];
  {
    float s0 = 0.f;
    for (int e = 0; e < 5; ++e)
      s0 += f32 ? ((const float*)edgeb)[e * 256 + t]
                : bf2f(((const __hip_bfloat16*)edgeb)[e * 256 + t]);
    seb[t] = s0;
  }
  __syncthreads();
  const int n = (r - 3585) * 256 + t;     // 0..767
  float s = f32 ? ((const float*)bih)[n] : bf2f(((const __hip_bfloat16*)bih)[n]);
  for (int k = 0; k < 256; ++k) {
    const float w = f32 ? ((const float*)wih)[n * 256 + k]
                        : bf2f(((const __hip_bfloat16*)wih)[n * 256 + k]);
    s += seb[k] * w;
  }
  pool[2560 + n] = s;
}

// ---------------------------------------------------------------------------
// 128x64-tile bf16 GEMM (round-3 verbatim): reg-staged, XOR-swizzled LDS.
// ---------------------------------------------------------------------------
template<bool HAS_BIAS, bool DUAL>
__global__ __launch_bounds__(256)
void gemm_bt128(const __hip_bfloat16* __restrict__ A, const __hip_bfloat16* __restrict__ Bt,
                const float* __restrict__ bias, __hip_bfloat16* __restrict__ C,
                const __hip_bfloat16* __restrict__ A2, const __hip_bfloat16* __restrict__ Bt2,
                const float* __restrict__ bias2, __hip_bfloat16* __restrict__ C2,
                int K, int lda, int ldb, int ldc,
                long aBatch, int zdivA, int zmodA,
                long bBatch, int zdivB, int zmodB,
                long cBatch, int zdivC, int zSplit)
{
  __shared__ __align__(16) __hip_bfloat16 sA[128 * 64];
  __shared__ __align__(16) __hip_bfloat16 sB[64 * 64];
  const int t = threadIdx.x;
  const int w = t >> 6;
  const int l = t & 63;
  const int m0 = blockIdx.x * 128;
  const int n0 = blockIdx.y * 64;
  int z = blockIdx.z;

  const __hip_bfloat16* Au = A; const __hip_bfloat16* Btu = Bt;
  const float* biasu = bias; __hip_bfloat16* Cu = C;
  if (DUAL && z >= zSplit) { Au = A2; Btu = Bt2; biasu = bias2; Cu = C2; z -= zSplit; }

  const __hip_bfloat16* Ab = Au + (long)((z / zdivA) % zmodA) * aBatch;
  const __hip_bfloat16* Bb = Btu + (long)((z / zdivB) % zmodB) * bBatch;

  int sra[4], sca[4];
#pragma unroll
  for (int i = 0; i < 4; ++i) {
    const int p = t + 256 * i;
    sra[i] = p >> 3;
    sca[i] = (p & 7) ^ (sra[i] & 7);
  }
  const int p0 = t, p1 = t + 256;
  const int sr0 = p0 >> 3, sc0 = (p0 & 7) ^ (sr0 & 7);
  const int sr1 = p1 >> 3, sc1 = (p1 & 7) ^ (sr1 & 7);

  f32x4 acc[2][4];
#pragma unroll
  for (int i = 0; i < 2; ++i)
#pragma unroll
    for (int j = 0; j < 4; ++j) acc[i][j] = (f32x4){0.f, 0.f, 0.f, 0.f};

  const int r15 = l & 15;
  const int quad = l >> 4;

  for (int k0 = 0; k0 < K; k0 += 64) {
    bf16x8 av[4];
#pragma unroll
    for (int i = 0; i < 4; ++i)
      av[i] = *(const bf16x8*)(Ab + (long)(m0 + sra[i]) * lda + (k0 + sca[i] * 8));
    bf16x8 b0 = *(const bf16x8*)(Bb + (long)(n0 + sr0) * ldb + (k0 + sc0 * 8));
    bf16x8 b1 = *(const bf16x8*)(Bb + (long)(n0 + sr1) * ldb + (k0 + sc1 * 8));
    __syncthreads();
#pragma unroll
    for (int i = 0; i < 4; ++i) *(bf16x8*)(sA + (t + 256 * i) * 8) = av[i];
    *(bf16x8*)(sB + p0 * 8) = b0;
    *(bf16x8*)(sB + p1 * 8) = b1;
    __syncthreads();
#pragma unroll
    for (int ks = 0; ks < 2; ++ks) {
      const int cg = ks * 4 + quad;
      bf16x8 aF[2], bF[4];
#pragma unroll
      for (int mi = 0; mi < 2; ++mi) {
        const int row = mi * 64 + w * 16 + r15;
        aF[mi] = *(const bf16x8*)(sA + row * 64 + ((cg ^ (row & 7)) * 8));
      }
#pragma unroll
      for (int ni = 0; ni < 4; ++ni) {
        const int nrow = ni * 16 + r15;
        bF[ni] = *(const bf16x8*)(sB + nrow * 64 + ((cg ^ (nrow & 7)) * 8));
      }
#pragma unroll
      for (int mi = 0; mi < 2; ++mi)
#pragma unroll
        for (int ni = 0; ni < 4; ++ni)
          acc[mi][ni] = __builtin_amdgcn_mfma_f32_16x16x32_bf16(
              aF[mi], bF[ni], acc[mi][ni], 0, 0, 0);
    }
  }

  const long cOff = (long)(z / zdivC) * cBatch;
#pragma unroll
  for (int mi = 0; mi < 2; ++mi) {
#pragma unroll
    for (int ni = 0; ni < 4; ++ni) {
      const int n = n0 + ni * 16 + r15;
      float bv = 0.f;
      if (HAS_BIAS) bv = biasu[n];
#pragma unroll
      for (int r = 0; r < 4; ++r) {
        const int m = m0 + mi * 64 + w * 16 + quad * 4 + r;
        Cu[cOff + (long)m * ldc + n] = f2bf(acc[mi][ni][r] + bv);
      }
    }
  }
}

// part || gh packed dispatch (round-3 verbatim), 1024 blocks of 128x64.
__global__ __launch_bounds__(256)
void part_gh(const __hip_bfloat16* __restrict__ adjb,
             const __hip_bfloat16* __restrict__ heT,
             __hip_bfloat16* __restrict__ part,
             const __hip_bfloat16* __restrict__ hbf,
             const __hip_bfloat16* __restrict__ whh,
             const float* __restrict__ bhh,
             __hip_bfloat16* __restrict__ gh)
{
  __shared__ __align__(16) __hip_bfloat16 sA[128 * 64];
  __shared__ __align__(16) __hip_bfloat16 sB[64 * 64];
  const int t = threadIdx.x;
  const int w = t >> 6;
  const int l = t & 63;
  const int bid = blockIdx.x;

  const __hip_bfloat16* Ab; const __hip_bfloat16* Bb;
  __hip_bfloat16* Cu; const float* biasu = nullptr;
  int K, lda, ldb, ldc, m0, n0;
  bool has_bias;
  if (bid < 640) {
    const int z = bid >> 5, rem = bid & 31;
    m0 = (rem & 7) * 128; n0 = (rem >> 3) * 64;
    Ab = adjb + (long)z * 1048576; lda = 1024; K = 1024;
    Bb = heT + (long)z * 262144;  ldb = 1024;
    Cu = part + (long)z * 262144; ldc = 256;
    has_bias = false;
  } else {
    const int idx = bid - 640;
    m0 = (idx & 31) * 128; n0 = (idx >> 5) * 64;
    Ab = hbf; lda = 256; K = 256;
    Bb = whh; ldb = 256;
    Cu = gh;  ldc = 768;
    biasu = bhh; has_bias = true;
  }

  int sra[4], sca[4];
#pragma unroll
  for (int i = 0; i < 4; ++i) {
    const int p = t + 256 * i;
    sra[i] = p >> 3;
    sca[i] = (p & 7) ^ (sra[i] & 7);
  }
  const int p0 = t, p1 = t + 256;
  const int sr0 = p0 >> 3, sc0 = (p0 & 7) ^ (sr0 & 7);
  const int sr1 = p1 >> 3, sc1 = (p1 & 7) ^ (sr1 & 7);

  f32x4 acc[2][4];
#pragma unroll
  for (int i = 0; i < 2; ++i)
#pragma unroll
    for (int j = 0; j < 4; ++j) acc[i][j] = (f32x4){0.f, 0.f, 0.f, 0.f};

  const int r15 = l & 15;
  const int quad = l >> 4;

  for (int k0 = 0; k0 < K; k0 += 64) {
    bf16x8 av[4];
#pragma unroll
    for (int i = 0; i < 4; ++i)
      av[i] = *(const bf16x8*)(Ab + (long)(m0 + sra[i]) * lda + (k0 + sca[i] * 8));
    bf16x8 b0 = *(const bf16x8*)(Bb + (long)(n0 + sr0) * ldb + (k0 + sc0 * 8));
    bf16x8 b1 = *(const bf16x8*)(Bb + (long)(n0 + sr1) * ldb + (k0 + sc1 * 8));
    __syncthreads();
#pragma unroll
    for (int i = 0; i < 4; ++i) *(bf16x8*)(sA + (t + 256 * i) * 8) = av[i];
    *(bf16x8*)(sB + p0 * 8) = b0;
    *(bf16x8*)(sB + p1 * 8) = b1;
    __syncthreads();
#pragma unroll
    for (int ks = 0; ks < 2; ++ks) {
      const int cg = ks * 4 + quad;
      bf16x8 aF[2], bF[4];
#pragma unroll
      for (int mi = 0; mi < 2; ++mi) {
        const int row = mi * 64 + w * 16 + r15;
        aF[mi] = *(const bf16x8*)(sA + row * 64 + ((cg ^ (row & 7)) * 8));
      }
#pragma unroll
      for (int ni = 0; ni < 4; ++ni) {
        const int nrow = ni * 16 + r15;
        bF[ni] = *(const bf16x8*)(sB + nrow * 64 + ((cg ^ (nrow & 7)) * 8));
      }
#pragma unroll
      for (int mi = 0; mi < 2; ++mi)
#pragma unroll
        for (int ni = 0; ni < 4; ++ni)
          acc[mi][ni] = __builtin_amdgcn_mfma_f32_16x16x32_bf16(
              aF[mi], bF[ni], acc[mi][ni], 0, 0, 0);
    }
  }

#pragma unroll
  for (int mi = 0; mi < 2; ++mi) {
#pragma unroll
    for (int ni = 0; ni < 4; ++ni) {
      const int n = n0 + ni * 16 + r15;
      const float bv = has_bias ? biasu[n] : 0.f;
#pragma unroll
      for (int r = 0; r < 4; ++r) {
        const int m = m0 + mi * 64 + w * 16 + quad * 4 + r;
        Cu[(long)m * ldc + n] = f2bf(acc[mi][ni][r] + bv);
      }
    }
  }
}

// gi + GRU gate fused (round-3 verbatim): 64x64 3-gate GEMM, sum5 A staging,
// epilogue applies torch-GRUCell gates and writes h in-place.
__global__ __launch_bounds__(256)
void gi_gate(const __hip_bfloat16* __restrict__ part,
             const __hip_bfloat16* __restrict__ wih,
             const float* __restrict__ biasgi,
             const __hip_bfloat16* __restrict__ gh,
             __hip_bfloat16* __restrict__ hbf,
             void* __restrict__ ns_out, const int* __restrict__ flag)
{
  __shared__ __align__(16) __hip_bfloat16 sA[64 * 64];
  __shared__ __align__(16) __hip_bfloat16 sB0[64 * 64];
  __shared__ __align__(16) __hip_bfloat16 sB1[64 * 64];
  __shared__ __align__(16) __hip_bfloat16 sB2[64 * 64];
  const int t = threadIdx.x;
  const int w = t >> 6;
  const int l = t & 63;
  const int m0 = (blockIdx.x & 63) * 64;
  const int n0 = (blockIdx.x >> 6) * 64;

  const int p0 = t, p1 = t + 256;
  const int sr0 = p0 >> 3, sc0 = (p0 & 7) ^ (sr0 & 7);
  const int sr1 = p1 >> 3, sc1 = (p1 & 7) ^ (sr1 & 7);

  f32x4 acc[3][4];
#pragma unroll
  for (int g = 0; g < 3; ++g)
#pragma unroll
    for (int j = 0; j < 4; ++j) acc[g][j] = (f32x4){0.f, 0.f, 0.f, 0.f};

  const int mrow = w * 16 + (l & 15);
  const int r15 = l & 15;
  const int quad = l >> 4;

  for (int k0 = 0; k0 < 256; k0 += 64) {
    bf16x8 a0 = ld8_sum5(part, m0 + sr0, k0 + sc0 * 8);
    bf16x8 a1 = ld8_sum5(part, m0 + sr1, k0 + sc1 * 8);
    bf16x8 bg[3][2];
#pragma unroll
    for (int g = 0; g < 3; ++g) {
      bg[g][0] = *(const bf16x8*)(wih + (long)(g * 256 + n0 + sr0) * 256 + (k0 + sc0 * 8));
      bg[g][1] = *(const bf16x8*)(wih + (long)(g * 256 + n0 + sr1) * 256 + (k0 + sc1 * 8));
    }
    __syncthreads();
    *(bf16x8*)(sA + p0 * 8) = a0;
    *(bf16x8*)(sA + p1 * 8) = a1;
    *(bf16x8*)(sB0 + p0 * 8) = bg[0][0]; *(bf16x8*)(sB0 + p1 * 8) = bg[0][1];
    *(bf16x8*)(sB1 + p0 * 8) = bg[1][0]; *(bf16x8*)(sB1 + p1 * 8) = bg[1][1];
    *(bf16x8*)(sB2 + p0 * 8) = bg[2][0]; *(bf16x8*)(sB2 + p1 * 8) = bg[2][1];
    __syncthreads();
#pragma unroll
    for (int ks = 0; ks < 2; ++ks) {
      const int cg = ks * 4 + quad;
      bf16x8 af = *(const bf16x8*)(sA + mrow * 64 + ((cg ^ (mrow & 7)) * 8));
#pragma unroll
      for (int t4 = 0; t4 < 4; ++t4) {
        const int nrow = t4 * 16 + r15;
        const int so = nrow * 64 + ((cg ^ (nrow & 7)) * 8);
        bf16x8 b0f = *(const bf16x8*)(sB0 + so);
        bf16x8 b1f = *(const bf16x8*)(sB1 + so);
        bf16x8 b2f = *(const bf16x8*)(sB2 + so);
        acc[0][t4] = __builtin_amdgcn_mfma_f32_16x16x32_bf16(af, b0f, acc[0][t4], 0, 0, 0);
        acc[1][t4] = __builtin_amdgcn_mfma_f32_16x16x32_bf16(af, b1f, acc[1][t4], 0, 0, 0);
        acc[2][t4] = __builtin_amdgcn_mfma_f32_16x16x32_bf16(af, b2f, acc[2][t4], 0, 0, 0);
      }
    }
  }

  const bool f32out = ns_out && (*flag != 0);
#pragma unroll
  for (int t4 = 0; t4 < 4; ++t4) {
    const int n = n0 + t4 * 16 + r15;
    const float bgr = biasgi[n];
    const float bgz = biasgi[256 + n];
    const float bgn = biasgi[512 + n];
#pragma unroll
    for (int r = 0; r < 4; ++r) {
      const int m = m0 + w * 16 + quad * 4 + r;
      const long gb = (long)m * 768;
      const float ir = acc[0][t4][r] + bgr;
      const float iz = acc[1][t4][r] + bgz;
      const float inn = acc[2][t4][r] + bgn;
      const float hr = bf2f(gh[gb + n]);
      const float hz = bf2f(gh[gb + 256 + n]);
      const float hn = bf2f(gh[gb + 512 + n]);
      const long hidx = (long)m * 256 + n;
      const float h = bf2f(hbf[hidx]);
      const float rr = 1.f / (1.f + __expf(-(ir + hr)));
      const float zz = 1.f / (1.f + __expf(-(iz + hz)));
      const float nn = tanhf(inn + rr * hn);
      const float hnew = (1.f - zz) * nn + zz * h;
      const __hip_bfloat16 hb = f2bf(hnew);
      hbf[hidx] = hb;
      if (ns_out) {
        if (f32out) ((float*)ns_out)[1024 + hidx] = hnew;
        else        ((__hip_bfloat16*)ns_out)[1024 + hidx] = hb;
      }
    }
  }
}

// generic 64^2 GEMM (h-init + non-adjb fallbacks; round-3 verbatim)
template<int OUT_MODE, bool HAS_BIAS, int A_MODE, bool DUAL>
__global__ __launch_bounds__(256)
void gemm_bt(const void* __restrict__ A, const __hip_bfloat16* __restrict__ Bt,
             const float* __restrict__ bias, void* __restrict__ Cp,
             const void* __restrict__ A2, const __hip_bfloat16* __restrict__ Bt2,
             const float* __restrict__ bias2, void* __restrict__ Cp2,
             const int* __restrict__ flag,
             int Kg, int ngrp, int lda, int ldb, int ldc,
             long aBatch, int zdivA, int zmodA,
             long bBatch, int zdivB, int zmodB,
             long cBatch, int zdivC, long aGrp, long bGrp, int zSplit)
{
  __shared__ __align__(16) __hip_bfloat16 sA[64 * 64];
  __shared__ __align__(16) __hip_bfloat16 sB[64 * 64];
  const bool af32 = (A_MODE == 1) ? (*flag != 0) : false;
  const int t = threadIdx.x;
  const int w = t >> 6;
  const int l = t & 63;
  const int m0 = blockIdx.x * 64;
  const int n0 = blockIdx.y * 64;
  int z = blockIdx.z;

  const void* Au = A; const __hip_bfloat16* Btu = Bt;
  const float* biasu = bias; void* Cpu = Cp;
  bool second = false;
  if (DUAL && z >= zSplit) {
    Au = A2; Btu = Bt2; biasu = bias2; Cpu = Cp2; z -= zSplit; second = true;
  }

  const long aOff = (long)((z / zdivA) % zmodA) * aBatch;
  const __hip_bfloat16* Bb = Btu + (long)((z / zdivB) % zmodB) * bBatch;

  const int p0 = t, p1 = t + 256;
  const int sr0 = p0 >> 3, sc0 = (p0 & 7) ^ (sr0 & 7);
  const int sr1 = p1 >> 3, sc1 = (p1 & 7) ^ (sr1 & 7);

  f32x4 acc[4];
#pragma unroll
  for (int i = 0; i < 4; ++i) acc[i] = (f32x4){0.f, 0.f, 0.f, 0.f};

  const int mrow = w * 16 + (l & 15);
  const int quad = l >> 4;

  for (int g = 0; g < ngrp; ++g) {
    const long aG = aOff + (long)g * aGrp;
    const __hip_bfloat16* Bg = Bb + (long)g * bGrp;
    for (int k0 = 0; k0 < Kg; k0 += 64) {
      bf16x8 a0, a1;
      if (A_MODE == 2 && !second) {
        a0 = ld8_sum5((const __hip_bfloat16*)Au, m0 + sr0, k0 + sc0 * 8);
        a1 = ld8_sum5((const __hip_bfloat16*)Au, m0 + sr1, k0 + sc1 * 8);
      } else if (A_MODE == 1) {
        a0 = ld8_ext(Au, aG + (long)(m0 + sr0) * lda + (k0 + sc0 * 8), af32);
        a1 = ld8_ext(Au, aG + (long)(m0 + sr1) * lda + (k0 + sc1 * 8), af32);
      } else {
        const __hip_bfloat16* Ab = (const __hip_bfloat16*)Au;
        a0 = *(const bf16x8*)(Ab + aG + (long)(m0 + sr0) * lda + (k0 + sc0 * 8));
        a1 = *(const bf16x8*)(Ab + aG + (long)(m0 + sr1) * lda + (k0 + sc1 * 8));
      }
      bf16x8 b0 = *(const bf16x8*)(Bg + (long)(n0 + sr0) * ldb + (k0 + sc0 * 8));
      bf16x8 b1 = *(const bf16x8*)(Bg + (long)(n0 + sr1) * ldb + (k0 + sc1 * 8));
      __syncthreads();
      *(bf16x8*)(sA + p0 * 8) = a0;
      *(bf16x8*)(sA + p1 * 8) = a1;
      *(bf16x8*)(sB + p0 * 8) = b0;
      *(bf16x8*)(sB + p1 * 8) = b1;
      __syncthreads();
#pragma unroll
      for (int ks = 0; ks < 2; ++ks) {
        const int cg = ks * 4 + quad;
        bf16x8 af = *(const bf16x8*)(sA + mrow * 64 + ((cg ^ (mrow & 7)) * 8));
#pragma unroll
        for (int t4 = 0; t4 < 4; ++t4) {
          const int nrow = t4 * 16 + (l & 15);
          bf16x8 bfr = *(const bf16x8*)(sB + nrow * 64 + ((cg ^ (nrow & 7)) * 8));
          acc[t4] = __builtin_amdgcn_mfma_f32_16x16x32_bf16(af, bfr, acc[t4], 0, 0, 0);
        }
      }
    }
  }

  const long cOff = (long)(z / zdivC) * cBatch;
#pragma unroll
  for (int t4 = 0; t4 < 4; ++t4) {
    const int n = n0 + t4 * 16 + (l & 15);
    float bv = 0.f;
    if (HAS_BIAS) bv = biasu[n];
#pragma unroll
    for (int r = 0; r < 4; ++r) {
      const int m = m0 + w * 16 + quad * 4 + r;
      const float v = acc[t4][r] + bv;
      if (OUT_MODE == 0)
        ((__hip_bfloat16*)Cpu)[cOff + (long)m * ldc + n] = f2bf(v);
      else
        ((float*)Cpu)[cOff + (long)m * ldc + n] = v;
    }
  }
}

// torch GRUCell gates [r,z,n] (fallback paths only)
__global__ void gru_gate8(const __hip_bfloat16* __restrict__ gi,
                          const __hip_bfloat16* __restrict__ gh,
                          __hip_bfloat16* __restrict__ hbf,
                          void* __restrict__ ns_out, const int* __restrict__ flag)
{
  const int t = blockIdx.x * 256 + threadIdx.x;  // 0..131071
  const int m = t >> 5;
  const int k = (t & 31) * 8;
  const long gb = (long)m * 768 + k;
  bf16x8 vir = *(const bf16x8*)(gi + gb);
  bf16x8 viz = *(const bf16x8*)(gi + gb + 256);
  bf16x8 vin = *(const bf16x8*)(gi + gb + 512);
  bf16x8 vhr = *(const bf16x8*)(gh + gb);
  bf16x8 vhz = *(const bf16x8*)(gh + gb + 256);
  bf16x8 vhn = *(const bf16x8*)(gh + gb + 512);
  const long hidx = (long)m * 256 + k;
  bf16x8 vh = *(const bf16x8*)(hbf + hidx);
  bf16x8 out;
  float hf[8];
#pragma unroll
  for (int j = 0; j < 8; ++j) {
    const float r = 1.f / (1.f + __expf(-(s2f(vir[j]) + s2f(vhr[j]))));
    const float zz = 1.f / (1.f + __expf(-(s2f(viz[j]) + s2f(vhz[j]))));
    const float nn = tanhf(s2f(vin[j]) + r * s2f(vhn[j]));
    hf[j] = (1.f - zz) * nn + zz * s2f(vh[j]);
    out[j] = f2bs(hf[j]);
  }
  *(bf16x8*)(hbf + hidx) = out;
  if (ns_out) {
    if (*flag) {
      float* o = (float*)ns_out + 1024 + hidx;
#pragma unroll
      for (int j = 0; j < 8; ++j) o[j] = hf[j];
    } else {
      *(bf16x8*)((__hip_bfloat16*)ns_out + 1024 + hidx) = out;
    }
  }
}

// fused output epilogue (round-3 conv body) + merged finish via last-block
// atomic counter (ge/am32 read back with coherent atomic-adds of 0).
__global__ __launch_bounds__(256)
void conv_fin(const __hip_bfloat16* __restrict__ hbf,
              const __hip_bfloat16* __restrict__ c1w,
              const __hip_bfloat16* __restrict__ c2w,
              const float* __restrict__ pool,
              float* __restrict__ geg, float* __restrict__ am32,
              int* __restrict__ done, void* __restrict__ dout,
              const int* __restrict__ flag)
{
  __shared__ __align__(16) __hip_bfloat16 sA[64 * 64];
  __shared__ __align__(16) __hip_bfloat16 sB1[64 * 64];
  __shared__ __align__(16) __hip_bfloat16 sB2[64 * 64];
  __shared__ float sge[64];
  __shared__ float sam[64];
  __shared__ int amLast;
  const int t = threadIdx.x, w = t >> 6, l = t & 63;
  const int m0 = blockIdx.x * 64, n0 = blockIdx.y * 64;
  if (t < 64) { sge[t] = 0.f; sam[t] = 0.f; }
  const int p0 = t, p1 = t + 256;
  const int sr0 = p0 >> 3, sc0 = (p0 & 7) ^ (sr0 & 7);
  const int sr1 = p1 >> 3, sc1 = (p1 & 7) ^ (sr1 & 7);
  f32x4 a1[4], a2[4];
#pragma unroll
  for (int i = 0; i < 4; ++i) { a1[i] = (f32x4){0,0,0,0}; a2[i] = (f32x4){0,0,0,0}; }
  const int mrow = w * 16 + (l & 15);
  const int quad = l >> 4;
  for (int k0 = 0; k0 < 256; k0 += 64) {
    bf16x8 va0 = *(const bf16x8*)(hbf + (long)(m0 + sr0) * 256 + (k0 + sc0 * 8));
    bf16x8 va1 = *(const bf16x8*)(hbf + (long)(m0 + sr1) * 256 + (k0 + sc1 * 8));
    bf16x8 vb0 = *(const bf16x8*)(c1w + (long)(n0 + sr0) * 256 + (k0 + sc0 * 8));
    bf16x8 vb1 = *(const bf16x8*)(c1w + (long)(n0 + sr1) * 256 + (k0 + sc1 * 8));
    bf16x8 vc0 = *(const bf16x8*)(c2w + (long)(n0 + sr0) * 256 + (k0 + sc0 * 8));
    bf16x8 vc1 = *(const bf16x8*)(c2w + (long)(n0 + sr1) * 256 + (k0 + sc1 * 8));
    __syncthreads();
    *(bf16x8*)(sA + p0 * 8) = va0;  *(bf16x8*)(sA + p1 * 8) = va1;
    *(bf16x8*)(sB1 + p0 * 8) = vb0; *(bf16x8*)(sB1 + p1 * 8) = vb1;
    *(bf16x8*)(sB2 + p0 * 8) = vc0; *(bf16x8*)(sB2 + p1 * 8) = vc1;
    __syncthreads();
#pragma unroll
    for (int ks = 0; ks < 2; ++ks) {
      const int cg = ks * 4 + quad;
      bf16x8 af = *(const bf16x8*)(sA + mrow * 64 + ((cg ^ (mrow & 7)) * 8));
#pragma unroll
      for (int t4 = 0; t4 < 4; ++t4) {
        const int nrow = t4 * 16 + (l & 15);
        bf16x8 b1f = *(const bf16x8*)(sB1 + nrow * 64 + ((cg ^ (nrow & 7)) * 8));
        bf16x8 b2f = *(const bf16x8*)(sB2 + nrow * 64 + ((cg ^ (nrow & 7)) * 8));
        a1[t4] = __builtin_amdgcn_mfma_f32_16x16x32_bf16(af, b1f, a1[t4], 0, 0, 0);
        a2[t4] = __builtin_amdgcn_mfma_f32_16x16x32_bf16(af, b2f, a2[t4], 0, 0, 0);
      }
    }
  }
  float asum[4] = {0.f, 0.f, 0.f, 0.f};
#pragma unroll
  for (int t4 = 0; t4 < 4; ++t4) {
    const int n = n0 + t4 * 16 + (l & 15);
    const float bb1 = pool[1792 + n], bb2 = pool[2048 + n];
    float g = 0.f;
#pragma unroll
    for (int r = 0; r < 4; ++r) {
      const float av = 1.f / (1.f + __expf(-(a1[t4][r] + bb1)));
      const float fv = tanhf(a2[t4][r] + bb2);
      g += av * fv;
      asum[r] += av;
    }
    atomicAdd(&sge[t4 * 16 + (l & 15)], g);
  }
#pragma unroll
  for (int r = 0; r < 4; ++r) atomicAdd(&sam[w * 16 + quad * 4 + r], asum[r]);
  __syncthreads();
  if (t < 64) atomicAdd(&geg[(m0 >> 10) * 256 + n0 + t], sge[t]);
  else if (t < 128) atomicAdd(&am32[m0 + (t - 64)], sam[t - 64]);

  // merged finish: last block writes dout
  __threadfence();
  __syncthreads();
  if (t == 0) amLast = (atomicAdd(done, 1) == 255) ? 1 : 0;
  __syncthreads();
  if (amLast) {
    const bool f32 = (*flag != 0);
    for (int i = t; i < 5120; i += 256) {
      if (i < 1024) {
        const float v = atomicAdd(&geg[i], 0.f);
        if (f32) ((float*)dout)[i] = v;
        else     ((__hip_bfloat16*)dout)[i] = f2bf(v);
      } else {
        const float v = atomicAdd(&am32[i - 1024], 0.f) * (1.f / 256.f);
        if (f32) ((float*)dout)[1049600 + i - 1024] = v;
        else     ((__hip_bfloat16*)dout)[1049600 + i - 1024] = f2bf(v);
      }
    }
  }
}

extern "C" void kernel_launch(void* const* d_in, const int* in_sizes, int n_in,
                              void* d_out, int out_size, void* d_ws, size_t ws_size,
                              hipStream_t stream) {
  (void)in_sizes; (void)n_in; (void)out_size;
  const void* node_f = d_in[0];
  const void* adj    = d_in[1];
  const void* fc_w   = d_in[2];
  const void* fc_b   = d_in[3];
  const void* edge_w = d_in[4];
  const void* edge_b = d_in[5];
  const void* w_ih   = d_in[6];
  const void* w_hh   = d_in[7];
  const void* b_ih   = d_in[8];
  const void* b_hh   = d_in[9];
  const void* c1w    = d_in[10];
  const void* c1b    = d_in[11];
  const void* c2w    = d_in[12];
  const void* c2b    = d_in[13];

  // ws layout:
  //  [0,4) flag | [64,68) done | [256, 13568) pool (3328 f) | [14336, 18432) ge
  //  [18432, 34816) am32 | [34816,..) wbf 1.75M | [1869824,..) hbf 2M
  //  S = ws+3966976: heT [0,10M) | part [10M,20M) | gi(fallback) [20M,26M) |
  //  gh [26M,32M)   adjb @ ws+40MiB (40 MiB)
  char* ws = (char*)d_ws;
  const size_t MB = (size_t)1 << 20;
  int*            flag = (int*)(ws);
  int*            done = (int*)(ws + 64);
  float*          bp   = (float*)(ws + 256);
  float*          ge   = (float*)(ws + 14336);
  float*          am32 = (float*)(ws + 18432);
  __hip_bfloat16* wbf  = (__hip_bfloat16*)(ws + 34816);
  __hip_bfloat16* hbf  = (__hip_bfloat16*)(ws + 1869824);
  char*           S    = ws + 3966976;
  __hip_bfloat16* heT  = (__hip_bfloat16*)(S);
  __hip_bfloat16* part = (__hip_bfloat16*)(S + 10 * MB);
  __hip_bfloat16* gi   = (__hip_bfloat16*)(S + 20 * MB);   // fallback only
  __hip_bfloat16* gh   = (__hip_bfloat16*)(S + 26 * MB);
  __hip_bfloat16* adjb = (__hip_bfloat16*)(ws + 40 * MB);

  const bool has_split = ws_size >= 38 * MB;   // part/gi/gh fit
  const bool has_adjb  = ws_size >= 81 * MB;   // adjb fits

  const int nAdj = has_adjb ? 10240 : 0;
  pre_all<<<nAdj + 3588, 256, 0, stream>>>(
      (const uint32_t*)adj, fc_b, b_ih, b_hh, c1b, c2b, edge_b,
      fc_w, edge_w, w_ih, w_hh, c1w, c2w,
      flag, bp, ge, am32, done, wbf, adjb, nAdj);

  // h = X @ fc_w^T + fc_b  (external, possibly fp32 A -> 64^2 path)
  gemm_bt<0, true, 1, false><<<dim3(64, 4, 1), 256, 0, stream>>>(
      node_f, wbf + 0, bp + 0, hbf, nullptr, nullptr, nullptr, nullptr, flag,
      256, 1, 256, 256, 256, 0, 1, 1, 0, 1, 1, 0, 1, 0, 0, 0);

  for (int s = 0; s < 5; ++s) {
    if (has_adjb) {
      // heT[b,e][d][node] = edge_w[e] @ h[b]^T : M=256 N=1024 K=256, z=(b,e)
      gemm_bt128<false, false><<<dim3(2, 16, 20), 256, 0, stream>>>(
          wbf + 65536, hbf, nullptr, heT, nullptr, nullptr, nullptr, nullptr,
          256, 256, 256, 1024,
          65536, 1, 5,
          262144, 5, 4,
          262144, 1, 0);
      // part[b,e] = adj @ he  ||  gh = h @ w_hh^T + b_hh   (one dispatch)
      part_gh<<<1024, 256, 0, stream>>>(adjb, heT, part,
                                        hbf, wbf + 589824, bp + 1024, gh);
      // gi (= sum_e part @ w_ih^T + bias_gi) + GRU gates, h updated in-place
      gi_gate<<<256, 256, 0, stream>>>(part, wbf + 393216, bp + 2560, gh, hbf,
                                       (s == 4) ? d_out : nullptr, flag);
    } else if (has_split) {
      gemm_bt<0, false, 0, false><<<dim3(4, 16, 20), 256, 0, stream>>>(
          wbf + 65536, hbf, nullptr, heT, nullptr, nullptr, nullptr, nullptr, flag,
          256, 1, 256, 256, 1024,
          65536, 1, 5, 262144, 5, 4,
          262144, 1, 0, 0, 0);
      gemm_bt<0, false, 1, false><<<dim3(16, 4, 20), 256, 0, stream>>>(
          adj, heT, nullptr, part, nullptr, nullptr, nullptr, nullptr, flag,
          1024, 1, 1024, 1024, 256,
          1048576, 1, 20, 262144, 1, 20,
          262144, 1, 0, 0, 0);
      gemm_bt<0, true, 2, true><<<dim3(64, 12, 2), 256, 0, stream>>>(
          part, wbf + 393216, bp + 2560, gi,
          hbf,  wbf + 589824, bp + 1024, gh, flag,
          256, 1, 256, 256, 768, 0, 1, 1, 0, 1, 1, 0, 1, 0, 0, 1);
      gru_gate8<<<512, 256, 0, stream>>>(gi, gh, hbf,
                                         (s == 4) ? d_out : nullptr, flag);
    } else {
      gemm_bt<0, false, 0, false><<<dim3(4, 16, 20), 256, 0, stream>>>(
          wbf + 65536, hbf, nullptr, heT, nullptr, nullptr, nullptr, nullptr, flag,
          256, 1, 256, 256, 1024,
          65536, 1, 5, 262144, 5, 4,
          262144, 1, 0, 0, 0);
      gemm_bt<0, true, 1, false><<<dim3(16, 4, 4), 256, 0, stream>>>(
          adj, heT, bp + 2304, part, nullptr, nullptr, nullptr, nullptr, flag,
          1024, 5, 1024, 1024, 256,
          (long)5 * 1048576, 1, 4, (long)5 * 262144, 1, 4,
          262144, 1, 1048576, 262144, 0);
      gemm_bt<0, true, 0, true><<<dim3(64, 12, 2), 256, 0, stream>>>(
          part, wbf + 393216, bp + 256, gi,
          hbf,  wbf + 589824, bp + 1024, gh, flag,
          256, 1, 256, 256, 768, 0, 1, 1, 0, 1, 1, 0, 1, 0, 0, 1);
      gru_gate8<<<512, 256, 0, stream>>>(gi, gh, hbf,
                                         (s == 4) ? d_out : nullptr, flag);
    }
  }

  conv_fin<<<dim3(64, 4), 256, 0, stream>>>(hbf, wbf + 786432, wbf + 851968,
                                            bp, ge, am32, done, d_out, flag);
}

// Round 9
// 435.200 us; speedup vs baseline: 3.4913x; 1.1205x over previous
//
#include <hip/hip_runtime.h>
#include <hip/hip_bf16.h>
#include <cstdint>

// GGNN encoder, B=4, N=1024, DIN=D=256, E=5, STEP=5. Inputs fp32 (sniffed).
// Round 17: resubmit of round-3 structure (measured best, 430.4us) after an
// infra-only failure (container died twice; no kernel signal). Per step:
// heT -> {part || gh} (one 1024-block dispatch) -> gi+GRU-gate fused.
// Separate pre dispatches (detect/prep/wcvt/bias_gi/adj_cvt). History:
// r15 merged pre_all +35us (sniff prologue broke streaming); r14 B-direct
// latency-bound (MfmaUtil 7%); r13 coop kernel grid.sync HBM refetch;
// r12 algebraic refactor extra FLOPs at 1 blk/CU. Tile bodies verbatim.

typedef __attribute__((ext_vector_type(8))) short bf16x8;
typedef __attribute__((ext_vector_type(4))) float f32x4;

__device__ __forceinline__ float bf2f(__hip_bfloat16 x) { return __bfloat162float(x); }
__device__ __forceinline__ __hip_bfloat16 f2bf(float x) { return __float2bfloat16(x); }
__device__ __forceinline__ short f2bs(float x) {
  __hip_bfloat16 h = __float2bfloat16(x);
  return *reinterpret_cast<short*>(&h);
}
__device__ __forceinline__ float s2f(short x) {
  __hip_bfloat16 h = *reinterpret_cast<__hip_bfloat16*>(&x);
  return __bfloat162float(h);
}

__device__ __forceinline__ bf16x8 ld8_ext(const void* base, long off, bool f32) {
  if (f32) {
    const float* p = (const float*)base + off;
    bf16x8 r;
#pragma unroll
    for (int i = 0; i < 8; ++i) r[i] = f2bs(p[i]);
    return r;
  }
  return *(const bf16x8*)((const __hip_bfloat16*)base + off);
}

// sum of 5 bf16 part slices: part[(b*5+e)][1024][256], row = b*1024+node
__device__ __forceinline__ bf16x8 ld8_sum5(const __hip_bfloat16* part, int row, int k) {
  const long base = (long)row * 256 + (long)(row >> 10) * 1048576 + k;
  float s[8] = {0.f, 0.f, 0.f, 0.f, 0.f, 0.f, 0.f, 0.f};
#pragma unroll
  for (int e = 0; e < 5; ++e) {
    bf16x8 v = *(const bf16x8*)(part + base + e * 262144);
#pragma unroll
    for (int j = 0; j < 8; ++j) s[j] += s2f(v[j]);
  }
  bf16x8 r;
#pragma unroll
  for (int j = 0; j < 8; ++j) r[j] = f2bs(s[j]);
  return r;
}

// ---- dtype sniffer: flag = 1 if inputs are fp32, 0 if bf16 ----
__global__ void detect_dtype(const uint32_t* __restrict__ raw, int* __restrict__ flag) {
  __shared__ int cnt;
  if (threadIdx.x == 0) cnt = 0;
  __syncthreads();
  int c = 0;
  for (int i = threadIdx.x; i < 512; i += 256) {
    uint32_t byte = (raw[i] >> 8) & 0xFF;
    if (byte >= 0x28 && byte <= 0x40) ++c;
  }
  atomicAdd(&cnt, c);
  __syncthreads();
  if (threadIdx.x == 0) *flag = (cnt < 300) ? 1 : 0;
}

// fp32 pool: [0:256) fc_b | [256:1024) b_ih | [1024:1792) b_hh | [1792:2048)
// conv1_b | [2048:2304) conv2_b | [2304:2560) sum_e edge_b | [2560:3328) bias_gi
__global__ void prep_pool(const void* fcb, const void* bih, const void* bhh,
                          const void* c1b, const void* c2b, const void* edgeb,
                          const int* __restrict__ flag,
                          float* __restrict__ pool, float* __restrict__ ge,
                          float* __restrict__ am32) {
  const bool f32 = (*flag != 0);
  for (int t = threadIdx.x; t < 2560; t += 256) {
    const void* p; int i;
    if (t < 256)       { p = fcb;  i = t; }
    else if (t < 1024) { p = bih;  i = t - 256; }
    else if (t < 1792) { p = bhh;  i = t - 1024; }
    else if (t < 2048) { p = c1b;  i = t - 1792; }
    else if (t < 2304) { p = c2b;  i = t - 2048; }
    else {
      int k = t - 2304; float s = 0.f;
      for (int e = 0; e < 5; ++e)
        s += f32 ? ((const float*)edgeb)[e * 256 + k]
                 : bf2f(((const __hip_bfloat16*)edgeb)[e * 256 + k]);
      pool[t] = s; continue;
    }
    pool[t] = f32 ? ((const float*)p)[i] : bf2f(((const __hip_bfloat16*)p)[i]);
  }
  for (int t = threadIdx.x; t < 1024; t += 256) ge[t] = 0.f;
  for (int t = threadIdx.x; t < 4096; t += 256) am32[t] = 0.f;
}

// bias_gi[n] = b_ih[n] + sum_k sum_edge_b[k] * w_ih[n][k]   (n < 768)
__global__ void bias_gi_k(const float* __restrict__ pool,
                          const __hip_bfloat16* __restrict__ wih,
                          float* __restrict__ out) {
  const int n = blockIdx.x * 256 + threadIdx.x;
  if (n >= 768) return;
  float s = pool[256 + n];
  for (int k = 0; k < 256; ++k) s += pool[2304 + k] * bf2f(wih[n * 256 + k]);
  out[n] = s;
}

// ingest all 6 weight matrices into one internal bf16 pool
__global__ void wcvt_all(const void* fcw, const void* edw, const void* wih,
                         const void* whh, const void* c1w, const void* c2w,
                         const int* __restrict__ flag, __hip_bfloat16* __restrict__ dst) {
  const bool f32 = (*flag != 0);
  const int i = blockIdx.x * 256 + threadIdx.x;   // 0..917503
  const void* src; int off;
  if      (i < 65536)  { src = fcw; off = i; }
  else if (i < 393216) { src = edw; off = i - 65536; }
  else if (i < 589824) { src = wih; off = i - 393216; }
  else if (i < 786432) { src = whh; off = i - 589824; }
  else if (i < 851968) { src = c1w; off = i - 786432; }
  else                 { src = c2w; off = i - 851968; }
  dst[i] = f32 ? f2bf(((const float*)src)[off])
               : ((const __hip_bfloat16*)src)[off];
}

// one-time adj -> internal bf16 (20,971,520 elems), 8 elems/thread
__global__ void adj_cvt(const void* __restrict__ src, const int* __restrict__ flag,
                        __hip_bfloat16* __restrict__ dst) {
  const bool f32 = (*flag != 0);
  const long i = ((long)blockIdx.x * 256 + threadIdx.x) * 8;
  bf16x8 r;
  if (f32) {
    const float* p = (const float*)src + i;
#pragma unroll
    for (int j = 0; j < 8; ++j) r[j] = f2bs(p[j]);
  } else {
    r = *(const bf16x8*)((const __hip_bfloat16*)src + i);
  }
  *(bf16x8*)(dst + i) = r;
}

// ---------------------------------------------------------------------------
// 128x64-tile bf16 GEMM, C = A @ Bt^T (+bias). Reg-staged, XOR-swizzled LDS.
// 4 waves, each 2 m-frags x 4 n-frags. Internal-bf16 operands only.
// DUAL: z>=zSplit switches to second operand set (same geometry).
// ---------------------------------------------------------------------------
template<bool HAS_BIAS, bool DUAL>
__global__ __launch_bounds__(256)
void gemm_bt128(const __hip_bfloat16* __restrict__ A, const __hip_bfloat16* __restrict__ Bt,
                const float* __restrict__ bias, __hip_bfloat16* __restrict__ C,
                const __hip_bfloat16* __restrict__ A2, const __hip_bfloat16* __restrict__ Bt2,
                const float* __restrict__ bias2, __hip_bfloat16* __restrict__ C2,
                int K, int lda, int ldb, int ldc,
                long aBatch, int zdivA, int zmodA,
                long bBatch, int zdivB, int zmodB,
                long cBatch, int zdivC, int zSplit)
{
  __shared__ __align__(16) __hip_bfloat16 sA[128 * 64];
  __shared__ __align__(16) __hip_bfloat16 sB[64 * 64];
  const int t = threadIdx.x;
  const int w = t >> 6;
  const int l = t & 63;
  const int m0 = blockIdx.x * 128;
  const int n0 = blockIdx.y * 64;
  int z = blockIdx.z;

  const __hip_bfloat16* Au = A; const __hip_bfloat16* Btu = Bt;
  const float* biasu = bias; __hip_bfloat16* Cu = C;
  if (DUAL && z >= zSplit) { Au = A2; Btu = Bt2; biasu = bias2; Cu = C2; z -= zSplit; }

  const __hip_bfloat16* Ab = Au + (long)((z / zdivA) % zmodA) * aBatch;
  const __hip_bfloat16* Bb = Btu + (long)((z / zdivB) % zmodB) * bBatch;

  int sra[4], sca[4];
#pragma unroll
  for (int i = 0; i < 4; ++i) {
    const int p = t + 256 * i;
    sra[i] = p >> 3;
    sca[i] = (p & 7) ^ (sra[i] & 7);
  }
  const int p0 = t, p1 = t + 256;
  const int sr0 = p0 >> 3, sc0 = (p0 & 7) ^ (sr0 & 7);
  const int sr1 = p1 >> 3, sc1 = (p1 & 7) ^ (sr1 & 7);

  f32x4 acc[2][4];
#pragma unroll
  for (int i = 0; i < 2; ++i)
#pragma unroll
    for (int j = 0; j < 4; ++j) acc[i][j] = (f32x4){0.f, 0.f, 0.f, 0.f};

  const int r15 = l & 15;
  const int quad = l >> 4;

  for (int k0 = 0; k0 < K; k0 += 64) {
    bf16x8 av[4];
#pragma unroll
    for (int i = 0; i < 4; ++i)
      av[i] = *(const bf16x8*)(Ab + (long)(m0 + sra[i]) * lda + (k0 + sca[i] * 8));
    bf16x8 b0 = *(const bf16x8*)(Bb + (long)(n0 + sr0) * ldb + (k0 + sc0 * 8));
    bf16x8 b1 = *(const bf16x8*)(Bb + (long)(n0 + sr1) * ldb + (k0 + sc1 * 8));
    __syncthreads();
#pragma unroll
    for (int i = 0; i < 4; ++i) *(bf16x8*)(sA + (t + 256 * i) * 8) = av[i];
    *(bf16x8*)(sB + p0 * 8) = b0;
    *(bf16x8*)(sB + p1 * 8) = b1;
    __syncthreads();
#pragma unroll
    for (int ks = 0; ks < 2; ++ks) {
      const int cg = ks * 4 + quad;
      bf16x8 aF[2], bF[4];
#pragma unroll
      for (int mi = 0; mi < 2; ++mi) {
        const int row = mi * 64 + w * 16 + r15;
        aF[mi] = *(const bf16x8*)(sA + row * 64 + ((cg ^ (row & 7)) * 8));
      }
#pragma unroll
      for (int ni = 0; ni < 4; ++ni) {
        const int nrow = ni * 16 + r15;
        bF[ni] = *(const bf16x8*)(sB + nrow * 64 + ((cg ^ (nrow & 7)) * 8));
      }
#pragma unroll
      for (int mi = 0; mi < 2; ++mi)
#pragma unroll
        for (int ni = 0; ni < 4; ++ni)
          acc[mi][ni] = __builtin_amdgcn_mfma_f32_16x16x32_bf16(
              aF[mi], bF[ni], acc[mi][ni], 0, 0, 0);
    }
  }

  const long cOff = (long)(z / zdivC) * cBatch;
#pragma unroll
  for (int mi = 0; mi < 2; ++mi) {
#pragma unroll
    for (int ni = 0; ni < 4; ++ni) {
      const int n = n0 + ni * 16 + r15;
      float bv = 0.f;
      if (HAS_BIAS) bv = biasu[n];
#pragma unroll
      for (int r = 0; r < 4; ++r) {
        const int m = m0 + mi * 64 + w * 16 + quad * 4 + r;
        Cu[cOff + (long)m * ldc + n] = f2bf(acc[mi][ni][r] + bv);
      }
    }
  }
}

// ---------------------------------------------------------------------------
// part || gh packed dispatch, 1D grid of 1024 blocks, 128x64 tile each.
//  bid <  640: part[b,e] = adj[b,e] @ heT[b,e]^T  (M=1024 N=256 K=1024)
//  bid >= 640: gh = h @ w_hh^T + b_hh             (M=4096 N=768  K=256)
// ---------------------------------------------------------------------------
__global__ __launch_bounds__(256)
void part_gh(const __hip_bfloat16* __restrict__ adjb,
             const __hip_bfloat16* __restrict__ heT,
             __hip_bfloat16* __restrict__ part,
             const __hip_bfloat16* __restrict__ hbf,
             const __hip_bfloat16* __restrict__ whh,
             const float* __restrict__ bhh,
             __hip_bfloat16* __restrict__ gh)
{
  __shared__ __align__(16) __hip_bfloat16 sA[128 * 64];
  __shared__ __align__(16) __hip_bfloat16 sB[64 * 64];
  const int t = threadIdx.x;
  const int w = t >> 6;
  const int l = t & 63;
  const int bid = blockIdx.x;

  const __hip_bfloat16* Ab; const __hip_bfloat16* Bb;
  __hip_bfloat16* Cu; const float* biasu = nullptr;
  int K, lda, ldb, ldc, m0, n0;
  bool has_bias;
  if (bid < 640) {
    const int z = bid >> 5, rem = bid & 31;
    m0 = (rem & 7) * 128; n0 = (rem >> 3) * 64;
    Ab = adjb + (long)z * 1048576; lda = 1024; K = 1024;
    Bb = heT + (long)z * 262144;  ldb = 1024;
    Cu = part + (long)z * 262144; ldc = 256;
    has_bias = false;
  } else {
    const int idx = bid - 640;
    m0 = (idx & 31) * 128; n0 = (idx >> 5) * 64;
    Ab = hbf; lda = 256; K = 256;
    Bb = whh; ldb = 256;
    Cu = gh;  ldc = 768;
    biasu = bhh; has_bias = true;
  }

  int sra[4], sca[4];
#pragma unroll
  for (int i = 0; i < 4; ++i) {
    const int p = t + 256 * i;
    sra[i] = p >> 3;
    sca[i] = (p & 7) ^ (sra[i] & 7);
  }
  const int p0 = t, p1 = t + 256;
  const int sr0 = p0 >> 3, sc0 = (p0 & 7) ^ (sr0 & 7);
  const int sr1 = p1 >> 3, sc1 = (p1 & 7) ^ (sr1 & 7);

  f32x4 acc[2][4];
#pragma unroll
  for (int i = 0; i < 2; ++i)
#pragma unroll
    for (int j = 0; j < 4; ++j) acc[i][j] = (f32x4){0.f, 0.f, 0.f, 0.f};

  const int r15 = l & 15;
  const int quad = l >> 4;

  for (int k0 = 0; k0 < K; k0 += 64) {
    bf16x8 av[4];
#pragma unroll
    for (int i = 0; i < 4; ++i)
      av[i] = *(const bf16x8*)(Ab + (long)(m0 + sra[i]) * lda + (k0 + sca[i] * 8));
    bf16x8 b0 = *(const bf16x8*)(Bb + (long)(n0 + sr0) * ldb + (k0 + sc0 * 8));
    bf16x8 b1 = *(const bf16x8*)(Bb + (long)(n0 + sr1) * ldb + (k0 + sc1 * 8));
    __syncthreads();
#pragma unroll
    for (int i = 0; i < 4; ++i) *(bf16x8*)(sA + (t + 256 * i) * 8) = av[i];
    *(bf16x8*)(sB + p0 * 8) = b0;
    *(bf16x8*)(sB + p1 * 8) = b1;
    __syncthreads();
#pragma unroll
    for (int ks = 0; ks < 2; ++ks) {
      const int cg = ks * 4 + quad;
      bf16x8 aF[2], bF[4];
#pragma unroll
      for (int mi = 0; mi < 2; ++mi) {
        const int row = mi * 64 + w * 16 + r15;
        aF[mi] = *(const bf16x8*)(sA + row * 64 + ((cg ^ (row & 7)) * 8));
      }
#pragma unroll
      for (int ni = 0; ni < 4; ++ni) {
        const int nrow = ni * 16 + r15;
        bF[ni] = *(const bf16x8*)(sB + nrow * 64 + ((cg ^ (nrow & 7)) * 8));
      }
#pragma unroll
      for (int mi = 0; mi < 2; ++mi)
#pragma unroll
        for (int ni = 0; ni < 4; ++ni)
          acc[mi][ni] = __builtin_amdgcn_mfma_f32_16x16x32_bf16(
              aF[mi], bF[ni], acc[mi][ni], 0, 0, 0);
    }
  }

#pragma unroll
  for (int mi = 0; mi < 2; ++mi) {
#pragma unroll
    for (int ni = 0; ni < 4; ++ni) {
      const int n = n0 + ni * 16 + r15;
      const float bv = has_bias ? biasu[n] : 0.f;
#pragma unroll
      for (int r = 0; r < 4; ++r) {
        const int m = m0 + mi * 64 + w * 16 + quad * 4 + r;
        Cu[(long)m * ldc + n] = f2bf(acc[mi][ni][r] + bv);
      }
    }
  }
}

// ---------------------------------------------------------------------------
// gi + GRU gate fused. 64x64-tile 3-gate GEMM over A = sum_e part (folded
// 5-slice staging), B = w_ih rows {n, 256+n, 512+n}. Epilogue reads gh & h,
// applies torch-GRUCell gates [r,z,n], writes h in-place (and node_states on
// the final step). 1D grid 256: m0=(bid&63)*64, n0=(bid>>6)*64.
// ---------------------------------------------------------------------------
__global__ __launch_bounds__(256)
void gi_gate(const __hip_bfloat16* __restrict__ part,
             const __hip_bfloat16* __restrict__ wih,
             const float* __restrict__ biasgi,
             const __hip_bfloat16* __restrict__ gh,
             __hip_bfloat16* __restrict__ hbf,
             void* __restrict__ ns_out, const int* __restrict__ flag)
{
  __shared__ __align__(16) __hip_bfloat16 sA[64 * 64];
  __shared__ __align__(16) __hip_bfloat16 sB0[64 * 64];
  __shared__ __align__(16) __hip_bfloat16 sB1[64 * 64];
  __shared__ __align__(16) __hip_bfloat16 sB2[64 * 64];
  const int t = threadIdx.x;
  const int w = t >> 6;
  const int l = t & 63;
  const int m0 = (blockIdx.x & 63) * 64;
  const int n0 = (blockIdx.x >> 6) * 64;

  const int p0 = t, p1 = t + 256;
  const int sr0 = p0 >> 3, sc0 = (p0 & 7) ^ (sr0 & 7);
  const int sr1 = p1 >> 3, sc1 = (p1 & 7) ^ (sr1 & 7);

  f32x4 acc[3][4];
#pragma unroll
  for (int g = 0; g < 3; ++g)
#pragma unroll
    for (int j = 0; j < 4; ++j) acc[g][j] = (f32x4){0.f, 0.f, 0.f, 0.f};

  const int mrow = w * 16 + (l & 15);
  const int r15 = l & 15;
  const int quad = l >> 4;

  for (int k0 = 0; k0 < 256; k0 += 64) {
    bf16x8 a0 = ld8_sum5(part, m0 + sr0, k0 + sc0 * 8);
    bf16x8 a1 = ld8_sum5(part, m0 + sr1, k0 + sc1 * 8);
    bf16x8 bg[3][2];
#pragma unroll
    for (int g = 0; g < 3; ++g) {
      bg[g][0] = *(const bf16x8*)(wih + (long)(g * 256 + n0 + sr0) * 256 + (k0 + sc0 * 8));
      bg[g][1] = *(const bf16x8*)(wih + (long)(g * 256 + n0 + sr1) * 256 + (k0 + sc1 * 8));
    }
    __syncthreads();
    *(bf16x8*)(sA + p0 * 8) = a0;
    *(bf16x8*)(sA + p1 * 8) = a1;
    *(bf16x8*)(sB0 + p0 * 8) = bg[0][0]; *(bf16x8*)(sB0 + p1 * 8) = bg[0][1];
    *(bf16x8*)(sB1 + p0 * 8) = bg[1][0]; *(bf16x8*)(sB1 + p1 * 8) = bg[1][1];
    *(bf16x8*)(sB2 + p0 * 8) = bg[2][0]; *(bf16x8*)(sB2 + p1 * 8) = bg[2][1];
    __syncthreads();
#pragma unroll
    for (int ks = 0; ks < 2; ++ks) {
      const int cg = ks * 4 + quad;
      bf16x8 af = *(const bf16x8*)(sA + mrow * 64 + ((cg ^ (mrow & 7)) * 8));
#pragma unroll
      for (int t4 = 0; t4 < 4; ++t4) {
        const int nrow = t4 * 16 + r15;
        const int so = nrow * 64 + ((cg ^ (nrow & 7)) * 8);
        bf16x8 b0f = *(const bf16x8*)(sB0 + so);
        bf16x8 b1f = *(const bf16x8*)(sB1 + so);
        bf16x8 b2f = *(const bf16x8*)(sB2 + so);
        acc[0][t4] = __builtin_amdgcn_mfma_f32_16x16x32_bf16(af, b0f, acc[0][t4], 0, 0, 0);
        acc[1][t4] = __builtin_amdgcn_mfma_f32_16x16x32_bf16(af, b1f, acc[1][t4], 0, 0, 0);
        acc[2][t4] = __builtin_amdgcn_mfma_f32_16x16x32_bf16(af, b2f, acc[2][t4], 0, 0, 0);
      }
    }
  }

  const bool f32out = ns_out && (*flag != 0);
#pragma unroll
  for (int t4 = 0; t4 < 4; ++t4) {
    const int n = n0 + t4 * 16 + r15;
    const float bgr = biasgi[n];
    const float bgz = biasgi[256 + n];
    const float bgn = biasgi[512 + n];
#pragma unroll
    for (int r = 0; r < 4; ++r) {
      const int m = m0 + w * 16 + quad * 4 + r;
      const long gb = (long)m * 768;
      const float ir = acc[0][t4][r] + bgr;
      const float iz = acc[1][t4][r] + bgz;
      const float inn = acc[2][t4][r] + bgn;
      const float hr = bf2f(gh[gb + n]);
      const float hz = bf2f(gh[gb + 256 + n]);
      const float hn = bf2f(gh[gb + 512 + n]);
      const long hidx = (long)m * 256 + n;
      const float h = bf2f(hbf[hidx]);
      const float rr = 1.f / (1.f + __expf(-(ir + hr)));
      const float zz = 1.f / (1.f + __expf(-(iz + hz)));
      const float nn = tanhf(inn + rr * hn);
      const float hnew = (1.f - zz) * nn + zz * h;
      const __hip_bfloat16 hb = f2bf(hnew);
      hbf[hidx] = hb;
      if (ns_out) {
        if (f32out) ((float*)ns_out)[1024 + hidx] = hnew;
        else        ((__hip_bfloat16*)ns_out)[1024 + hidx] = hb;
      }
    }
  }
}

// OUT_MODE: 0=bf16 C; 1=fp32 C.  A_MODE: 0=internal bf16, 1=external (flag
// dtype), 2=sum-of-5-bf16-slices (gi).  DUAL: z>=zSplit switches to 2nd set.
template<int OUT_MODE, bool HAS_BIAS, int A_MODE, bool DUAL>
__global__ __launch_bounds__(256)
void gemm_bt(const void* __restrict__ A, const __hip_bfloat16* __restrict__ Bt,
             const float* __restrict__ bias, void* __restrict__ Cp,
             const void* __restrict__ A2, const __hip_bfloat16* __restrict__ Bt2,
             const float* __restrict__ bias2, void* __restrict__ Cp2,
             const int* __restrict__ flag,
             int Kg, int ngrp, int lda, int ldb, int ldc,
             long aBatch, int zdivA, int zmodA,
             long bBatch, int zdivB, int zmodB,
             long cBatch, int zdivC, long aGrp, long bGrp, int zSplit)
{
  __shared__ __align__(16) __hip_bfloat16 sA[64 * 64];
  __shared__ __align__(16) __hip_bfloat16 sB[64 * 64];
  const bool af32 = (A_MODE == 1) ? (*flag != 0) : false;
  const int t = threadIdx.x;
  const int w = t >> 6;
  const int l = t & 63;
  const int m0 = blockIdx.x * 64;
  const int n0 = blockIdx.y * 64;
  int z = blockIdx.z;

  const void* Au = A; const __hip_bfloat16* Btu = Bt;
  const float* biasu = bias; void* Cpu = Cp;
  bool second = false;
  if (DUAL && z >= zSplit) {
    Au = A2; Btu = Bt2; biasu = bias2; Cpu = Cp2; z -= zSplit; second = true;
  }

  const long aOff = (long)((z / zdivA) % zmodA) * aBatch;
  const __hip_bfloat16* Bb = Btu + (long)((z / zdivB) % zmodB) * bBatch;

  const int p0 = t, p1 = t + 256;
  const int sr0 = p0 >> 3, sc0 = (p0 & 7) ^ (sr0 & 7);
  const int sr1 = p1 >> 3, sc1 = (p1 & 7) ^ (sr1 & 7);

  f32x4 acc[4];
#pragma unroll
  for (int i = 0; i < 4; ++i) acc[i] = (f32x4){0.f, 0.f, 0.f, 0.f};

  const int mrow = w * 16 + (l & 15);
  const int quad = l >> 4;

  for (int g = 0; g < ngrp; ++g) {
    const long aG = aOff + (long)g * aGrp;
    const __hip_bfloat16* Bg = Bb + (long)g * bGrp;
    for (int k0 = 0; k0 < Kg; k0 += 64) {
      bf16x8 a0, a1;
      if (A_MODE == 2 && !second) {
        a0 = ld8_sum5((const __hip_bfloat16*)Au, m0 + sr0, k0 + sc0 * 8);
        a1 = ld8_sum5((const __hip_bfloat16*)Au, m0 + sr1, k0 + sc1 * 8);
      } else if (A_MODE == 1) {
        a0 = ld8_ext(Au, aG + (long)(m0 + sr0) * lda + (k0 + sc0 * 8), af32);
        a1 = ld8_ext(Au, aG + (long)(m0 + sr1) * lda + (k0 + sc1 * 8), af32);
      } else {
        const __hip_bfloat16* Ab = (const __hip_bfloat16*)Au;
        a0 = *(const bf16x8*)(Ab + aG + (long)(m0 + sr0) * lda + (k0 + sc0 * 8));
        a1 = *(const bf16x8*)(Ab + aG + (long)(m0 + sr1) * lda + (k0 + sc1 * 8));
      }
      bf16x8 b0 = *(const bf16x8*)(Bg + (long)(n0 + sr0) * ldb + (k0 + sc0 * 8));
      bf16x8 b1 = *(const bf16x8*)(Bg + (long)(n0 + sr1) * ldb + (k0 + sc1 * 8));
      __syncthreads();
      *(bf16x8*)(sA + p0 * 8) = a0;
      *(bf16x8*)(sA + p1 * 8) = a1;
      *(bf16x8*)(sB + p0 * 8) = b0;
      *(bf16x8*)(sB + p1 * 8) = b1;
      __syncthreads();
#pragma unroll
      for (int ks = 0; ks < 2; ++ks) {
        const int cg = ks * 4 + quad;
        bf16x8 af = *(const bf16x8*)(sA + mrow * 64 + ((cg ^ (mrow & 7)) * 8));
#pragma unroll
        for (int t4 = 0; t4 < 4; ++t4) {
          const int nrow = t4 * 16 + (l & 15);
          bf16x8 bfr = *(const bf16x8*)(sB + nrow * 64 + ((cg ^ (nrow & 7)) * 8));
          acc[t4] = __builtin_amdgcn_mfma_f32_16x16x32_bf16(af, bfr, acc[t4], 0, 0, 0);
        }
      }
    }
  }

  const long cOff = (long)(z / zdivC) * cBatch;
#pragma unroll
  for (int t4 = 0; t4 < 4; ++t4) {
    const int n = n0 + t4 * 16 + (l & 15);
    float bv = 0.f;
    if (HAS_BIAS) bv = biasu[n];
#pragma unroll
    for (int r = 0; r < 4; ++r) {
      const int m = m0 + w * 16 + quad * 4 + r;
      const float v = acc[t4][r] + bv;
      if (OUT_MODE == 0)
        ((__hip_bfloat16*)Cpu)[cOff + (long)m * ldc + n] = f2bf(v);
      else
        ((float*)Cpu)[cOff + (long)m * ldc + n] = v;
    }
  }
}

// torch GRUCell gates [r,z,n] (fallback paths only)
__global__ void gru_gate8(const __hip_bfloat16* __restrict__ gi,
                          const __hip_bfloat16* __restrict__ gh,
                          __hip_bfloat16* __restrict__ hbf,
                          void* __restrict__ ns_out, const int* __restrict__ flag)
{
  const int t = blockIdx.x * 256 + threadIdx.x;  // 0..131071
  const int m = t >> 5;                          // row 0..4095
  const int k = (t & 31) * 8;                    // 0..255 step 8
  const long gb = (long)m * 768 + k;
  bf16x8 vir = *(const bf16x8*)(gi + gb);
  bf16x8 viz = *(const bf16x8*)(gi + gb + 256);
  bf16x8 vin = *(const bf16x8*)(gi + gb + 512);
  bf16x8 vhr = *(const bf16x8*)(gh + gb);
  bf16x8 vhz = *(const bf16x8*)(gh + gb + 256);
  bf16x8 vhn = *(const bf16x8*)(gh + gb + 512);
  const long hidx = (long)m * 256 + k;
  bf16x8 vh = *(const bf16x8*)(hbf + hidx);
  bf16x8 out;
  float hf[8];
#pragma unroll
  for (int j = 0; j < 8; ++j) {
    const float r = 1.f / (1.f + __expf(-(s2f(vir[j]) + s2f(vhr[j]))));
    const float zz = 1.f / (1.f + __expf(-(s2f(viz[j]) + s2f(vhz[j]))));
    const float nn = tanhf(s2f(vin[j]) + r * s2f(vhn[j]));
    hf[j] = (1.f - zz) * nn + zz * s2f(vh[j]);
    out[j] = f2bs(hf[j]);
  }
  *(bf16x8*)(hbf + hidx) = out;
  if (ns_out) {
    if (*flag) {
      float* o = (float*)ns_out + 1024 + hidx;
#pragma unroll
      for (int j = 0; j < 8; ++j) o[j] = hf[j];
    } else {
      *(bf16x8*)((__hip_bfloat16*)ns_out + 1024 + hidx) = out;
    }
  }
}

// fused output epilogue: per 64x64 tile compute attl & fetl via MFMA, apply
// sigmoid/tanh, reduce ge (sum over nodes) and attn row-sums via LDS+atomics.
__global__ __launch_bounds__(256)
void conv_fused(const __hip_bfloat16* __restrict__ hbf,
                const __hip_bfloat16* __restrict__ c1w,
                const __hip_bfloat16* __restrict__ c2w,
                const float* __restrict__ pool,
                float* __restrict__ geg, float* __restrict__ am32)
{
  __shared__ __align__(16) __hip_bfloat16 sA[64 * 64];
  __shared__ __align__(16) __hip_bfloat16 sB1[64 * 64];
  __shared__ __align__(16) __hip_bfloat16 sB2[64 * 64];
  __shared__ float sge[64];
  __shared__ float sam[64];
  const int t = threadIdx.x, w = t >> 6, l = t & 63;
  const int m0 = blockIdx.x * 64, n0 = blockIdx.y * 64;
  if (t < 64) { sge[t] = 0.f; sam[t] = 0.f; }
  const int p0 = t, p1 = t + 256;
  const int sr0 = p0 >> 3, sc0 = (p0 & 7) ^ (sr0 & 7);
  const int sr1 = p1 >> 3, sc1 = (p1 & 7) ^ (sr1 & 7);
  f32x4 a1[4], a2[4];
#pragma unroll
  for (int i = 0; i < 4; ++i) { a1[i] = (f32x4){0,0,0,0}; a2[i] = (f32x4){0,0,0,0}; }
  const int mrow = w * 16 + (l & 15);
  const int quad = l >> 4;
  for (int k0 = 0; k0 < 256; k0 += 64) {
    bf16x8 va0 = *(const bf16x8*)(hbf + (long)(m0 + sr0) * 256 + (k0 + sc0 * 8));
    bf16x8 va1 = *(const bf16x8*)(hbf + (long)(m0 + sr1) * 256 + (k0 + sc1 * 8));
    bf16x8 vb0 = *(const bf16x8*)(c1w + (long)(n0 + sr0) * 256 + (k0 + sc0 * 8));
    bf16x8 vb1 = *(const bf16x8*)(c1w + (long)(n0 + sr1) * 256 + (k0 + sc1 * 8));
    bf16x8 vc0 = *(const bf16x8*)(c2w + (long)(n0 + sr0) * 256 + (k0 + sc0 * 8));
    bf16x8 vc1 = *(const bf16x8*)(c2w + (long)(n0 + sr1) * 256 + (k0 + sc1 * 8));
    __syncthreads();
    *(bf16x8*)(sA + p0 * 8) = va0;  *(bf16x8*)(sA + p1 * 8) = va1;
    *(bf16x8*)(sB1 + p0 * 8) = vb0; *(bf16x8*)(sB1 + p1 * 8) = vb1;
    *(bf16x8*)(sB2 + p0 * 8) = vc0; *(bf16x8*)(sB2 + p1 * 8) = vc1;
    __syncthreads();
#pragma unroll
    for (int ks = 0; ks < 2; ++ks) {
      const int cg = ks * 4 + quad;
      bf16x8 af = *(const bf16x8*)(sA + mrow * 64 + ((cg ^ (mrow & 7)) * 8));
#pragma unroll
      for (int t4 = 0; t4 < 4; ++t4) {
        const int nrow = t4 * 16 + (l & 15);
        bf16x8 b1f = *(const bf16x8*)(sB1 + nrow * 64 + ((cg ^ (nrow & 7)) * 8));
        bf16x8 b2f = *(const bf16x8*)(sB2 + nrow * 64 + ((cg ^ (nrow & 7)) * 8));
        a1[t4] = __builtin_amdgcn_mfma_f32_16x16x32_bf16(af, b1f, a1[t4], 0, 0, 0);
        a2[t4] = __builtin_amdgcn_mfma_f32_16x16x32_bf16(af, b2f, a2[t4], 0, 0, 0);
      }
    }
  }
  float asum[4] = {0.f, 0.f, 0.f, 0.f};
#pragma unroll
  for (int t4 = 0; t4 < 4; ++t4) {
    const int n = n0 + t4 * 16 + (l & 15);
    const float bb1 = pool[1792 + n], bb2 = pool[2048 + n];
    float g = 0.f;
#pragma unroll
    for (int r = 0; r < 4; ++r) {
      const float av = 1.f / (1.f + __expf(-(a1[t4][r] + bb1)));
      const float fv = tanhf(a2[t4][r] + bb2);
      g += av * fv;
      asum[r] += av;
    }
    atomicAdd(&sge[t4 * 16 + (l & 15)], g);
  }
#pragma unroll
  for (int r = 0; r < 4; ++r) atomicAdd(&sam[w * 16 + quad * 4 + r], asum[r]);
  __syncthreads();
  if (t < 64) atomicAdd(&geg[(m0 >> 10) * 256 + n0 + t], sge[t]);
  else if (t < 128) atomicAdd(&am32[m0 + (t - 64)], sam[t - 64]);
}

__global__ void finish_out(const float* __restrict__ ge, const float* __restrict__ am32,
                           void* __restrict__ dout, const int* __restrict__ flag)
{
  const int t = blockIdx.x * 256 + threadIdx.x;   // 0..5119
  const bool f32 = (*flag != 0);
  if (t < 1024) {
    if (f32) ((float*)dout)[t] = ge[t];
    else     ((__hip_bfloat16*)dout)[t] = f2bf(ge[t]);
  } else {
    const float v = am32[t - 1024] * (1.f / 256.f);
    if (f32) ((float*)dout)[1049600 + t - 1024] = v;
    else     ((__hip_bfloat16*)dout)[1049600 + t - 1024] = f2bf(v);
  }
}

extern "C" void kernel_launch(void* const* d_in, const int* in_sizes, int n_in,
                              void* d_out, int out_size, void* d_ws, size_t ws_size,
                              hipStream_t stream) {
  (void)in_sizes; (void)n_in; (void)out_size;
  const void* node_f = d_in[0];
  const void* adj    = d_in[1];
  const void* fc_w   = d_in[2];
  const void* fc_b   = d_in[3];
  const void* edge_w = d_in[4];
  const void* edge_b = d_in[5];
  const void* w_ih   = d_in[6];
  const void* w_hh   = d_in[7];
  const void* b_ih   = d_in[8];
  const void* b_hh   = d_in[9];
  const void* c1w    = d_in[10];
  const void* c1b    = d_in[11];
  const void* c2w    = d_in[12];
  const void* c2b    = d_in[13];

  // ws layout:
  //  [0,4) flag | [256, 13568) pool (3328 f) | [14336, 18432) ge (1024 f)
  //  [18432, 34816) am32 (4096 f) | [34816, ..) wbf 1.75M | [1869824, ..) hbf 2M
  //  S = ws+3966976: heT [0,10M) | part [10M,20M) | gi(fallback) [20M,26M) |
  //  gh [26M,32M)   adjb @ ws+40MiB (40 MiB)
  char* ws = (char*)d_ws;
  const size_t MB = (size_t)1 << 20;
  int*            flag = (int*)(ws);
  float*          bp   = (float*)(ws + 256);
  float*          ge   = (float*)(ws + 14336);
  float*          am32 = (float*)(ws + 18432);
  __hip_bfloat16* wbf  = (__hip_bfloat16*)(ws + 34816);
  __hip_bfloat16* hbf  = (__hip_bfloat16*)(ws + 1869824);
  char*           S    = ws + 3966976;
  __hip_bfloat16* heT  = (__hip_bfloat16*)(S);
  __hip_bfloat16* part = (__hip_bfloat16*)(S + 10 * MB);
  __hip_bfloat16* gi   = (__hip_bfloat16*)(S + 20 * MB);   // fallback only
  __hip_bfloat16* gh   = (__hip_bfloat16*)(S + 26 * MB);
  __hip_bfloat16* adjb = (__hip_bfloat16*)(ws + 40 * MB);

  const bool has_split = ws_size >= 38 * MB;   // part/gi/gh fit
  const bool has_adjb  = ws_size >= 81 * MB;   // adjb fits

  detect_dtype<<<1, 256, 0, stream>>>((const uint32_t*)adj, flag);
  prep_pool<<<1, 256, 0, stream>>>(fc_b, b_ih, b_hh, c1b, c2b, edge_b, flag, bp, ge, am32);
  wcvt_all<<<3584, 256, 0, stream>>>(fc_w, edge_w, w_ih, w_hh, c1w, c2w, flag, wbf);
  bias_gi_k<<<3, 256, 0, stream>>>(bp, wbf + 393216, bp + 2560);
  if (has_adjb) adj_cvt<<<10240, 256, 0, stream>>>(adj, flag, adjb);

  // h = X @ fc_w^T + fc_b  (external, possibly fp32 A -> keep 64^2 path)
  gemm_bt<0, true, 1, false><<<dim3(64, 4, 1), 256, 0, stream>>>(
      node_f, wbf + 0, bp + 0, hbf, nullptr, nullptr, nullptr, nullptr, flag,
      256, 1, 256, 256, 256, 0, 1, 1, 0, 1, 1, 0, 1, 0, 0, 0);

  for (int s = 0; s < 5; ++s) {
    if (has_adjb) {
      // heT[b,e][d][node] = edge_w[e] @ h[b]^T : M=256 N=1024 K=256, z=(b,e)
      gemm_bt128<false, false><<<dim3(2, 16, 20), 256, 0, stream>>>(
          wbf + 65536, hbf, nullptr, heT, nullptr, nullptr, nullptr, nullptr,
          256, 256, 256, 1024,
          65536, 1, 5,
          262144, 5, 4,
          262144, 1, 0);
      // part[b,e] = adj @ he  ||  gh = h @ w_hh^T + b_hh   (one dispatch)
      part_gh<<<1024, 256, 0, stream>>>(adjb, heT, part,
                                        hbf, wbf + 589824, bp + 1024, gh);
      // gi (= sum_e part @ w_ih^T + bias_gi) + GRU gates, h updated in-place
      gi_gate<<<256, 256, 0, stream>>>(part, wbf + 393216, bp + 2560, gh, hbf,
                                       (s == 4) ? d_out : nullptr, flag);
    } else if (has_split) {
      gemm_bt<0, false, 0, false><<<dim3(4, 16, 20), 256, 0, stream>>>(
          wbf + 65536, hbf, nullptr, heT, nullptr, nullptr, nullptr, nullptr, flag,
          256, 1, 256, 256, 1024,
          65536, 1, 5, 262144, 5, 4,
          262144, 1, 0, 0, 0);
      gemm_bt<0, false, 1, false><<<dim3(16, 4, 20), 256, 0, stream>>>(
          adj, heT, nullptr, part, nullptr, nullptr, nullptr, nullptr, flag,
          1024, 1, 1024, 1024, 256,
          1048576, 1, 20, 262144, 1, 20,
          262144, 1, 0, 0, 0);
      gemm_bt<0, true, 2, true><<<dim3(64, 12, 2), 256, 0, stream>>>(
          part, wbf + 393216, bp + 2560, gi,
          hbf,  wbf + 589824, bp + 1024, gh, flag,
          256, 1, 256, 256, 768, 0, 1, 1, 0, 1, 1, 0, 1, 0, 0, 1);
      gru_gate8<<<512, 256, 0, stream>>>(gi, gh, hbf,
                                         (s == 4) ? d_out : nullptr, flag);
    } else {
      gemm_bt<0, false, 0, false><<<dim3(4, 16, 20), 256, 0, stream>>>(
          wbf + 65536, hbf, nullptr, heT, nullptr, nullptr, nullptr, nullptr, flag,
          256, 1, 256, 256, 1024,
          65536, 1, 5, 262144, 5, 4,
          262144, 1, 0, 0, 0);
      gemm_bt<0, true, 1, false><<<dim3(16, 4, 4), 256, 0, stream>>>(
          adj, heT, bp + 2304, part, nullptr, nullptr, nullptr, nullptr, flag,
          1024, 5, 1024, 1024, 256,
          (long)5 * 1048576, 1, 4, (long)5 * 262144, 1, 4,
          262144, 1, 1048576, 262144, 0);
      gemm_bt<0, true, 0, true><<<dim3(64, 12, 2), 256, 0, stream>>>(
          part, wbf + 393216, bp + 256, gi,
          hbf,  wbf + 589824, bp + 1024, gh, flag,
          256, 1, 256, 256, 768, 0, 1, 1, 0, 1, 1, 0, 1, 0, 0, 1);
      gru_gate8<<<512, 256, 0, stream>>>(gi, gh, hbf,
                                         (s == 4) ? d_out : nullptr, flag);
    }
  }

  conv_fused<<<dim3(64, 4), 256, 0, stream>>>(hbf, wbf + 786432, wbf + 851968,
                                              bp, ge, am32);
  finish_out<<<20, 256, 0, stream>>>(ge, am32, d_out, flag);
}

// Round 10
// 423.054 us; speedup vs baseline: 3.5915x; 1.0287x over previous
//
#include <hip/hip_runtime.h>
#include <hip/hip_bf16.h>
#include <cstdint>

// GGNN encoder, B=4, N=1024, DIN=D=256, E=5, STEP=5. Inputs fp32 (sniffed).
// Round 18: round-3 structure (repro'd 430-435us) + T1 XCD-chunked swizzle
// on part_gh's part region: lb=(bid&7)*80+(bid>>3) makes each XCD own 2.5
// complete z-slices, so the 8 m-blocks sharing a heT panel land on ONE XCD
// L2 (was: consecutive bids -> 8-way cross-XCD replication, 65.8MB FETCH).
// Bijective (640=8x80); performance-only. All else byte-identical.
// History: r15 merged-pre +35us; r14 B-direct latency-bound; r13 coop
// grid.sync HBM refetch; r12 algebra refactor; r9-10 tile variants neutral.

typedef __attribute__((ext_vector_type(8))) short bf16x8;
typedef __attribute__((ext_vector_type(4))) float f32x4;

__device__ __forceinline__ float bf2f(__hip_bfloat16 x) { return __bfloat162float(x); }
__device__ __forceinline__ __hip_bfloat16 f2bf(float x) { return __float2bfloat16(x); }
__device__ __forceinline__ short f2bs(float x) {
  __hip_bfloat16 h = __float2bfloat16(x);
  return *reinterpret_cast<short*>(&h);
}
__device__ __forceinline__ float s2f(short x) {
  __hip_bfloat16 h = *reinterpret_cast<__hip_bfloat16*>(&x);
  return __bfloat162float(h);
}

__device__ __forceinline__ bf16x8 ld8_ext(const void* base, long off, bool f32) {
  if (f32) {
    const float* p = (const float*)base + off;
    bf16x8 r;
#pragma unroll
    for (int i = 0; i < 8; ++i) r[i] = f2bs(p[i]);
    return r;
  }
  return *(const bf16x8*)((const __hip_bfloat16*)base + off);
}

// sum of 5 bf16 part slices: part[(b*5+e)][1024][256], row = b*1024+node
__device__ __forceinline__ bf16x8 ld8_sum5(const __hip_bfloat16* part, int row, int k) {
  const long base = (long)row * 256 + (long)(row >> 10) * 1048576 + k;
  float s[8] = {0.f, 0.f, 0.f, 0.f, 0.f, 0.f, 0.f, 0.f};
#pragma unroll
  for (int e = 0; e < 5; ++e) {
    bf16x8 v = *(const bf16x8*)(part + base + e * 262144);
#pragma unroll
    for (int j = 0; j < 8; ++j) s[j] += s2f(v[j]);
  }
  bf16x8 r;
#pragma unroll
  for (int j = 0; j < 8; ++j) r[j] = f2bs(s[j]);
  return r;
}

// ---- dtype sniffer: flag = 1 if inputs are fp32, 0 if bf16 ----
__global__ void detect_dtype(const uint32_t* __restrict__ raw, int* __restrict__ flag) {
  __shared__ int cnt;
  if (threadIdx.x == 0) cnt = 0;
  __syncthreads();
  int c = 0;
  for (int i = threadIdx.x; i < 512; i += 256) {
    uint32_t byte = (raw[i] >> 8) & 0xFF;
    if (byte >= 0x28 && byte <= 0x40) ++c;
  }
  atomicAdd(&cnt, c);
  __syncthreads();
  if (threadIdx.x == 0) *flag = (cnt < 300) ? 1 : 0;
}

// fp32 pool: [0:256) fc_b | [256:1024) b_ih | [1024:1792) b_hh | [1792:2048)
// conv1_b | [2048:2304) conv2_b | [2304:2560) sum_e edge_b | [2560:3328) bias_gi
__global__ void prep_pool(const void* fcb, const void* bih, const void* bhh,
                          const void* c1b, const void* c2b, const void* edgeb,
                          const int* __restrict__ flag,
                          float* __restrict__ pool, float* __restrict__ ge,
                          float* __restrict__ am32) {
  const bool f32 = (*flag != 0);
  for (int t = threadIdx.x; t < 2560; t += 256) {
    const void* p; int i;
    if (t < 256)       { p = fcb;  i = t; }
    else if (t < 1024) { p = bih;  i = t - 256; }
    else if (t < 1792) { p = bhh;  i = t - 1024; }
    else if (t < 2048) { p = c1b;  i = t - 1792; }
    else if (t < 2304) { p = c2b;  i = t - 2048; }
    else {
      int k = t - 2304; float s = 0.f;
      for (int e = 0; e < 5; ++e)
        s += f32 ? ((const float*)edgeb)[e * 256 + k]
                 : bf2f(((const __hip_bfloat16*)edgeb)[e * 256 + k]);
      pool[t] = s; continue;
    }
    pool[t] = f32 ? ((const float*)p)[i] : bf2f(((const __hip_bfloat16*)p)[i]);
  }
  for (int t = threadIdx.x; t < 1024; t += 256) ge[t] = 0.f;
  for (int t = threadIdx.x; t < 4096; t += 256) am32[t] = 0.f;
}

// bias_gi[n] = b_ih[n] + sum_k sum_edge_b[k] * w_ih[n][k]   (n < 768)
__global__ void bias_gi_k(const float* __restrict__ pool,
                          const __hip_bfloat16* __restrict__ wih,
                          float* __restrict__ out) {
  const int n = blockIdx.x * 256 + threadIdx.x;
  if (n >= 768) return;
  float s = pool[256 + n];
  for (int k = 0; k < 256; ++k) s += pool[2304 + k] * bf2f(wih[n * 256 + k]);
  out[n] = s;
}

// ingest all 6 weight matrices into one internal bf16 pool
__global__ void wcvt_all(const void* fcw, const void* edw, const void* wih,
                         const void* whh, const void* c1w, const void* c2w,
                         const int* __restrict__ flag, __hip_bfloat16* __restrict__ dst) {
  const bool f32 = (*flag != 0);
  const int i = blockIdx.x * 256 + threadIdx.x;   // 0..917503
  const void* src; int off;
  if      (i < 65536)  { src = fcw; off = i; }
  else if (i < 393216) { src = edw; off = i - 65536; }
  else if (i < 589824) { src = wih; off = i - 393216; }
  else if (i < 786432) { src = whh; off = i - 589824; }
  else if (i < 851968) { src = c1w; off = i - 786432; }
  else                 { src = c2w; off = i - 851968; }
  dst[i] = f32 ? f2bf(((const float*)src)[off])
               : ((const __hip_bfloat16*)src)[off];
}

// one-time adj -> internal bf16 (20,971,520 elems), 8 elems/thread
__global__ void adj_cvt(const void* __restrict__ src, const int* __restrict__ flag,
                        __hip_bfloat16* __restrict__ dst) {
  const bool f32 = (*flag != 0);
  const long i = ((long)blockIdx.x * 256 + threadIdx.x) * 8;
  bf16x8 r;
  if (f32) {
    const float* p = (const float*)src + i;
#pragma unroll
    for (int j = 0; j < 8; ++j) r[j] = f2bs(p[j]);
  } else {
    r = *(const bf16x8*)((const __hip_bfloat16*)src + i);
  }
  *(bf16x8*)(dst + i) = r;
}

// ---------------------------------------------------------------------------
// 128x64-tile bf16 GEMM, C = A @ Bt^T (+bias). Reg-staged, XOR-swizzled LDS.
// 4 waves, each 2 m-frags x 4 n-frags. Internal-bf16 operands only.
// DUAL: z>=zSplit switches to second operand set (same geometry).
// ---------------------------------------------------------------------------
template<bool HAS_BIAS, bool DUAL>
__global__ __launch_bounds__(256)
void gemm_bt128(const __hip_bfloat16* __restrict__ A, const __hip_bfloat16* __restrict__ Bt,
                const float* __restrict__ bias, __hip_bfloat16* __restrict__ C,
                const __hip_bfloat16* __restrict__ A2, const __hip_bfloat16* __restrict__ Bt2,
                const float* __restrict__ bias2, __hip_bfloat16* __restrict__ C2,
                int K, int lda, int ldb, int ldc,
                long aBatch, int zdivA, int zmodA,
                long bBatch, int zdivB, int zmodB,
                long cBatch, int zdivC, int zSplit)
{
  __shared__ __align__(16) __hip_bfloat16 sA[128 * 64];
  __shared__ __align__(16) __hip_bfloat16 sB[64 * 64];
  const int t = threadIdx.x;
  const int w = t >> 6;
  const int l = t & 63;
  const int m0 = blockIdx.x * 128;
  const int n0 = blockIdx.y * 64;
  int z = blockIdx.z;

  const __hip_bfloat16* Au = A; const __hip_bfloat16* Btu = Bt;
  const float* biasu = bias; __hip_bfloat16* Cu = C;
  if (DUAL && z >= zSplit) { Au = A2; Btu = Bt2; biasu = bias2; Cu = C2; z -= zSplit; }

  const __hip_bfloat16* Ab = Au + (long)((z / zdivA) % zmodA) * aBatch;
  const __hip_bfloat16* Bb = Btu + (long)((z / zdivB) % zmodB) * bBatch;

  int sra[4], sca[4];
#pragma unroll
  for (int i = 0; i < 4; ++i) {
    const int p = t + 256 * i;
    sra[i] = p >> 3;
    sca[i] = (p & 7) ^ (sra[i] & 7);
  }
  const int p0 = t, p1 = t + 256;
  const int sr0 = p0 >> 3, sc0 = (p0 & 7) ^ (sr0 & 7);
  const int sr1 = p1 >> 3, sc1 = (p1 & 7) ^ (sr1 & 7);

  f32x4 acc[2][4];
#pragma unroll
  for (int i = 0; i < 2; ++i)
#pragma unroll
    for (int j = 0; j < 4; ++j) acc[i][j] = (f32x4){0.f, 0.f, 0.f, 0.f};

  const int r15 = l & 15;
  const int quad = l >> 4;

  for (int k0 = 0; k0 < K; k0 += 64) {
    bf16x8 av[4];
#pragma unroll
    for (int i = 0; i < 4; ++i)
      av[i] = *(const bf16x8*)(Ab + (long)(m0 + sra[i]) * lda + (k0 + sca[i] * 8));
    bf16x8 b0 = *(const bf16x8*)(Bb + (long)(n0 + sr0) * ldb + (k0 + sc0 * 8));
    bf16x8 b1 = *(const bf16x8*)(Bb + (long)(n0 + sr1) * ldb + (k0 + sc1 * 8));
    __syncthreads();
#pragma unroll
    for (int i = 0; i < 4; ++i) *(bf16x8*)(sA + (t + 256 * i) * 8) = av[i];
    *(bf16x8*)(sB + p0 * 8) = b0;
    *(bf16x8*)(sB + p1 * 8) = b1;
    __syncthreads();
#pragma unroll
    for (int ks = 0; ks < 2; ++ks) {
      const int cg = ks * 4 + quad;
      bf16x8 aF[2], bF[4];
#pragma unroll
      for (int mi = 0; mi < 2; ++mi) {
        const int row = mi * 64 + w * 16 + r15;
        aF[mi] = *(const bf16x8*)(sA + row * 64 + ((cg ^ (row & 7)) * 8));
      }
#pragma unroll
      for (int ni = 0; ni < 4; ++ni) {
        const int nrow = ni * 16 + r15;
        bF[ni] = *(const bf16x8*)(sB + nrow * 64 + ((cg ^ (nrow & 7)) * 8));
      }
#pragma unroll
      for (int mi = 0; mi < 2; ++mi)
#pragma unroll
        for (int ni = 0; ni < 4; ++ni)
          acc[mi][ni] = __builtin_amdgcn_mfma_f32_16x16x32_bf16(
              aF[mi], bF[ni], acc[mi][ni], 0, 0, 0);
    }
  }

  const long cOff = (long)(z / zdivC) * cBatch;
#pragma unroll
  for (int mi = 0; mi < 2; ++mi) {
#pragma unroll
    for (int ni = 0; ni < 4; ++ni) {
      const int n = n0 + ni * 16 + r15;
      float bv = 0.f;
      if (HAS_BIAS) bv = biasu[n];
#pragma unroll
      for (int r = 0; r < 4; ++r) {
        const int m = m0 + mi * 64 + w * 16 + quad * 4 + r;
        Cu[cOff + (long)m * ldc + n] = f2bf(acc[mi][ni][r] + bv);
      }
    }
  }
}

// ---------------------------------------------------------------------------
// part || gh packed dispatch, 1D grid of 1024 blocks, 128x64 tile each.
//  bid <  640: part[b,e] = adj[b,e] @ heT[b,e]^T  (M=1024 N=256 K=1024)
//              T1 XCD-chunked swizzle: lb=(bid&7)*80+(bid>>3) so each XCD
//              owns 2.5 contiguous z-slices (heT panels + adj rows L2-local)
//  bid >= 640: gh = h @ w_hh^T + b_hh             (M=4096 N=768  K=256)
// ---------------------------------------------------------------------------
__global__ __launch_bounds__(256)
void part_gh(const __hip_bfloat16* __restrict__ adjb,
             const __hip_bfloat16* __restrict__ heT,
             __hip_bfloat16* __restrict__ part,
             const __hip_bfloat16* __restrict__ hbf,
             const __hip_bfloat16* __restrict__ whh,
             const float* __restrict__ bhh,
             __hip_bfloat16* __restrict__ gh)
{
  __shared__ __align__(16) __hip_bfloat16 sA[128 * 64];
  __shared__ __align__(16) __hip_bfloat16 sB[64 * 64];
  const int t = threadIdx.x;
  const int w = t >> 6;
  const int l = t & 63;
  const int bid = blockIdx.x;

  const __hip_bfloat16* Ab; const __hip_bfloat16* Bb;
  __hip_bfloat16* Cu; const float* biasu = nullptr;
  int K, lda, ldb, ldc, m0, n0;
  bool has_bias;
  if (bid < 640) {
    const int lb = (bid & 7) * 80 + (bid >> 3);   // bijective XCD chunking
    const int z = lb >> 5, rem = lb & 31;
    m0 = (rem & 7) * 128; n0 = (rem >> 3) * 64;
    Ab = adjb + (long)z * 1048576; lda = 1024; K = 1024;
    Bb = heT + (long)z * 262144;  ldb = 1024;
    Cu = part + (long)z * 262144; ldc = 256;
    has_bias = false;
  } else {
    const int idx = bid - 640;
    m0 = (idx & 31) * 128; n0 = (idx >> 5) * 64;
    Ab = hbf; lda = 256; K = 256;
    Bb = whh; ldb = 256;
    Cu = gh;  ldc = 768;
    biasu = bhh; has_bias = true;
  }

  int sra[4], sca[4];
#pragma unroll
  for (int i = 0; i < 4; ++i) {
    const int p = t + 256 * i;
    sra[i] = p >> 3;
    sca[i] = (p & 7) ^ (sra[i] & 7);
  }
  const int p0 = t, p1 = t + 256;
  const int sr0 = p0 >> 3, sc0 = (p0 & 7) ^ (sr0 & 7);
  const int sr1 = p1 >> 3, sc1 = (p1 & 7) ^ (sr1 & 7);

  f32x4 acc[2][4];
#pragma unroll
  for (int i = 0; i < 2; ++i)
#pragma unroll
    for (int j = 0; j < 4; ++j) acc[i][j] = (f32x4){0.f, 0.f, 0.f, 0.f};

  const int r15 = l & 15;
  const int quad = l >> 4;

  for (int k0 = 0; k0 < K; k0 += 64) {
    bf16x8 av[4];
#pragma unroll
    for (int i = 0; i < 4; ++i)
      av[i] = *(const bf16x8*)(Ab + (long)(m0 + sra[i]) * lda + (k0 + sca[i] * 8));
    bf16x8 b0 = *(const bf16x8*)(Bb + (long)(n0 + sr0) * ldb + (k0 + sc0 * 8));
    bf16x8 b1 = *(const bf16x8*)(Bb + (long)(n0 + sr1) * ldb + (k0 + sc1 * 8));
    __syncthreads();
#pragma unroll
    for (int i = 0; i < 4; ++i) *(bf16x8*)(sA + (t + 256 * i) * 8) = av[i];
    *(bf16x8*)(sB + p0 * 8) = b0;
    *(bf16x8*)(sB + p1 * 8) = b1;
    __syncthreads();
#pragma unroll
    for (int ks = 0; ks < 2; ++ks) {
      const int cg = ks * 4 + quad;
      bf16x8 aF[2], bF[4];
#pragma unroll
      for (int mi = 0; mi < 2; ++mi) {
        const int row = mi * 64 + w * 16 + r15;
        aF[mi] = *(const bf16x8*)(sA + row * 64 + ((cg ^ (row & 7)) * 8));
      }
#pragma unroll
      for (int ni = 0; ni < 4; ++ni) {
        const int nrow = ni * 16 + r15;
        bF[ni] = *(const bf16x8*)(sB + nrow * 64 + ((cg ^ (nrow & 7)) * 8));
      }
#pragma unroll
      for (int mi = 0; mi < 2; ++mi)
#pragma unroll
        for (int ni = 0; ni < 4; ++ni)
          acc[mi][ni] = __builtin_amdgcn_mfma_f32_16x16x32_bf16(
              aF[mi], bF[ni], acc[mi][ni], 0, 0, 0);
    }
  }

#pragma unroll
  for (int mi = 0; mi < 2; ++mi) {
#pragma unroll
    for (int ni = 0; ni < 4; ++ni) {
      const int n = n0 + ni * 16 + r15;
      const float bv = has_bias ? biasu[n] : 0.f;
#pragma unroll
      for (int r = 0; r < 4; ++r) {
        const int m = m0 + mi * 64 + w * 16 + quad * 4 + r;
        Cu[(long)m * ldc + n] = f2bf(acc[mi][ni][r] + bv);
      }
    }
  }
}

// ---------------------------------------------------------------------------
// gi + GRU gate fused. 64x64-tile 3-gate GEMM over A = sum_e part (folded
// 5-slice staging), B = w_ih rows {n, 256+n, 512+n}. Epilogue reads gh & h,
// applies torch-GRUCell gates [r,z,n], writes h in-place (and node_states on
// the final step). 1D grid 256: m0=(bid&63)*64, n0=(bid>>6)*64.
// (A-sharing blocks are bid, bid+64, ... == same mod 8 -> already XCD-local.)
// ---------------------------------------------------------------------------
__global__ __launch_bounds__(256)
void gi_gate(const __hip_bfloat16* __restrict__ part,
             const __hip_bfloat16* __restrict__ wih,
             const float* __restrict__ biasgi,
             const __hip_bfloat16* __restrict__ gh,
             __hip_bfloat16* __restrict__ hbf,
             void* __restrict__ ns_out, const int* __restrict__ flag)
{
  __shared__ __align__(16) __hip_bfloat16 sA[64 * 64];
  __shared__ __align__(16) __hip_bfloat16 sB0[64 * 64];
  __shared__ __align__(16) __hip_bfloat16 sB1[64 * 64];
  __shared__ __align__(16) __hip_bfloat16 sB2[64 * 64];
  const int t = threadIdx.x;
  const int w = t >> 6;
  const int l = t & 63;
  const int m0 = (blockIdx.x & 63) * 64;
  const int n0 = (blockIdx.x >> 6) * 64;

  const int p0 = t, p1 = t + 256;
  const int sr0 = p0 >> 3, sc0 = (p0 & 7) ^ (sr0 & 7);
  const int sr1 = p1 >> 3, sc1 = (p1 & 7) ^ (sr1 & 7);

  f32x4 acc[3][4];
#pragma unroll
  for (int g = 0; g < 3; ++g)
#pragma unroll
    for (int j = 0; j < 4; ++j) acc[g][j] = (f32x4){0.f, 0.f, 0.f, 0.f};

  const int mrow = w * 16 + (l & 15);
  const int r15 = l & 15;
  const int quad = l >> 4;

  for (int k0 = 0; k0 < 256; k0 += 64) {
    bf16x8 a0 = ld8_sum5(part, m0 + sr0, k0 + sc0 * 8);
    bf16x8 a1 = ld8_sum5(part, m0 + sr1, k0 + sc1 * 8);
    bf16x8 bg[3][2];
#pragma unroll
    for (int g = 0; g < 3; ++g) {
      bg[g][0] = *(const bf16x8*)(wih + (long)(g * 256 + n0 + sr0) * 256 + (k0 + sc0 * 8));
      bg[g][1] = *(const bf16x8*)(wih + (long)(g * 256 + n0 + sr1) * 256 + (k0 + sc1 * 8));
    }
    __syncthreads();
    *(bf16x8*)(sA + p0 * 8) = a0;
    *(bf16x8*)(sA + p1 * 8) = a1;
    *(bf16x8*)(sB0 + p0 * 8) = bg[0][0]; *(bf16x8*)(sB0 + p1 * 8) = bg[0][1];
    *(bf16x8*)(sB1 + p0 * 8) = bg[1][0]; *(bf16x8*)(sB1 + p1 * 8) = bg[1][1];
    *(bf16x8*)(sB2 + p0 * 8) = bg[2][0]; *(bf16x8*)(sB2 + p1 * 8) = bg[2][1];
    __syncthreads();
#pragma unroll
    for (int ks = 0; ks < 2; ++ks) {
      const int cg = ks * 4 + quad;
      bf16x8 af = *(const bf16x8*)(sA + mrow * 64 + ((cg ^ (mrow & 7)) * 8));
#pragma unroll
      for (int t4 = 0; t4 < 4; ++t4) {
        const int nrow = t4 * 16 + r15;
        const int so = nrow * 64 + ((cg ^ (nrow & 7)) * 8);
        bf16x8 b0f = *(const bf16x8*)(sB0 + so);
        bf16x8 b1f = *(const bf16x8*)(sB1 + so);
        bf16x8 b2f = *(const bf16x8*)(sB2 + so);
        acc[0][t4] = __builtin_amdgcn_mfma_f32_16x16x32_bf16(af, b0f, acc[0][t4], 0, 0, 0);
        acc[1][t4] = __builtin_amdgcn_mfma_f32_16x16x32_bf16(af, b1f, acc[1][t4], 0, 0, 0);
        acc[2][t4] = __builtin_amdgcn_mfma_f32_16x16x32_bf16(af, b2f, acc[2][t4], 0, 0, 0);
      }
    }
  }

  const bool f32out = ns_out && (*flag != 0);
#pragma unroll
  for (int t4 = 0; t4 < 4; ++t4) {
    const int n = n0 + t4 * 16 + r15;
    const float bgr = biasgi[n];
    const float bgz = biasgi[256 + n];
    const float bgn = biasgi[512 + n];
#pragma unroll
    for (int r = 0; r < 4; ++r) {
      const int m = m0 + w * 16 + quad * 4 + r;
      const long gb = (long)m * 768;
      const float ir = acc[0][t4][r] + bgr;
      const float iz = acc[1][t4][r] + bgz;
      const float inn = acc[2][t4][r] + bgn;
      const float hr = bf2f(gh[gb + n]);
      const float hz = bf2f(gh[gb + 256 + n]);
      const float hn = bf2f(gh[gb + 512 + n]);
      const long hidx = (long)m * 256 + n;
      const float h = bf2f(hbf[hidx]);
      const float rr = 1.f / (1.f + __expf(-(ir + hr)));
      const float zz = 1.f / (1.f + __expf(-(iz + hz)));
      const float nn = tanhf(inn + rr * hn);
      const float hnew = (1.f - zz) * nn + zz * h;
      const __hip_bfloat16 hb = f2bf(hnew);
      hbf[hidx] = hb;
      if (ns_out) {
        if (f32out) ((float*)ns_out)[1024 + hidx] = hnew;
        else        ((__hip_bfloat16*)ns_out)[1024 + hidx] = hb;
      }
    }
  }
}

// OUT_MODE: 0=bf16 C; 1=fp32 C.  A_MODE: 0=internal bf16, 1=external (flag
// dtype), 2=sum-of-5-bf16-slices (gi).  DUAL: z>=zSplit switches to 2nd set.
template<int OUT_MODE, bool HAS_BIAS, int A_MODE, bool DUAL>
__global__ __launch_bounds__(256)
void gemm_bt(const void* __restrict__ A, const __hip_bfloat16* __restrict__ Bt,
             const float* __restrict__ bias, void* __restrict__ Cp,
             const void* __restrict__ A2, const __hip_bfloat16* __restrict__ Bt2,
             const float* __restrict__ bias2, void* __restrict__ Cp2,
             const int* __restrict__ flag,
             int Kg, int ngrp, int lda, int ldb, int ldc,
             long aBatch, int zdivA, int zmodA,
             long bBatch, int zdivB, int zmodB,
             long cBatch, int zdivC, long aGrp, long bGrp, int zSplit)
{
  __shared__ __align__(16) __hip_bfloat16 sA[64 * 64];
  __shared__ __align__(16) __hip_bfloat16 sB[64 * 64];
  const bool af32 = (A_MODE == 1) ? (*flag != 0) : false;
  const int t = threadIdx.x;
  const int w = t >> 6;
  const int l = t & 63;
  const int m0 = blockIdx.x * 64;
  const int n0 = blockIdx.y * 64;
  int z = blockIdx.z;

  const void* Au = A; const __hip_bfloat16* Btu = Bt;
  const float* biasu = bias; void* Cpu = Cp;
  bool second = false;
  if (DUAL && z >= zSplit) {
    Au = A2; Btu = Bt2; biasu = bias2; Cpu = Cp2; z -= zSplit; second = true;
  }

  const long aOff = (long)((z / zdivA) % zmodA) * aBatch;
  const __hip_bfloat16* Bb = Btu + (long)((z / zdivB) % zmodB) * bBatch;

  const int p0 = t, p1 = t + 256;
  const int sr0 = p0 >> 3, sc0 = (p0 & 7) ^ (sr0 & 7);
  const int sr1 = p1 >> 3, sc1 = (p1 & 7) ^ (sr1 & 7);

  f32x4 acc[4];
#pragma unroll
  for (int i = 0; i < 4; ++i) acc[i] = (f32x4){0.f, 0.f, 0.f, 0.f};

  const int mrow = w * 16 + (l & 15);
  const int quad = l >> 4;

  for (int g = 0; g < ngrp; ++g) {
    const long aG = aOff + (long)g * aGrp;
    const __hip_bfloat16* Bg = Bb + (long)g * bGrp;
    for (int k0 = 0; k0 < Kg; k0 += 64) {
      bf16x8 a0, a1;
      if (A_MODE == 2 && !second) {
        a0 = ld8_sum5((const __hip_bfloat16*)Au, m0 + sr0, k0 + sc0 * 8);
        a1 = ld8_sum5((const __hip_bfloat16*)Au, m0 + sr1, k0 + sc1 * 8);
      } else if (A_MODE == 1) {
        a0 = ld8_ext(Au, aG + (long)(m0 + sr0) * lda + (k0 + sc0 * 8), af32);
        a1 = ld8_ext(Au, aG + (long)(m0 + sr1) * lda + (k0 + sc1 * 8), af32);
      } else {
        const __hip_bfloat16* Ab = (const __hip_bfloat16*)Au;
        a0 = *(const bf16x8*)(Ab + aG + (long)(m0 + sr0) * lda + (k0 + sc0 * 8));
        a1 = *(const bf16x8*)(Ab + aG + (long)(m0 + sr1) * lda + (k0 + sc1 * 8));
      }
      bf16x8 b0 = *(const bf16x8*)(Bg + (long)(n0 + sr0) * ldb + (k0 + sc0 * 8));
      bf16x8 b1 = *(const bf16x8*)(Bg + (long)(n0 + sr1) * ldb + (k0 + sc1 * 8));
      __syncthreads();
      *(bf16x8*)(sA + p0 * 8) = a0;
      *(bf16x8*)(sA + p1 * 8) = a1;
      *(bf16x8*)(sB + p0 * 8) = b0;
      *(bf16x8*)(sB + p1 * 8) = b1;
      __syncthreads();
#pragma unroll
      for (int ks = 0; ks < 2; ++ks) {
        const int cg = ks * 4 + quad;
        bf16x8 af = *(const bf16x8*)(sA + mrow * 64 + ((cg ^ (mrow & 7)) * 8));
#pragma unroll
        for (int t4 = 0; t4 < 4; ++t4) {
          const int nrow = t4 * 16 + (l & 15);
          bf16x8 bfr = *(const bf16x8*)(sB + nrow * 64 + ((cg ^ (nrow & 7)) * 8));
          acc[t4] = __builtin_amdgcn_mfma_f32_16x16x32_bf16(af, bfr, acc[t4], 0, 0, 0);
        }
      }
    }
  }

  const long cOff = (long)(z / zdivC) * cBatch;
#pragma unroll
  for (int t4 = 0; t4 < 4; ++t4) {
    const int n = n0 + t4 * 16 + (l & 15);
    float bv = 0.f;
    if (HAS_BIAS) bv = biasu[n];
#pragma unroll
    for (int r = 0; r < 4; ++r) {
      const int m = m0 + w * 16 + quad * 4 + r;
      const float v = acc[t4][r] + bv;
      if (OUT_MODE == 0)
        ((__hip_bfloat16*)Cpu)[cOff + (long)m * ldc + n] = f2bf(v);
      else
        ((float*)Cpu)[cOff + (long)m * ldc + n] = v;
    }
  }
}

// torch GRUCell gates [r,z,n] (fallback paths only)
__global__ void gru_gate8(const __hip_bfloat16* __restrict__ gi,
                          const __hip_bfloat16* __restrict__ gh,
                          __hip_bfloat16* __restrict__ hbf,
                          void* __restrict__ ns_out, const int* __restrict__ flag)
{
  const int t = blockIdx.x * 256 + threadIdx.x;  // 0..131071
  const int m = t >> 5;                          // row 0..4095
  const int k = (t & 31) * 8;                    // 0..255 step 8
  const long gb = (long)m * 768 + k;
  bf16x8 vir = *(const bf16x8*)(gi + gb);
  bf16x8 viz = *(const bf16x8*)(gi + gb + 256);
  bf16x8 vin = *(const bf16x8*)(gi + gb + 512);
  bf16x8 vhr = *(const bf16x8*)(gh + gb);
  bf16x8 vhz = *(const bf16x8*)(gh + gb + 256);
  bf16x8 vhn = *(const bf16x8*)(gh + gb + 512);
  const long hidx = (long)m * 256 + k;
  bf16x8 vh = *(const bf16x8*)(hbf + hidx);
  bf16x8 out;
  float hf[8];
#pragma unroll
  for (int j = 0; j < 8; ++j) {
    const float r = 1.f / (1.f + __expf(-(s2f(vir[j]) + s2f(vhr[j]))));
    const float zz = 1.f / (1.f + __expf(-(s2f(viz[j]) + s2f(vhz[j]))));
    const float nn = tanhf(s2f(vin[j]) + r * s2f(vhn[j]));
    hf[j] = (1.f - zz) * nn + zz * s2f(vh[j]);
    out[j] = f2bs(hf[j]);
  }
  *(bf16x8*)(hbf + hidx) = out;
  if (ns_out) {
    if (*flag) {
      float* o = (float*)ns_out + 1024 + hidx;
#pragma unroll
      for (int j = 0; j < 8; ++j) o[j] = hf[j];
    } else {
      *(bf16x8*)((__hip_bfloat16*)ns_out + 1024 + hidx) = out;
    }
  }
}

// fused output epilogue: per 64x64 tile compute attl & fetl via MFMA, apply
// sigmoid/tanh, reduce ge (sum over nodes) and attn row-sums via LDS+atomics.
__global__ __launch_bounds__(256)
void conv_fused(const __hip_bfloat16* __restrict__ hbf,
                const __hip_bfloat16* __restrict__ c1w,
                const __hip_bfloat16* __restrict__ c2w,
                const float* __restrict__ pool,
                float* __restrict__ geg, float* __restrict__ am32)
{
  __shared__ __align__(16) __hip_bfloat16 sA[64 * 64];
  __shared__ __align__(16) __hip_bfloat16 sB1[64 * 64];
  __shared__ __align__(16) __hip_bfloat16 sB2[64 * 64];
  __shared__ float sge[64];
  __shared__ float sam[64];
  const int t = threadIdx.x, w = t >> 6, l = t & 63;
  const int m0 = blockIdx.x * 64, n0 = blockIdx.y * 64;
  if (t < 64) { sge[t] = 0.f; sam[t] = 0.f; }
  const int p0 = t, p1 = t + 256;
  const int sr0 = p0 >> 3, sc0 = (p0 & 7) ^ (sr0 & 7);
  const int sr1 = p1 >> 3, sc1 = (p1 & 7) ^ (sr1 & 7);
  f32x4 a1[4], a2[4];
#pragma unroll
  for (int i = 0; i < 4; ++i) { a1[i] = (f32x4){0,0,0,0}; a2[i] = (f32x4){0,0,0,0}; }
  const int mrow = w * 16 + (l & 15);
  const int quad = l >> 4;
  for (int k0 = 0; k0 < 256; k0 += 64) {
    bf16x8 va0 = *(const bf16x8*)(hbf + (long)(m0 + sr0) * 256 + (k0 + sc0 * 8));
    bf16x8 va1 = *(const bf16x8*)(hbf + (long)(m0 + sr1) * 256 + (k0 + sc1 * 8));
    bf16x8 vb0 = *(const bf16x8*)(c1w + (long)(n0 + sr0) * 256 + (k0 + sc0 * 8));
    bf16x8 vb1 = *(const bf16x8*)(c1w + (long)(n0 + sr1) * 256 + (k0 + sc1 * 8));
    bf16x8 vc0 = *(const bf16x8*)(c2w + (long)(n0 + sr0) * 256 + (k0 + sc0 * 8));
    bf16x8 vc1 = *(const bf16x8*)(c2w + (long)(n0 + sr1) * 256 + (k0 + sc1 * 8));
    __syncthreads();
    *(bf16x8*)(sA + p0 * 8) = va0;  *(bf16x8*)(sA + p1 * 8) = va1;
    *(bf16x8*)(sB1 + p0 * 8) = vb0; *(bf16x8*)(sB1 + p1 * 8) = vb1;
    *(bf16x8*)(sB2 + p0 * 8) = vc0; *(bf16x8*)(sB2 + p1 * 8) = vc1;
    __syncthreads();
#pragma unroll
    for (int ks = 0; ks < 2; ++ks) {
      const int cg = ks * 4 + quad;
      bf16x8 af = *(const bf16x8*)(sA + mrow * 64 + ((cg ^ (mrow & 7)) * 8));
#pragma unroll
      for (int t4 = 0; t4 < 4; ++t4) {
        const int nrow = t4 * 16 + (l & 15);
        bf16x8 b1f = *(const bf16x8*)(sB1 + nrow * 64 + ((cg ^ (nrow & 7)) * 8));
        bf16x8 b2f = *(const bf16x8*)(sB2 + nrow * 64 + ((cg ^ (nrow & 7)) * 8));
        a1[t4] = __builtin_amdgcn_mfma_f32_16x16x32_bf16(af, b1f, a1[t4], 0, 0, 0);
        a2[t4] = __builtin_amdgcn_mfma_f32_16x16x32_bf16(af, b2f, a2[t4], 0, 0, 0);
      }
    }
  }
  float asum[4] = {0.f, 0.f, 0.f, 0.f};
#pragma unroll
  for (int t4 = 0; t4 < 4; ++t4) {
    const int n = n0 + t4 * 16 + (l & 15);
    const float bb1 = pool[1792 + n], bb2 = pool[2048 + n];
    float g = 0.f;
#pragma unroll
    for (int r = 0; r < 4; ++r) {
      const float av = 1.f / (1.f + __expf(-(a1[t4][r] + bb1)));
      const float fv = tanhf(a2[t4][r] + bb2);
      g += av * fv;
      asum[r] += av;
    }
    atomicAdd(&sge[t4 * 16 + (l & 15)], g);
  }
#pragma unroll
  for (int r = 0; r < 4; ++r) atomicAdd(&sam[w * 16 + quad * 4 + r], asum[r]);
  __syncthreads();
  if (t < 64) atomicAdd(&geg[(m0 >> 10) * 256 + n0 + t], sge[t]);
  else if (t < 128) atomicAdd(&am32[m0 + (t - 64)], sam[t - 64]);
}

__global__ void finish_out(const float* __restrict__ ge, const float* __restrict__ am32,
                           void* __restrict__ dout, const int* __restrict__ flag)
{
  const int t = blockIdx.x * 256 + threadIdx.x;   // 0..5119
  const bool f32 = (*flag != 0);
  if (t < 1024) {
    if (f32) ((float*)dout)[t] = ge[t];
    else     ((__hip_bfloat16*)dout)[t] = f2bf(ge[t]);
  } else {
    const float v = am32[t - 1024] * (1.f / 256.f);
    if (f32) ((float*)dout)[1049600 + t - 1024] = v;
    else     ((__hip_bfloat16*)dout)[1049600 + t - 1024] = f2bf(v);
  }
}

extern "C" void kernel_launch(void* const* d_in, const int* in_sizes, int n_in,
                              void* d_out, int out_size, void* d_ws, size_t ws_size,
                              hipStream_t stream) {
  (void)in_sizes; (void)n_in; (void)out_size;
  const void* node_f = d_in[0];
  const void* adj    = d_in[1];
  const void* fc_w   = d_in[2];
  const void* fc_b   = d_in[3];
  const void* edge_w = d_in[4];
  const void* edge_b = d_in[5];
  const void* w_ih   = d_in[6];
  const void* w_hh   = d_in[7];
  const void* b_ih   = d_in[8];
  const void* b_hh   = d_in[9];
  const void* c1w    = d_in[10];
  const void* c1b    = d_in[11];
  const void* c2w    = d_in[12];
  const void* c2b    = d_in[13];

  // ws layout:
  //  [0,4) flag | [256, 13568) pool (3328 f) | [14336, 18432) ge (1024 f)
  //  [18432, 34816) am32 (4096 f) | [34816, ..) wbf 1.75M | [1869824, ..) hbf 2M
  //  S = ws+3966976: heT [0,10M) | part [10M,20M) | gi(fallback) [20M,26M) |
  //  gh [26M,32M)   adjb @ ws+40MiB (40 MiB)
  char* ws = (char*)d_ws;
  const size_t MB = (size_t)1 << 20;
  int*            flag = (int*)(ws);
  float*          bp   = (float*)(ws + 256);
  float*          ge   = (float*)(ws + 14336);
  float*          am32 = (float*)(ws + 18432);
  __hip_bfloat16* wbf  = (__hip_bfloat16*)(ws + 34816);
  __hip_bfloat16* hbf  = (__hip_bfloat16*)(ws + 1869824);
  char*           S    = ws + 3966976;
  __hip_bfloat16* heT  = (__hip_bfloat16*)(S);
  __hip_bfloat16* part = (__hip_bfloat16*)(S + 10 * MB);
  __hip_bfloat16* gi   = (__hip_bfloat16*)(S + 20 * MB);   // fallback only
  __hip_bfloat16* gh   = (__hip_bfloat16*)(S + 26 * MB);
  __hip_bfloat16* adjb = (__hip_bfloat16*)(ws + 40 * MB);

  const bool has_split = ws_size >= 38 * MB;   // part/gi/gh fit
  const bool has_adjb  = ws_size >= 81 * MB;   // adjb fits

  detect_dtype<<<1, 256, 0, stream>>>((const uint32_t*)adj, flag);
  prep_pool<<<1, 256, 0, stream>>>(fc_b, b_ih, b_hh, c1b, c2b, edge_b, flag, bp, ge, am32);
  wcvt_all<<<3584, 256, 0, stream>>>(fc_w, edge_w, w_ih, w_hh, c1w, c2w, flag, wbf);
  bias_gi_k<<<3, 256, 0, stream>>>(bp, wbf + 393216, bp + 2560);
  if (has_adjb) adj_cvt<<<10240, 256, 0, stream>>>(adj, flag, adjb);

  // h = X @ fc_w^T + fc_b  (external, possibly fp32 A -> keep 64^2 path)
  gemm_bt<0, true, 1, false><<<dim3(64, 4, 1), 256, 0, stream>>>(
      node_f, wbf + 0, bp + 0, hbf, nullptr, nullptr, nullptr, nullptr, flag,
      256, 1, 256, 256, 256, 0, 1, 1, 0, 1, 1, 0, 1, 0, 0, 0);

  for (int s = 0; s < 5; ++s) {
    if (has_adjb) {
      // heT[b,e][d][node] = edge_w[e] @ h[b]^T : M=256 N=1024 K=256, z=(b,e)
      gemm_bt128<false, false><<<dim3(2, 16, 20), 256, 0, stream>>>(
          wbf + 65536, hbf, nullptr, heT, nullptr, nullptr, nullptr, nullptr,
          256, 256, 256, 1024,
          65536, 1, 5,
          262144, 5, 4,
          262144, 1, 0);
      // part[b,e] = adj @ he  ||  gh = h @ w_hh^T + b_hh   (one dispatch)
      part_gh<<<1024, 256, 0, stream>>>(adjb, heT, part,
                                        hbf, wbf + 589824, bp + 1024, gh);
      // gi (= sum_e part @ w_ih^T + bias_gi) + GRU gates, h updated in-place
      gi_gate<<<256, 256, 0, stream>>>(part, wbf + 393216, bp + 2560, gh, hbf,
                                       (s == 4) ? d_out : nullptr, flag);
    } else if (has_split) {
      gemm_bt<0, false, 0, false><<<dim3(4, 16, 20), 256, 0, stream>>>(
          wbf + 65536, hbf, nullptr, heT, nullptr, nullptr, nullptr, nullptr, flag,
          256, 1, 256, 256, 1024,
          65536, 1, 5, 262144, 5, 4,
          262144, 1, 0, 0, 0);
      gemm_bt<0, false, 1, false><<<dim3(16, 4, 20), 256, 0, stream>>>(
          adj, heT, nullptr, part, nullptr, nullptr, nullptr, nullptr, flag,
          1024, 1, 1024, 1024, 256,
          1048576, 1, 20, 262144, 1, 20,
          262144, 1, 0, 0, 0);
      gemm_bt<0, true, 2, true><<<dim3(64, 12, 2), 256, 0, stream>>>(
          part, wbf + 393216, bp + 2560, gi,
          hbf,  wbf + 589824, bp + 1024, gh, flag,
          256, 1, 256, 256, 768, 0, 1, 1, 0, 1, 1, 0, 1, 0, 0, 1);
      gru_gate8<<<512, 256, 0, stream>>>(gi, gh, hbf,
                                         (s == 4) ? d_out : nullptr, flag);
    } else {
      gemm_bt<0, false, 0, false><<<dim3(4, 16, 20), 256, 0, stream>>>(
          wbf + 65536, hbf, nullptr, heT, nullptr, nullptr, nullptr, nullptr, flag,
          256, 1, 256, 256, 1024,
          65536, 1, 5, 262144, 5, 4,
          262144, 1, 0, 0, 0);
      gemm_bt<0, true, 1, false><<<dim3(16, 4, 4), 256, 0, stream>>>(
          adj, heT, bp + 2304, part, nullptr, nullptr, nullptr, nullptr, flag,
          1024, 5, 1024, 1024, 256,
          (long)5 * 1048576, 1, 4, (long)5 * 262144, 1, 4,
          262144, 1, 1048576, 262144, 0);
      gemm_bt<0, true, 0, true><<<dim3(64, 12, 2), 256, 0, stream>>>(
          part, wbf + 393216, bp + 256, gi,
          hbf,  wbf + 589824, bp + 1024, gh, flag,
          256, 1, 256, 256, 768, 0, 1, 1, 0, 1, 1, 0, 1, 0, 0, 1);
      gru_gate8<<<512, 256, 0, stream>>>(gi, gh, hbf,
                                         (s == 4) ? d_out : nullptr, flag);
    }
  }

  conv_fused<<<dim3(64, 4), 256, 0, stream>>>(hbf, wbf + 786432, wbf + 851968,
                                              bp, ge, am32);
  finish_out<<<20, 256, 0, stream>>>(ge, am32, d_out, flag);
}